// Round 1
// baseline (3837.125 us; speedup 1.0000x reference)
//
#include <hip/hip_runtime.h>
#include <math.h>

#define BQ 4
#define LQ 4104
#define NTQ 4096
#define CDIM 320
#define DIP 1352
#define DI 640
#define CONVD 704
#define NH 8
#define HD 80
#define DS 32
#define MQ (BQ*LQ)   // 16416

__device__ __forceinline__ float warp_sum(float v){
  #pragma unroll
  for (int o = 32; o; o >>= 1) v += __shfl_xor(v, o);
  return v;
}

// ---------------- K1: build seq (x transpose + point embeddings) + LayerNorm ----------------
__global__ __launch_bounds__(320) void k_seq_ln(
    const float* __restrict__ x, const float* __restrict__ pcoords,
    const float* __restrict__ lnw, const float* __restrict__ lnb,
    const float* __restrict__ pgauss, const float* __restrict__ pemb_w,
    const float* __restrict__ nap, const int* __restrict__ plabels,
    float* __restrict__ xn)
{
  int mtok = blockIdx.x;
  int b = mtok / LQ, l = mtok % LQ;
  int c = threadIdx.x;
  float val;
  if (l < NTQ) {
    val = x[((size_t)(b*CDIM + c))*NTQ + l];
  } else {
    int j = l - NTQ;
    int f = (c < 160) ? c : c - 160;
    float p0 = pcoords[(b*8+j)*3+0]*(2.0f/16.0f) - 1.0f;
    float p1 = pcoords[(b*8+j)*3+1]*(2.0f/16.0f) - 1.0f;
    float p2 = pcoords[(b*8+j)*3+2]*(2.0f/16.0f) - 1.0f;
    float pe = 6.283185307179586f*(p0*pgauss[f] + p1*pgauss[160+f] + p2*pgauss[320+f]);
    float pv = (c < 160) ? sinf(pe) : cosf(pe);
    int lab = plabels[b*8+j];
    if (lab == -1) {
      val = nap[c];
    } else {
      int safe = lab < 0 ? 0 : (lab > 1 ? 1 : lab);
      val = pv + pemb_w[safe*CDIM + c];
    }
  }
  float s  = warp_sum(val);
  float s2 = warp_sum(val*val);
  __shared__ float r1[5], r2[5];
  int w = threadIdx.x >> 6, lane = threadIdx.x & 63;
  if (lane == 0) { r1[w] = s; r2[w] = s2; }
  __syncthreads();
  float ts = 0.f, ts2 = 0.f;
  #pragma unroll
  for (int i = 0; i < 5; i++) { ts += r1[i]; ts2 += r2[i]; }
  float mu  = ts * (1.0f/CDIM);
  float var = ts2 * (1.0f/CDIM) - mu*mu;
  float rsig = rsqrtf(var + 1e-5f);
  xn[(size_t)mtok*CDIM + c] = (val - mu)*rsig*lnw[c] + lnb[c];
}

// ---------------- K2: zxbcdt = xn @ in_proj_w^T  (M x 1352, K=320) ----------------
__global__ __launch_bounds__(256) void k_gemm1(
    const float* __restrict__ A, const float* __restrict__ W,
    float* __restrict__ Cout)
{
  __shared__ float As[16][129];
  __shared__ float Bs[16][129];
  int m0 = blockIdx.y * 128;
  int n0 = blockIdx.x * 128;
  int tid = threadIdx.x;
  int tx = tid & 15, ty = tid >> 4;
  float acc[8][8] = {};
  for (int k0 = 0; k0 < CDIM; k0 += 16) {
    #pragma unroll
    for (int t = 0; t < 2; t++) {
      int idx = tid + t*256;
      int r = idx >> 2, kq = (idx & 3) << 2;
      float4 av = make_float4(0,0,0,0);
      int m = m0 + r;
      if (m < MQ) av = *(const float4*)(A + (size_t)m*CDIM + k0 + kq);
      As[kq+0][r]=av.x; As[kq+1][r]=av.y; As[kq+2][r]=av.z; As[kq+3][r]=av.w;
      float4 bv = make_float4(0,0,0,0);
      int n = n0 + r;
      if (n < DIP) bv = *(const float4*)(W + (size_t)n*CDIM + k0 + kq);
      Bs[kq+0][r]=bv.x; Bs[kq+1][r]=bv.y; Bs[kq+2][r]=bv.z; Bs[kq+3][r]=bv.w;
    }
    __syncthreads();
    #pragma unroll
    for (int kk = 0; kk < 16; kk++) {
      float a[8], bb[8];
      #pragma unroll
      for (int i = 0; i < 8; i++) a[i] = As[kk][ty*8+i];
      #pragma unroll
      for (int j = 0; j < 8; j++) bb[j] = Bs[kk][tx*8+j];
      #pragma unroll
      for (int i = 0; i < 8; i++)
        #pragma unroll
        for (int j = 0; j < 8; j++)
          acc[i][j] = fmaf(a[i], bb[j], acc[i][j]);
    }
    __syncthreads();
  }
  #pragma unroll
  for (int i = 0; i < 8; i++) {
    int m = m0 + ty*8 + i;
    if (m >= MQ) continue;
    #pragma unroll
    for (int j = 0; j < 8; j++) {
      int n = n0 + tx*8 + j;
      if (n < DIP) Cout[(size_t)m*DIP + n] = acc[i][j];
    }
  }
}

// ---------------- K3: dt = softplus(dt_raw + bias), dA = exp(dt * -exp(A_log)) ----------------
__global__ __launch_bounds__(256) void k_dt(
    const float* __restrict__ zx, const float* __restrict__ dt_bias,
    const float* __restrict__ A_log, float* __restrict__ dtb, float* __restrict__ dab)
{
  int i = blockIdx.x*256 + threadIdx.x;
  if (i >= MQ*NH) return;
  int m = i >> 3, h = i & 7;
  float v = zx[(size_t)m*DIP + (DI + CONVD) + h] + dt_bias[h];
  float sp = (v > 20.f) ? v : log1pf(expf(v));
  float A = -expf(A_log[h]);
  dtb[i] = sp;
  dab[i] = expf(sp * A);
}

// ---------------- K4: depthwise causal conv(4) + bias + SiLU ----------------
__global__ __launch_bounds__(256) void k_conv(
    const float* __restrict__ zx, const float* __restrict__ cw,
    const float* __restrict__ cb, float* __restrict__ xc)
{
  int c = blockIdx.x*256 + threadIdx.x;
  if (c >= CONVD) return;
  int m = blockIdx.y;
  int l = m % LQ;
  float acc = cb[c];
  #pragma unroll
  for (int j = 0; j < 4; j++) {
    int ls = l - 3 + j;
    if (ls >= 0) acc = fmaf(zx[(size_t)(m-3+j)*DIP + DI + c], cw[c*4+j], acc);
  }
  float sv = acc / (1.f + expf(-acc));
  xc[(size_t)m*CONVD + c] = sv;
}

// ---------------- K5: sequential selective scan + Dp skip + z-gating ----------------
__global__ __launch_bounds__(640) void k_scan(
    const float* __restrict__ xc, const float* __restrict__ dtb,
    const float* __restrict__ dab, const float* __restrict__ zx,
    const float* __restrict__ Dp, float* __restrict__ yg)
{
  int b = blockIdx.x;
  int c = threadIdx.x;       // 0..639 : h = c/80, p = c%80
  int h = c / HD;
  float dpv = Dp[h];
  float hs[32];
  #pragma unroll
  for (int n = 0; n < 32; n++) hs[n] = 0.f;
  const float* xcb = xc + (size_t)b*LQ*CONVD;
  const float* zxb = zx + (size_t)b*LQ*DIP;
  float* ygb = yg + (size_t)b*LQ*DI;
  for (int l = 0; l < LQ; l++) {
    size_t ro = (size_t)l*CONVD;
    float xv  = xcb[ro + c];
    float dtv = dtb[((size_t)b*LQ + l)*NH + h];
    float dAv = dab[((size_t)b*LQ + l)*NH + h];
    const float4* Bp = (const float4*)(xcb + ro + DI);
    const float4* Cp = (const float4*)(xcb + ro + DI + DS);
    float dtx = dtv * xv;
    float y0=0.f, y1=0.f, y2=0.f, y3=0.f;
    #pragma unroll
    for (int q = 0; q < 8; q++) {
      float4 Bq = Bp[q], Cq = Cp[q];
      float h0 = hs[4*q+0]*dAv + dtx*Bq.x;
      float h1 = hs[4*q+1]*dAv + dtx*Bq.y;
      float h2 = hs[4*q+2]*dAv + dtx*Bq.z;
      float h3 = hs[4*q+3]*dAv + dtx*Bq.w;
      hs[4*q+0]=h0; hs[4*q+1]=h1; hs[4*q+2]=h2; hs[4*q+3]=h3;
      y0 = fmaf(h0, Cq.x, y0);
      y1 = fmaf(h1, Cq.y, y1);
      y2 = fmaf(h2, Cq.z, y2);
      y3 = fmaf(h3, Cq.w, y3);
    }
    float y = (y0+y1) + (y2+y3);
    y = fmaf(xv, dpv, y);
    float zv = zxb[(size_t)l*DIP + c];
    float g = zv / (1.f + expf(-zv));
    ygb[(size_t)l*DI + c] = y * g;
  }
}

// ---------------- K6: RMS scale per row ----------------
__global__ __launch_bounds__(256) void k_rms(const float* __restrict__ yg, float* __restrict__ rs)
{
  int m = blockIdx.x;
  int tid = threadIdx.x;
  const float* row = yg + (size_t)m*DI;
  float ss = 0.f;
  for (int k = tid; k < DI; k += 256) { float v = row[k]; ss = fmaf(v, v, ss); }
  ss = warp_sum(ss);
  __shared__ float r[4];
  int w = tid >> 6, lane = tid & 63;
  if (lane == 0) r[w] = ss;
  __syncthreads();
  if (tid == 0) {
    float t = r[0] + r[1] + r[2] + r[3];
    rs[m] = rsqrtf(t*(1.0f/DI) + 1e-5f);
  }
}

// ---------------- K7: out = (yg * rs * rms_w) @ out_proj_w^T, transposed store ----------------
__global__ __launch_bounds__(256) void k_gemm2(
    const float* __restrict__ yg, const float* __restrict__ rs,
    const float* __restrict__ rsw, const float* __restrict__ W2,
    float* __restrict__ out)
{
  __shared__ float As[16][129];
  __shared__ float Bs[16][65];
  int m0 = blockIdx.y * 128;
  int n0 = blockIdx.x * 64;
  int tid = threadIdx.x;
  int tx = tid & 15, ty = tid >> 4;
  float acc[8][4] = {};
  for (int k0 = 0; k0 < DI; k0 += 16) {
    #pragma unroll
    for (int t = 0; t < 2; t++) {
      int idx = tid + t*256;
      int r = idx >> 2, kq = (idx & 3) << 2;
      int m = m0 + r;
      float4 av = make_float4(0,0,0,0);
      float scale = 0.f;
      if (m < MQ) { av = *(const float4*)(yg + (size_t)m*DI + k0 + kq); scale = rs[m]; }
      float4 wv = *(const float4*)(rsw + k0 + kq);
      As[kq+0][r] = av.x*scale*wv.x;
      As[kq+1][r] = av.y*scale*wv.y;
      As[kq+2][r] = av.z*scale*wv.z;
      As[kq+3][r] = av.w*scale*wv.w;
    }
    {
      int r = tid >> 2, kq = (tid & 3) << 2;   // 64 rows x 4 quads = 256 threads
      float4 bv = *(const float4*)(W2 + (size_t)(n0 + r)*DI + k0 + kq);
      Bs[kq+0][r]=bv.x; Bs[kq+1][r]=bv.y; Bs[kq+2][r]=bv.z; Bs[kq+3][r]=bv.w;
    }
    __syncthreads();
    #pragma unroll
    for (int kk = 0; kk < 16; kk++) {
      float a[8], bb[4];
      #pragma unroll
      for (int i = 0; i < 8; i++) a[i] = As[kk][ty*8+i];
      #pragma unroll
      for (int j = 0; j < 4; j++) bb[j] = Bs[kk][tx*4+j];
      #pragma unroll
      for (int i = 0; i < 8; i++)
        #pragma unroll
        for (int j = 0; j < 4; j++)
          acc[i][j] = fmaf(a[i], bb[j], acc[i][j]);
    }
    __syncthreads();
  }
  #pragma unroll
  for (int i = 0; i < 8; i++) {
    int m = m0 + ty*8 + i;
    if (m >= MQ) continue;
    int b = m / LQ, l = m % LQ;
    if (l >= NTQ) continue;
    #pragma unroll
    for (int j = 0; j < 4; j++) {
      int n = n0 + tx*4 + j;
      out[((size_t)(b*CDIM) + n)*NTQ + l] = acc[i][j];
    }
  }
}

extern "C" void kernel_launch(void* const* d_in, const int* in_sizes, int n_in,
                              void* d_out, int out_size, void* d_ws, size_t ws_size,
                              hipStream_t stream)
{
  const float* x       = (const float*)d_in[0];
  const float* pc      = (const float*)d_in[1];
  const float* lnw     = (const float*)d_in[2];
  const float* lnb     = (const float*)d_in[3];
  const float* w1      = (const float*)d_in[4];
  const float* cw      = (const float*)d_in[5];
  const float* cb      = (const float*)d_in[6];
  const float* dt_bias = (const float*)d_in[7];
  const float* A_log   = (const float*)d_in[8];
  const float* Dp      = (const float*)d_in[9];
  const float* rsw     = (const float*)d_in[10];
  const float* w2      = (const float*)d_in[11];
  const float* pg      = (const float*)d_in[12];
  const float* pew     = (const float*)d_in[13];
  const float* nap     = (const float*)d_in[14];
  const int*   plab    = (const int*)d_in[15];
  float* out = (float*)d_out;

  float* xn  = (float*)d_ws;
  float* zx  = xn  + (size_t)MQ*CDIM;
  float* xc  = zx  + (size_t)MQ*DIP;
  float* dtb = xc  + (size_t)MQ*CONVD;
  float* dab = dtb + (size_t)MQ*NH;
  float* yg  = dab + (size_t)MQ*NH;
  float* rs  = yg  + (size_t)MQ*DI;

  k_seq_ln<<<MQ, 320, 0, stream>>>(x, pc, lnw, lnb, pg, pew, nap, plab, xn);
  dim3 g1(11, 129);
  k_gemm1<<<g1, 256, 0, stream>>>(xn, w1, zx);
  k_dt<<<(MQ*NH + 255)/256, 256, 0, stream>>>(zx, dt_bias, A_log, dtb, dab);
  dim3 g4(3, MQ);
  k_conv<<<g4, 256, 0, stream>>>(zx, cw, cb, xc);
  k_scan<<<BQ, 640, 0, stream>>>(xc, dtb, dab, zx, Dp, yg);
  k_rms<<<MQ, 256, 0, stream>>>(yg, rs);
  dim3 g7(5, 129);
  k_gemm2<<<g7, 256, 0, stream>>>(yg, rs, rsw, w2, out);
}

// Round 2
// 928.131 us; speedup vs baseline: 4.1342x; 4.1342x over previous
//
#include <hip/hip_runtime.h>
#include <math.h>

#define BQ 4
#define LQ 4104
#define NTQ 4096
#define CDIM 320
#define DIP 1352
#define DI 640
#define CONVD 704
#define NH 8
#define HD 80
#define DS 32
#define MQ (BQ*LQ)   // 16416
#define QC 128       // chunk length
#define NC 33        // ceil(LQ/QC): 32 full + 1 tail of 8

__device__ __forceinline__ float warp_sum(float v){
  #pragma unroll
  for (int o = 32; o; o >>= 1) v += __shfl_xor(v, o);
  return v;
}

// ---------------- K1: build seq (x transpose + point embeddings) + LayerNorm ----------------
__global__ __launch_bounds__(320) void k_seq_ln(
    const float* __restrict__ x, const float* __restrict__ pcoords,
    const float* __restrict__ lnw, const float* __restrict__ lnb,
    const float* __restrict__ pgauss, const float* __restrict__ pemb_w,
    const float* __restrict__ nap, const int* __restrict__ plabels,
    float* __restrict__ xn)
{
  int mtok = blockIdx.x;
  int b = mtok / LQ, l = mtok % LQ;
  int c = threadIdx.x;
  float val;
  if (l < NTQ) {
    val = x[((size_t)(b*CDIM + c))*NTQ + l];
  } else {
    int j = l - NTQ;
    int f = (c < 160) ? c : c - 160;
    float p0 = pcoords[(b*8+j)*3+0]*(2.0f/16.0f) - 1.0f;
    float p1 = pcoords[(b*8+j)*3+1]*(2.0f/16.0f) - 1.0f;
    float p2 = pcoords[(b*8+j)*3+2]*(2.0f/16.0f) - 1.0f;
    float pe = 6.283185307179586f*(p0*pgauss[f] + p1*pgauss[160+f] + p2*pgauss[320+f]);
    float pv = (c < 160) ? sinf(pe) : cosf(pe);
    int lab = plabels[b*8+j];
    if (lab == -1) {
      val = nap[c];
    } else {
      int safe = lab < 0 ? 0 : (lab > 1 ? 1 : lab);
      val = pv + pemb_w[safe*CDIM + c];
    }
  }
  float s  = warp_sum(val);
  float s2 = warp_sum(val*val);
  __shared__ float r1[5], r2[5];
  int w = threadIdx.x >> 6, lane = threadIdx.x & 63;
  if (lane == 0) { r1[w] = s; r2[w] = s2; }
  __syncthreads();
  float ts = 0.f, ts2 = 0.f;
  #pragma unroll
  for (int i = 0; i < 5; i++) { ts += r1[i]; ts2 += r2[i]; }
  float mu  = ts * (1.0f/CDIM);
  float var = ts2 * (1.0f/CDIM) - mu*mu;
  float rsig = rsqrtf(var + 1e-5f);
  xn[(size_t)mtok*CDIM + c] = (val - mu)*rsig*lnw[c] + lnb[c];
}

// ---------------- K2: zxbcdt = xn @ in_proj_w^T  (M x 1352, K=320) ----------------
__global__ __launch_bounds__(256) void k_gemm1(
    const float* __restrict__ A, const float* __restrict__ W,
    float* __restrict__ Cout)
{
  __shared__ float As[16][129];
  __shared__ float Bs[16][129];
  int m0 = blockIdx.y * 128;
  int n0 = blockIdx.x * 128;
  int tid = threadIdx.x;
  int tx = tid & 15, ty = tid >> 4;
  float acc[8][8] = {};
  for (int k0 = 0; k0 < CDIM; k0 += 16) {
    #pragma unroll
    for (int t = 0; t < 2; t++) {
      int idx = tid + t*256;
      int r = idx >> 2, kq = (idx & 3) << 2;
      float4 av = make_float4(0,0,0,0);
      int m = m0 + r;
      if (m < MQ) av = *(const float4*)(A + (size_t)m*CDIM + k0 + kq);
      As[kq+0][r]=av.x; As[kq+1][r]=av.y; As[kq+2][r]=av.z; As[kq+3][r]=av.w;
      float4 bv = make_float4(0,0,0,0);
      int n = n0 + r;
      if (n < DIP) bv = *(const float4*)(W + (size_t)n*CDIM + k0 + kq);
      Bs[kq+0][r]=bv.x; Bs[kq+1][r]=bv.y; Bs[kq+2][r]=bv.z; Bs[kq+3][r]=bv.w;
    }
    __syncthreads();
    #pragma unroll
    for (int kk = 0; kk < 16; kk++) {
      float a[8], bb[8];
      #pragma unroll
      for (int i = 0; i < 8; i++) a[i] = As[kk][ty*8+i];
      #pragma unroll
      for (int j = 0; j < 8; j++) bb[j] = Bs[kk][tx*8+j];
      #pragma unroll
      for (int i = 0; i < 8; i++)
        #pragma unroll
        for (int j = 0; j < 8; j++)
          acc[i][j] = fmaf(a[i], bb[j], acc[i][j]);
    }
    __syncthreads();
  }
  #pragma unroll
  for (int i = 0; i < 8; i++) {
    int m = m0 + ty*8 + i;
    if (m >= MQ) continue;
    #pragma unroll
    for (int j = 0; j < 8; j++) {
      int n = n0 + tx*8 + j;
      if (n < DIP) Cout[(size_t)m*DIP + n] = acc[i][j];
    }
  }
}

// ---------------- K3: dt = softplus(dt_raw + bias) ----------------
__global__ __launch_bounds__(256) void k_dt(
    const float* __restrict__ zx, const float* __restrict__ dt_bias,
    float* __restrict__ dtb)
{
  int i = blockIdx.x*256 + threadIdx.x;
  if (i >= MQ*NH) return;
  int m = i >> 3, h = i & 7;
  float v = zx[(size_t)m*DIP + (DI + CONVD) + h] + dt_bias[h];
  float sp = (v > 20.f) ? v : log1pf(expf(v));
  dtb[i] = sp;
}

// ---------------- K4: depthwise causal conv(4) + bias + SiLU ----------------
__global__ __launch_bounds__(256) void k_conv(
    const float* __restrict__ zx, const float* __restrict__ cw,
    const float* __restrict__ cb, float* __restrict__ xc)
{
  int c = blockIdx.x*256 + threadIdx.x;
  if (c >= CONVD) return;
  int m = blockIdx.y;
  int l = m % LQ;
  float acc = cb[c];
  #pragma unroll
  for (int j = 0; j < 4; j++) {
    int ls = l - 3 + j;
    if (ls >= 0) acc = fmaf(zx[(size_t)(m-3+j)*DIP + DI + c], cw[c*4+j], acc);
  }
  float sv = acc / (1.f + expf(-acc));
  xc[(size_t)m*CONVD + c] = sv;
}

// ---------------- K5a: per-chunk inclusive cumsum of dt*A ----------------
__global__ __launch_bounds__(QC) void k_cumsum(
    const float* __restrict__ dtb, const float* __restrict__ A_log,
    float* __restrict__ cs, float* __restrict__ Dc)
{
  int c = blockIdx.x, h = blockIdx.y, b = blockIdx.z;
  int l = threadIdx.x;
  int gl = c*QC + l;
  int len = LQ - c*QC; if (len > QC) len = QC;
  float A = -expf(A_log[h]);
  float a = (gl < LQ) ? dtb[((size_t)(b*LQ+gl))*NH + h] * A : 0.f;
  __shared__ float sm[QC];
  sm[l] = a;
  __syncthreads();
  for (int off = 1; off < QC; off <<= 1) {
    float v = (l >= off) ? sm[l-off] : 0.f;
    __syncthreads();
    sm[l] += v;
    __syncthreads();
  }
  cs[((size_t)(b*NH+h)*NC + c)*QC + l] = sm[l];
  if (l == len-1) Dc[(b*NH+h)*NC + c] = expf(sm[l]);
}

// ---------------- K5b: per-chunk end-state contribution S = sum_i w_i * x_i (x) B_i ----------------
__global__ __launch_bounds__(256) void k_chunk_state(
    const float* __restrict__ xc, const float* __restrict__ dtb,
    const float* __restrict__ cs, float* __restrict__ Sbuf)
{
  int c = blockIdx.x, h = blockIdx.y, b = blockIdx.z;
  int len = LQ - c*QC; if (len > QC) len = QC;
  int t = threadIdx.x;
  int m0 = b*LQ + c*QC;
  __shared__ float Xs[QC][HD+1];
  __shared__ float Bs[QC][DS+1];
  __shared__ float ws[QC];
  const float* csb = cs + ((size_t)(b*NH+h)*NC + c)*QC;
  float s_end = csb[len-1];
  for (int idx = t; idx < len*HD; idx += 256) {
    int i = idx / HD, p = idx % HD;
    Xs[i][p] = xc[((size_t)(m0+i))*CONVD + h*HD + p];
  }
  for (int idx = t; idx < len*DS; idx += 256) {
    int i = idx >> 5, n = idx & 31;
    Bs[i][n] = xc[((size_t)(m0+i))*CONVD + DI + n];
  }
  if (t < len) ws[t] = expf(s_end - csb[t]) * dtb[((size_t)(m0+t))*NH + h];
  __syncthreads();
  int n = t & 31, pb = t >> 5;   // pb in 0..7
  float acc[10] = {};
  for (int i = 0; i < len; i++) {
    float bw = ws[i] * Bs[i][n];
    #pragma unroll
    for (int k = 0; k < 10; k++) acc[k] = fmaf(bw, Xs[i][pb + 8*k], acc[k]);
  }
  size_t base = ((size_t)(b*NC + c)*NH + h)*(HD*DS);
  #pragma unroll
  for (int k = 0; k < 10; k++) Sbuf[base + (size_t)(pb + 8*k)*DS + n] = acc[k];
}

// ---------------- K5c: tiny sequential scan over 33 chunk states ----------------
__global__ __launch_bounds__(256) void k_state_scan(
    const float* __restrict__ Sbuf, const float* __restrict__ Dc,
    float* __restrict__ H0)
{
  int tid = blockIdx.x*256 + threadIdx.x;   // B*NH*HD*DS = 81920
  int pn = tid % (HD*DS);
  int bh = tid / (HD*DS);
  int b = bh >> 3, h = bh & 7;
  float hst = 0.f;
  for (int c = 0; c < NC; c++) {
    size_t idx = ((size_t)(b*NC + c)*NH + h)*(HD*DS) + pn;
    H0[idx] = hst;
    hst = hst * Dc[bh*NC + c] + Sbuf[idx];
  }
}

// ---------------- K5d: per-chunk outputs: inter + intra, Dp skip, z-gate ----------------
__global__ __launch_bounds__(256) void k_chunk_y(
    const float* __restrict__ xc, const float* __restrict__ zx,
    const float* __restrict__ dtb, const float* __restrict__ cs,
    const float* __restrict__ H0, const float* __restrict__ Dp,
    float* __restrict__ yg)
{
  int c = blockIdx.x, h = blockIdx.y, b = blockIdx.z;
  int len = LQ - c*QC; if (len > QC) len = QC;
  int t = threadIdx.x;
  int tx = t & 15, ty = t >> 4;
  int m0 = b*LQ + c*QC;
  __shared__ float Cs[QC][DS+1];
  __shared__ float Ws[QC][DS+1];
  __shared__ float h0s[HD][DS+1];
  __shared__ float Xs[DS][HD+1];
  __shared__ float Bs[DS][DS+1];
  __shared__ float sl[QC], dtl[QC];
  const float* csb = cs + ((size_t)(b*NH+h)*NC + c)*QC;
  for (int idx = t; idx < QC*DS; idx += 256) {
    int l = idx >> 5, n = idx & 31;
    Cs[l][n] = (c*QC + l < LQ) ? xc[((size_t)(m0+l))*CONVD + DI + DS + n] : 0.f;
  }
  {
    size_t hb = ((size_t)(b*NC + c)*NH + h)*(HD*DS);
    for (int idx = t; idx < HD*DS; idx += 256) {
      h0s[idx >> 5][idx & 31] = H0[hb + idx];
    }
  }
  if (t < QC) {
    sl[t] = csb[t];
    dtl[t] = (c*QC + t < LQ) ? dtb[((size_t)(m0+t))*NH + h] : 0.f;
  }
  __syncthreads();

  float acc[8][5];
  // inter-chunk: exp(s_l) * C_l . h0
  #pragma unroll
  for (int i2 = 0; i2 < 8; i2++) {
    int l = ty*8 + i2;
    float el = expf(sl[l]);
    float crow[DS];
    #pragma unroll
    for (int n = 0; n < DS; n++) crow[n] = Cs[l][n];
    #pragma unroll
    for (int j = 0; j < 5; j++) {
      int p = tx*5 + j;
      float s = 0.f;
      #pragma unroll
      for (int n = 0; n < DS; n++) s = fmaf(crow[n], h0s[p][n], s);
      acc[i2][j] = el * s;
    }
  }

  int ntile = (len + DS - 1) / DS;
  for (int tt = 0; tt < ntile; tt++) {
    int i0 = tt*DS;
    int tl = len - i0; if (tl > DS) tl = DS;
    for (int idx = t; idx < DS*DS; idx += 256) {
      int i = idx >> 5, n = idx & 31;
      Bs[i][n] = (i < tl) ? xc[((size_t)(m0+i0+i))*CONVD + DI + n] : 0.f;
    }
    for (int idx = t; idx < DS*HD; idx += 256) {
      int i = idx / HD, p = idx % HD;
      Xs[i][p] = (i < tl) ? xc[((size_t)(m0+i0+i))*CONVD + h*HD + p] : 0.f;
    }
    __syncthreads();
    // W[l][i] = (C_l . B_i) * exp(s_l - s_i) * dt_i, causal-masked
    for (int idx = t; idx < QC*DS; idx += 256) {
      int l = idx >> 5, i = idx & 31;
      float v = 0.f;
      int gi = i0 + i;
      if (i < tl && gi <= l && l < len) {
        float s = 0.f;
        #pragma unroll
        for (int n = 0; n < DS; n++) s = fmaf(Cs[l][n], Bs[i][n], s);
        v = s * expf(sl[l] - sl[gi]) * dtl[gi];
      }
      Ws[l][i] = v;
    }
    __syncthreads();
    #pragma unroll
    for (int i2 = 0; i2 < 8; i2++) {
      int l = ty*8 + i2;
      float wrow[DS];
      #pragma unroll
      for (int i = 0; i < DS; i++) wrow[i] = Ws[l][i];
      #pragma unroll
      for (int i = 0; i < DS; i++) {
        #pragma unroll
        for (int j = 0; j < 5; j++)
          acc[i2][j] = fmaf(wrow[i], Xs[i][tx*5 + j], acc[i2][j]);
      }
    }
    __syncthreads();
  }

  float dpv = Dp[h];
  #pragma unroll
  for (int i2 = 0; i2 < 8; i2++) {
    int l = ty*8 + i2;
    if (l >= len) continue;
    size_t m = m0 + l;
    #pragma unroll
    for (int j = 0; j < 5; j++) {
      int cc = h*HD + tx*5 + j;
      float xv = xc[m*CONVD + cc];
      float y = acc[i2][j] + xv*dpv;
      float zv = zx[m*DIP + cc];
      y *= zv / (1.f + expf(-zv));
      yg[m*DI + cc] = y;
    }
  }
}

// ---------------- K6: RMS scale per row ----------------
__global__ __launch_bounds__(256) void k_rms(const float* __restrict__ yg, float* __restrict__ rs)
{
  int m = blockIdx.x;
  int tid = threadIdx.x;
  const float* row = yg + (size_t)m*DI;
  float ss = 0.f;
  for (int k = tid; k < DI; k += 256) { float v = row[k]; ss = fmaf(v, v, ss); }
  ss = warp_sum(ss);
  __shared__ float r[4];
  int w = tid >> 6, lane = tid & 63;
  if (lane == 0) r[w] = ss;
  __syncthreads();
  if (tid == 0) {
    float t = r[0] + r[1] + r[2] + r[3];
    rs[m] = rsqrtf(t*(1.0f/DI) + 1e-5f);
  }
}

// ---------------- K7: out = (yg * rs * rms_w) @ out_proj_w^T, transposed store ----------------
__global__ __launch_bounds__(256) void k_gemm2(
    const float* __restrict__ yg, const float* __restrict__ rs,
    const float* __restrict__ rsw, const float* __restrict__ W2,
    float* __restrict__ out)
{
  __shared__ float As[16][129];
  __shared__ float Bs[16][65];
  int m0 = blockIdx.y * 128;
  int n0 = blockIdx.x * 64;
  int tid = threadIdx.x;
  int tx = tid & 15, ty = tid >> 4;
  float acc[8][4] = {};
  for (int k0 = 0; k0 < DI; k0 += 16) {
    #pragma unroll
    for (int t = 0; t < 2; t++) {
      int idx = tid + t*256;
      int r = idx >> 2, kq = (idx & 3) << 2;
      int m = m0 + r;
      float4 av = make_float4(0,0,0,0);
      float scale = 0.f;
      if (m < MQ) { av = *(const float4*)(yg + (size_t)m*DI + k0 + kq); scale = rs[m]; }
      float4 wv = *(const float4*)(rsw + k0 + kq);
      As[kq+0][r] = av.x*scale*wv.x;
      As[kq+1][r] = av.y*scale*wv.y;
      As[kq+2][r] = av.z*scale*wv.z;
      As[kq+3][r] = av.w*scale*wv.w;
    }
    {
      int r = tid >> 2, kq = (tid & 3) << 2;
      float4 bv = *(const float4*)(W2 + (size_t)(n0 + r)*DI + k0 + kq);
      Bs[kq+0][r]=bv.x; Bs[kq+1][r]=bv.y; Bs[kq+2][r]=bv.z; Bs[kq+3][r]=bv.w;
    }
    __syncthreads();
    #pragma unroll
    for (int kk = 0; kk < 16; kk++) {
      float a[8], bb[4];
      #pragma unroll
      for (int i = 0; i < 8; i++) a[i] = As[kk][ty*8+i];
      #pragma unroll
      for (int j = 0; j < 4; j++) bb[j] = Bs[kk][tx*4+j];
      #pragma unroll
      for (int i = 0; i < 8; i++)
        #pragma unroll
        for (int j = 0; j < 4; j++)
          acc[i][j] = fmaf(a[i], bb[j], acc[i][j]);
    }
    __syncthreads();
  }
  #pragma unroll
  for (int i = 0; i < 8; i++) {
    int m = m0 + ty*8 + i;
    if (m >= MQ) continue;
    int b = m / LQ, l = m % LQ;
    if (l >= NTQ) continue;
    #pragma unroll
    for (int j = 0; j < 4; j++) {
      int n = n0 + tx*4 + j;
      out[((size_t)(b*CDIM) + n)*NTQ + l] = acc[i][j];
    }
  }
}

extern "C" void kernel_launch(void* const* d_in, const int* in_sizes, int n_in,
                              void* d_out, int out_size, void* d_ws, size_t ws_size,
                              hipStream_t stream)
{
  const float* x       = (const float*)d_in[0];
  const float* pc      = (const float*)d_in[1];
  const float* lnw     = (const float*)d_in[2];
  const float* lnb     = (const float*)d_in[3];
  const float* w1      = (const float*)d_in[4];
  const float* cw      = (const float*)d_in[5];
  const float* cb      = (const float*)d_in[6];
  const float* dt_bias = (const float*)d_in[7];
  const float* A_log   = (const float*)d_in[8];
  const float* Dp      = (const float*)d_in[9];
  const float* rsw     = (const float*)d_in[10];
  const float* w2      = (const float*)d_in[11];
  const float* pg      = (const float*)d_in[12];
  const float* pew     = (const float*)d_in[13];
  const float* nap     = (const float*)d_in[14];
  const int*   plab    = (const int*)d_in[15];
  float* out = (float*)d_out;

  float* xn  = (float*)d_ws;
  float* zx  = xn  + (size_t)MQ*CDIM;
  float* xc  = zx  + (size_t)MQ*DIP;
  float* dtb = xc  + (size_t)MQ*CONVD;
  float* cs  = dtb + (size_t)MQ*NH;
  float* Dc  = cs  + (size_t)BQ*NH*NC*QC;
  float* Sb  = Dc  + (size_t)BQ*NH*NC;
  float* H0  = Sb  + (size_t)BQ*NC*NH*HD*DS;
  float* yg  = H0  + (size_t)BQ*NC*NH*HD*DS;
  float* rs  = yg  + (size_t)MQ*DI;

  k_seq_ln<<<MQ, 320, 0, stream>>>(x, pc, lnw, lnb, pg, pew, nap, plab, xn);
  dim3 g1(11, 129);
  k_gemm1<<<g1, 256, 0, stream>>>(xn, w1, zx);
  k_dt<<<(MQ*NH + 255)/256, 256, 0, stream>>>(zx, dt_bias, dtb);
  dim3 g4(3, MQ);
  k_conv<<<g4, 256, 0, stream>>>(zx, cw, cb, xc);
  dim3 gc(NC, NH, BQ);
  k_cumsum<<<gc, QC, 0, stream>>>(dtb, A_log, cs, Dc);
  k_chunk_state<<<gc, 256, 0, stream>>>(xc, dtb, cs, Sb);
  k_state_scan<<<(BQ*NH*HD*DS)/256, 256, 0, stream>>>(Sb, Dc, H0);
  k_chunk_y<<<gc, 256, 0, stream>>>(xc, zx, dtb, cs, H0, Dp, yg);
  k_rms<<<MQ, 256, 0, stream>>>(yg, rs);
  dim3 g7(5, 129);
  k_gemm2<<<g7, 256, 0, stream>>>(yg, rs, rsw, w2, out);
}

// Round 3
// 540.395 us; speedup vs baseline: 7.1006x; 1.7175x over previous
//
#include <hip/hip_runtime.h>
#include <math.h>

#define BQ 4
#define LQ 4104
#define NTQ 4096
#define CDIM 320
#define DIP 1352
#define DI 640
#define CONVD 704
#define NH 8
#define HD 80
#define DS 32
#define MQ (BQ*LQ)   // 16416
#define QC 128       // chunk length
#define NC 33        // ceil(LQ/QC)

typedef __attribute__((ext_vector_type(8))) short bf16x8;
typedef __attribute__((ext_vector_type(4))) float f32x4;

__device__ __forceinline__ unsigned short f2bf(float f){
  union { float f; unsigned u; } v; v.f = f;
  unsigned r = v.u + 0x7FFFu + ((v.u >> 16) & 1u);
  return (unsigned short)(r >> 16);
}

__device__ __forceinline__ float warp_sum(float v){
  #pragma unroll
  for (int o = 32; o; o >>= 1) v += __shfl_xor(v, o);
  return v;
}

// ---------------- K0: f32 -> bf16 bulk convert ----------------
__global__ __launch_bounds__(256) void k_f2bf(
    const float* __restrict__ s, unsigned short* __restrict__ d, int n)
{
  int i = blockIdx.x*256 + threadIdx.x;
  if (i < n) d[i] = f2bf(s[i]);
}

// ---------------- K1: build seq + LayerNorm, emit bf16 ----------------
__global__ __launch_bounds__(320) void k_seq_ln(
    const float* __restrict__ x, const float* __restrict__ pcoords,
    const float* __restrict__ lnw, const float* __restrict__ lnb,
    const float* __restrict__ pgauss, const float* __restrict__ pemb_w,
    const float* __restrict__ nap, const int* __restrict__ plabels,
    unsigned short* __restrict__ xnh)
{
  int mtok = blockIdx.x;
  int b = mtok / LQ, l = mtok % LQ;
  int c = threadIdx.x;
  float val;
  if (l < NTQ) {
    val = x[((size_t)(b*CDIM + c))*NTQ + l];
  } else {
    int j = l - NTQ;
    int f = (c < 160) ? c : c - 160;
    float p0 = pcoords[(b*8+j)*3+0]*(2.0f/16.0f) - 1.0f;
    float p1 = pcoords[(b*8+j)*3+1]*(2.0f/16.0f) - 1.0f;
    float p2 = pcoords[(b*8+j)*3+2]*(2.0f/16.0f) - 1.0f;
    float pe = 6.283185307179586f*(p0*pgauss[f] + p1*pgauss[160+f] + p2*pgauss[320+f]);
    float pv = (c < 160) ? sinf(pe) : cosf(pe);
    int lab = plabels[b*8+j];
    if (lab == -1) {
      val = nap[c];
    } else {
      int safe = lab < 0 ? 0 : (lab > 1 ? 1 : lab);
      val = pv + pemb_w[safe*CDIM + c];
    }
  }
  float s  = warp_sum(val);
  float s2 = warp_sum(val*val);
  __shared__ float r1[5], r2[5];
  int w = threadIdx.x >> 6, lane = threadIdx.x & 63;
  if (lane == 0) { r1[w] = s; r2[w] = s2; }
  __syncthreads();
  float ts = 0.f, ts2 = 0.f;
  #pragma unroll
  for (int i = 0; i < 5; i++) { ts += r1[i]; ts2 += r2[i]; }
  float mu  = ts * (1.0f/CDIM);
  float var = ts2 * (1.0f/CDIM) - mu*mu;
  float rsig = rsqrtf(var + 1e-5f);
  xnh[(size_t)mtok*CDIM + c] = f2bf((val - mu)*rsig*lnw[c] + lnb[c]);
}

// ---------------- K2: zx = xn @ w1^T via MFMA (M x 1352, K=320) ----------------
__global__ __launch_bounds__(256) void k_gemm1_mfma(
    const unsigned short* __restrict__ Abf, const unsigned short* __restrict__ Wbf,
    float* __restrict__ Cout)
{
  __shared__ unsigned short As[128][40];
  __shared__ unsigned short Bs[128][40];
  int m0 = blockIdx.y * 128;
  int n0 = blockIdx.x * 128;
  int tid = threadIdx.x;
  int lane = tid & 63, wid = tid >> 6;
  int wr = wid >> 1, wc = wid & 1;
  int fr = lane & 15, fq = lane >> 4;
  f32x4 acc[4][4] = {};
  for (int k0 = 0; k0 < CDIM; k0 += 32) {
    #pragma unroll
    for (int rnd = 0; rnd < 2; rnd++) {
      int idx = tid + rnd*256;
      int row = idx >> 2, slot = idx & 3;
      uint4 va = make_uint4(0,0,0,0);
      if (m0 + row < MQ) va = *(const uint4*)(Abf + (size_t)(m0+row)*CDIM + k0 + slot*8);
      *(uint4*)&As[row][slot*8] = va;
      uint4 vb = make_uint4(0,0,0,0);
      if (n0 + row < DIP) vb = *(const uint4*)(Wbf + (size_t)(n0+row)*CDIM + k0 + slot*8);
      *(uint4*)&Bs[row][slot*8] = vb;
    }
    __syncthreads();
    bf16x8 fa[4], fb[4];
    #pragma unroll
    for (int i = 0; i < 4; i++) {
      fa[i] = *(const bf16x8*)&As[wr*64 + i*16 + fr][fq*8];
      fb[i] = *(const bf16x8*)&Bs[wc*64 + i*16 + fr][fq*8];
    }
    #pragma unroll
    for (int i = 0; i < 4; i++)
      #pragma unroll
      for (int j = 0; j < 4; j++)
        acc[i][j] = __builtin_amdgcn_mfma_f32_16x16x32_bf16(fa[i], fb[j], acc[i][j], 0, 0, 0);
    __syncthreads();
  }
  #pragma unroll
  for (int i = 0; i < 4; i++) {
    #pragma unroll
    for (int j = 0; j < 4; j++) {
      #pragma unroll
      for (int r = 0; r < 4; r++) {
        int grow = m0 + wr*64 + i*16 + fq*4 + r;
        int gcol = n0 + wc*64 + j*16 + fr;
        if (grow < MQ && gcol < DIP) Cout[(size_t)grow*DIP + gcol] = acc[i][j][r];
      }
    }
  }
}

// ---------------- K3: dt = softplus(dt_raw + bias) ----------------
__global__ __launch_bounds__(256) void k_dt(
    const float* __restrict__ zx, const float* __restrict__ dt_bias,
    float* __restrict__ dtb)
{
  int i = blockIdx.x*256 + threadIdx.x;
  if (i >= MQ*NH) return;
  int m = i >> 3, h = i & 7;
  float v = zx[(size_t)m*DIP + (DI + CONVD) + h] + dt_bias[h];
  float sp = (v > 20.f) ? v : log1pf(expf(v));
  dtb[i] = sp;
}

// ---------------- K4: depthwise causal conv(4) + bias + SiLU ----------------
__global__ __launch_bounds__(256) void k_conv(
    const float* __restrict__ zx, const float* __restrict__ cw,
    const float* __restrict__ cb, float* __restrict__ xc)
{
  int c = blockIdx.x*256 + threadIdx.x;
  if (c >= CONVD) return;
  int m = blockIdx.y;
  int l = m % LQ;
  float acc = cb[c];
  #pragma unroll
  for (int j = 0; j < 4; j++) {
    int ls = l - 3 + j;
    if (ls >= 0) acc = fmaf(zx[(size_t)(m-3+j)*DIP + DI + c], cw[c*4+j], acc);
  }
  float sv = acc / (1.f + expf(-acc));
  xc[(size_t)m*CONVD + c] = sv;
}

// ---------------- K5a: per-chunk inclusive cumsum of dt*A ----------------
__global__ __launch_bounds__(QC) void k_cumsum(
    const float* __restrict__ dtb, const float* __restrict__ A_log,
    float* __restrict__ cs, float* __restrict__ Dc)
{
  int c = blockIdx.x, h = blockIdx.y, b = blockIdx.z;
  int l = threadIdx.x;
  int gl = c*QC + l;
  int len = LQ - c*QC; if (len > QC) len = QC;
  float A = -expf(A_log[h]);
  float a = (gl < LQ) ? dtb[((size_t)(b*LQ+gl))*NH + h] * A : 0.f;
  __shared__ float sm[QC];
  sm[l] = a;
  __syncthreads();
  for (int off = 1; off < QC; off <<= 1) {
    float v = (l >= off) ? sm[l-off] : 0.f;
    __syncthreads();
    sm[l] += v;
    __syncthreads();
  }
  cs[((size_t)(b*NH+h)*NC + c)*QC + l] = sm[l];
  if (l == len-1) Dc[(b*NH+h)*NC + c] = expf(sm[l]);
}

// ---------------- K5b: per-chunk end-state S = sum_i w_i * x_i (x) B_i ----------------
__global__ __launch_bounds__(256) void k_chunk_state(
    const float* __restrict__ xc, const float* __restrict__ dtb,
    const float* __restrict__ cs, float* __restrict__ Sbuf)
{
  int c = blockIdx.x, h = blockIdx.y, b = blockIdx.z;
  int len = LQ - c*QC; if (len > QC) len = QC;
  int t = threadIdx.x;
  int m0 = b*LQ + c*QC;
  __shared__ float Xs[QC][HD+1];
  __shared__ float Bs[QC][DS+1];
  __shared__ float ws[QC];
  const float* csb = cs + ((size_t)(b*NH+h)*NC + c)*QC;
  float s_end = csb[len-1];
  for (int idx = t; idx < len*HD; idx += 256) {
    int i = idx / HD, p = idx % HD;
    Xs[i][p] = xc[((size_t)(m0+i))*CONVD + h*HD + p];
  }
  for (int idx = t; idx < len*DS; idx += 256) {
    int i = idx >> 5, n = idx & 31;
    Bs[i][n] = xc[((size_t)(m0+i))*CONVD + DI + n];
  }
  if (t < len) ws[t] = expf(s_end - csb[t]) * dtb[((size_t)(m0+t))*NH + h];
  __syncthreads();
  int n = t & 31, pb = t >> 5;
  float acc[10] = {};
  for (int i = 0; i < len; i++) {
    float bw = ws[i] * Bs[i][n];
    #pragma unroll
    for (int k = 0; k < 10; k++) acc[k] = fmaf(bw, Xs[i][pb + 8*k], acc[k]);
  }
  size_t base = ((size_t)(b*NC + c)*NH + h)*(HD*DS);
  #pragma unroll
  for (int k = 0; k < 10; k++) Sbuf[base + (size_t)(pb + 8*k)*DS + n] = acc[k];
}

// ---------------- K5c: tiny sequential scan over chunk states ----------------
__global__ __launch_bounds__(256) void k_state_scan(
    const float* __restrict__ Sbuf, const float* __restrict__ Dc,
    float* __restrict__ H0)
{
  int tid = blockIdx.x*256 + threadIdx.x;
  int pn = tid % (HD*DS);
  int bh = tid / (HD*DS);
  int b = bh >> 3, h = bh & 7;
  float hst = 0.f;
  for (int c = 0; c < NC; c++) {
    size_t idx = ((size_t)(b*NC + c)*NH + h)*(HD*DS) + pn;
    H0[idx] = hst;
    hst = hst * Dc[bh*NC + c] + Sbuf[idx];
  }
}

// ---------------- K5d: per-chunk outputs: inter + intra, Dp skip, z-gate ----------------
__global__ __launch_bounds__(256) void k_chunk_y(
    const float* __restrict__ xc, const float* __restrict__ zx,
    const float* __restrict__ dtb, const float* __restrict__ cs,
    const float* __restrict__ H0, const float* __restrict__ Dp,
    float* __restrict__ yg)
{
  int c = blockIdx.x, h = blockIdx.y, b = blockIdx.z;
  int len = LQ - c*QC; if (len > QC) len = QC;
  int t = threadIdx.x;
  int tx = t & 15, ty = t >> 4;
  int m0 = b*LQ + c*QC;
  __shared__ float Cs[QC][DS+1];
  __shared__ float Ws[QC][DS+1];
  __shared__ float h0s[HD][DS+1];
  __shared__ float Xs[DS][HD+1];
  __shared__ float Bs[DS][DS+1];
  __shared__ float sl[QC], dtl[QC];
  const float* csb = cs + ((size_t)(b*NH+h)*NC + c)*QC;
  for (int idx = t; idx < QC*DS; idx += 256) {
    int l = idx >> 5, n = idx & 31;
    Cs[l][n] = (c*QC + l < LQ) ? xc[((size_t)(m0+l))*CONVD + DI + DS + n] : 0.f;
  }
  {
    size_t hb = ((size_t)(b*NC + c)*NH + h)*(HD*DS);
    for (int idx = t; idx < HD*DS; idx += 256) {
      h0s[idx >> 5][idx & 31] = H0[hb + idx];
    }
  }
  if (t < QC) {
    sl[t] = csb[t];
    dtl[t] = (c*QC + t < LQ) ? dtb[((size_t)(m0+t))*NH + h] : 0.f;
  }
  __syncthreads();

  float acc[8][5];
  #pragma unroll
  for (int i2 = 0; i2 < 8; i2++) {
    int l = ty*8 + i2;
    float el = expf(sl[l]);
    float crow[DS];
    #pragma unroll
    for (int n = 0; n < DS; n++) crow[n] = Cs[l][n];
    #pragma unroll
    for (int j = 0; j < 5; j++) {
      int p = tx*5 + j;
      float s = 0.f;
      #pragma unroll
      for (int n = 0; n < DS; n++) s = fmaf(crow[n], h0s[p][n], s);
      acc[i2][j] = el * s;
    }
  }

  int ntile = (len + DS - 1) / DS;
  for (int tt = 0; tt < ntile; tt++) {
    int i0 = tt*DS;
    int tl = len - i0; if (tl > DS) tl = DS;
    for (int idx = t; idx < DS*DS; idx += 256) {
      int i = idx >> 5, n = idx & 31;
      Bs[i][n] = (i < tl) ? xc[((size_t)(m0+i0+i))*CONVD + DI + n] : 0.f;
    }
    for (int idx = t; idx < DS*HD; idx += 256) {
      int i = idx / HD, p = idx % HD;
      Xs[i][p] = (i < tl) ? xc[((size_t)(m0+i0+i))*CONVD + h*HD + p] : 0.f;
    }
    __syncthreads();
    for (int idx = t; idx < QC*DS; idx += 256) {
      int l = idx >> 5, i = idx & 31;
      float v = 0.f;
      int gi = i0 + i;
      if (i < tl && gi <= l && l < len) {
        float s = 0.f;
        #pragma unroll
        for (int n = 0; n < DS; n++) s = fmaf(Cs[l][n], Bs[i][n], s);
        v = s * expf(sl[l] - sl[gi]) * dtl[gi];
      }
      Ws[l][i] = v;
    }
    __syncthreads();
    #pragma unroll
    for (int i2 = 0; i2 < 8; i2++) {
      int l = ty*8 + i2;
      float wrow[DS];
      #pragma unroll
      for (int i = 0; i < DS; i++) wrow[i] = Ws[l][i];
      #pragma unroll
      for (int i = 0; i < DS; i++) {
        #pragma unroll
        for (int j = 0; j < 5; j++)
          acc[i2][j] = fmaf(wrow[i], Xs[i][tx*5 + j], acc[i2][j]);
      }
    }
    __syncthreads();
  }

  float dpv = Dp[h];
  #pragma unroll
  for (int i2 = 0; i2 < 8; i2++) {
    int l = ty*8 + i2;
    if (l >= len) continue;
    size_t m = m0 + l;
    #pragma unroll
    for (int j = 0; j < 5; j++) {
      int cc = h*HD + tx*5 + j;
      float xv = xc[m*CONVD + cc];
      float y = acc[i2][j] + xv*dpv;
      float zv = zx[m*DIP + cc];
      y *= zv / (1.f + expf(-zv));
      yg[m*DI + cc] = y;
    }
  }
}

// ---------------- K6: RMS + scale, emit bf16 A for GEMM2 ----------------
__global__ __launch_bounds__(256) void k_rms_scale(
    const float* __restrict__ yg, const float* __restrict__ rsw,
    unsigned short* __restrict__ ygh)
{
  int m = blockIdx.x;
  int t = threadIdx.x;
  const float* row = yg + (size_t)m*DI;
  float v0 = row[t];
  float v1 = row[t+256];
  float v2 = (t < 128) ? row[t+512] : 0.f;
  float ss = v0*v0 + v1*v1 + v2*v2;
  ss = warp_sum(ss);
  __shared__ float r[4];
  int w = t >> 6, lane = t & 63;
  if (lane == 0) r[w] = ss;
  __syncthreads();
  float tot = r[0] + r[1] + r[2] + r[3];
  float rsv = rsqrtf(tot*(1.0f/DI) + 1e-5f);
  ygh[(size_t)m*DI + t]       = f2bf(v0 * rsv * rsw[t]);
  ygh[(size_t)m*DI + t + 256] = f2bf(v1 * rsv * rsw[t+256]);
  if (t < 128)
    ygh[(size_t)m*DI + t + 512] = f2bf(v2 * rsv * rsw[t+512]);
}

// ---------------- K7: out^T = w2 @ ygh^T via MFMA, coalesced transposed store ----------------
__global__ __launch_bounds__(256) void k_gemm2_mfma(
    const unsigned short* __restrict__ W2h, const unsigned short* __restrict__ Ygh,
    float* __restrict__ out)
{
  __shared__ unsigned short As[128][40];
  __shared__ unsigned short Bs[128][40];
  int c0 = blockIdx.y * 128;   // out channel tile (over 320)
  int t0 = blockIdx.x * 128;   // token tile (over MQ)
  int tid = threadIdx.x;
  int lane = tid & 63, wid = tid >> 6;
  int wr = wid >> 1, wc = wid & 1;
  int fr = lane & 15, fq = lane >> 4;
  f32x4 acc[4][4] = {};
  for (int k0 = 0; k0 < DI; k0 += 32) {
    #pragma unroll
    for (int rnd = 0; rnd < 2; rnd++) {
      int idx = tid + rnd*256;
      int row = idx >> 2, slot = idx & 3;
      uint4 va = make_uint4(0,0,0,0);
      if (c0 + row < CDIM) va = *(const uint4*)(W2h + (size_t)(c0+row)*DI + k0 + slot*8);
      *(uint4*)&As[row][slot*8] = va;
      uint4 vb = make_uint4(0,0,0,0);
      if (t0 + row < MQ) vb = *(const uint4*)(Ygh + (size_t)(t0+row)*DI + k0 + slot*8);
      *(uint4*)&Bs[row][slot*8] = vb;
    }
    __syncthreads();
    bf16x8 fa[4], fb[4];
    #pragma unroll
    for (int i = 0; i < 4; i++) {
      fa[i] = *(const bf16x8*)&As[wr*64 + i*16 + fr][fq*8];
      fb[i] = *(const bf16x8*)&Bs[wc*64 + i*16 + fr][fq*8];
    }
    #pragma unroll
    for (int i = 0; i < 4; i++)
      #pragma unroll
      for (int j = 0; j < 4; j++)
        acc[i][j] = __builtin_amdgcn_mfma_f32_16x16x32_bf16(fa[i], fb[j], acc[i][j], 0, 0, 0);
    __syncthreads();
  }
  #pragma unroll
  for (int i = 0; i < 4; i++) {
    #pragma unroll
    for (int j = 0; j < 4; j++) {
      #pragma unroll
      for (int r = 0; r < 4; r++) {
        int ch  = c0 + wr*64 + i*16 + fq*4 + r;     // out channel
        int tok = t0 + wc*64 + j*16 + fr;           // token
        if (ch < CDIM && tok < MQ) {
          int b = tok / LQ, l = tok % LQ;
          if (l < NTQ)
            out[((size_t)(b*CDIM + ch))*NTQ + l] = acc[i][j][r];
        }
      }
    }
  }
}

extern "C" void kernel_launch(void* const* d_in, const int* in_sizes, int n_in,
                              void* d_out, int out_size, void* d_ws, size_t ws_size,
                              hipStream_t stream)
{
  const float* x       = (const float*)d_in[0];
  const float* pc      = (const float*)d_in[1];
  const float* lnw     = (const float*)d_in[2];
  const float* lnb     = (const float*)d_in[3];
  const float* w1      = (const float*)d_in[4];
  const float* cw      = (const float*)d_in[5];
  const float* cb      = (const float*)d_in[6];
  const float* dt_bias = (const float*)d_in[7];
  const float* A_log   = (const float*)d_in[8];
  const float* Dp      = (const float*)d_in[9];
  const float* rsw     = (const float*)d_in[10];
  const float* w2      = (const float*)d_in[11];
  const float* pg      = (const float*)d_in[12];
  const float* pew     = (const float*)d_in[13];
  const float* nap     = (const float*)d_in[14];
  const int*   plab    = (const int*)d_in[15];
  float* out = (float*)d_out;

  unsigned short* xnh = (unsigned short*)d_ws;                      // MQ*CDIM bf16
  float* zx  = (float*)(xnh + (size_t)MQ*CDIM);                     // MQ*DIP f32
  float* xc  = zx  + (size_t)MQ*DIP;                                // MQ*CONVD f32
  float* dtb = xc  + (size_t)MQ*CONVD;                              // MQ*NH
  float* cs  = dtb + (size_t)MQ*NH;                                 // B*NH*NC*QC
  float* Dc  = cs  + (size_t)BQ*NH*NC*QC;                           // B*NH*NC
  float* Sb  = Dc  + (size_t)BQ*NH*NC;                              // B*NC*NH*HD*DS
  float* H0  = Sb  + (size_t)BQ*NC*NH*HD*DS;
  float* yg  = H0  + (size_t)BQ*NC*NH*HD*DS;                        // MQ*DI f32
  unsigned short* w1h = (unsigned short*)(yg + (size_t)MQ*DI);      // DIP*CDIM bf16
  unsigned short* w2h = w1h + (size_t)DIP*CDIM;                     // CDIM*DI bf16
  unsigned short* ygh = (unsigned short*)xc;  // alias: xc dead after k_chunk_y

  k_f2bf<<<(DIP*CDIM + 255)/256, 256, 0, stream>>>(w1, w1h, DIP*CDIM);
  k_f2bf<<<(CDIM*DI + 255)/256, 256, 0, stream>>>(w2, w2h, CDIM*DI);
  k_seq_ln<<<MQ, 320, 0, stream>>>(x, pc, lnw, lnb, pg, pew, nap, plab, xnh);
  dim3 g1(11, 129);
  k_gemm1_mfma<<<g1, 256, 0, stream>>>(xnh, w1h, zx);
  k_dt<<<(MQ*NH + 255)/256, 256, 0, stream>>>(zx, dt_bias, dtb);
  dim3 g4(3, MQ);
  k_conv<<<g4, 256, 0, stream>>>(zx, cw, cb, xc);
  dim3 gc(NC, NH, BQ);
  k_cumsum<<<gc, QC, 0, stream>>>(dtb, A_log, cs, Dc);
  k_chunk_state<<<gc, 256, 0, stream>>>(xc, dtb, cs, Sb);
  k_state_scan<<<(BQ*NH*HD*DS)/256, 256, 0, stream>>>(Sb, Dc, H0);
  k_chunk_y<<<gc, 256, 0, stream>>>(xc, zx, dtb, cs, H0, Dp, yg);
  k_rms_scale<<<MQ, 256, 0, stream>>>(yg, rsw, ygh);
  dim3 g7(129, 3);
  k_gemm2_mfma<<<g7, 256, 0, stream>>>(w2h, ygh, out);
}

// Round 4
// 333.889 us; speedup vs baseline: 11.4922x; 1.6185x over previous
//
#include <hip/hip_runtime.h>
#include <math.h>

#define BQ 4
#define LQ 4104
#define NTQ 4096
#define CDIM 320
#define DIP 1352
#define DI 640
#define CONVD 704
#define NH 8
#define HD 80
#define DS 32
#define MQ (BQ*LQ)   // 16416
#define QC 128       // chunk length
#define NC 33        // ceil(LQ/QC)

typedef __attribute__((ext_vector_type(8))) short bf16x8;
typedef __attribute__((ext_vector_type(4))) float f32x4;

__device__ __forceinline__ unsigned short f2bf(float f){
  union { float f; unsigned u; } v; v.f = f;
  unsigned r = v.u + 0x7FFFu + ((v.u >> 16) & 1u);
  return (unsigned short)(r >> 16);
}

__device__ __forceinline__ float warp_sum(float v){
  #pragma unroll
  for (int o = 32; o; o >>= 1) v += __shfl_xor(v, o);
  return v;
}

// ---------------- K0: f32 -> bf16 bulk convert ----------------
__global__ __launch_bounds__(256) void k_f2bf(
    const float* __restrict__ s, unsigned short* __restrict__ d, int n)
{
  int i = blockIdx.x*256 + threadIdx.x;
  if (i < n) d[i] = f2bf(s[i]);
}

// ---------------- K1: build seq + LayerNorm, emit bf16 ----------------
__global__ __launch_bounds__(320) void k_seq_ln(
    const float* __restrict__ x, const float* __restrict__ pcoords,
    const float* __restrict__ lnw, const float* __restrict__ lnb,
    const float* __restrict__ pgauss, const float* __restrict__ pemb_w,
    const float* __restrict__ nap, const int* __restrict__ plabels,
    unsigned short* __restrict__ xnh)
{
  int mtok = blockIdx.x;
  int b = mtok / LQ, l = mtok % LQ;
  int c = threadIdx.x;
  float val;
  if (l < NTQ) {
    val = x[((size_t)(b*CDIM + c))*NTQ + l];
  } else {
    int j = l - NTQ;
    int f = (c < 160) ? c : c - 160;
    float p0 = pcoords[(b*8+j)*3+0]*(2.0f/16.0f) - 1.0f;
    float p1 = pcoords[(b*8+j)*3+1]*(2.0f/16.0f) - 1.0f;
    float p2 = pcoords[(b*8+j)*3+2]*(2.0f/16.0f) - 1.0f;
    float pe = 6.283185307179586f*(p0*pgauss[f] + p1*pgauss[160+f] + p2*pgauss[320+f]);
    float pv = (c < 160) ? sinf(pe) : cosf(pe);
    int lab = plabels[b*8+j];
    if (lab == -1) {
      val = nap[c];
    } else {
      int safe = lab < 0 ? 0 : (lab > 1 ? 1 : lab);
      val = pv + pemb_w[safe*CDIM + c];
    }
  }
  float s  = warp_sum(val);
  float s2 = warp_sum(val*val);
  __shared__ float r1[5], r2[5];
  int w = threadIdx.x >> 6, lane = threadIdx.x & 63;
  if (lane == 0) { r1[w] = s; r2[w] = s2; }
  __syncthreads();
  float ts = 0.f, ts2 = 0.f;
  #pragma unroll
  for (int i = 0; i < 5; i++) { ts += r1[i]; ts2 += r2[i]; }
  float mu  = ts * (1.0f/CDIM);
  float var = ts2 * (1.0f/CDIM) - mu*mu;
  float rsig = rsqrtf(var + 1e-5f);
  xnh[(size_t)mtok*CDIM + c] = f2bf((val - mu)*rsig*lnw[c] + lnb[c]);
}

// ---------------- K2: zx = xn @ w1^T via MFMA (M x 1352, K=320) ----------------
__global__ __launch_bounds__(256) void k_gemm1_mfma(
    const unsigned short* __restrict__ Abf, const unsigned short* __restrict__ Wbf,
    float* __restrict__ Cout)
{
  __shared__ unsigned short As[128][40];
  __shared__ unsigned short Bs[128][40];
  int m0 = blockIdx.y * 128;
  int n0 = blockIdx.x * 128;
  int tid = threadIdx.x;
  int lane = tid & 63, wid = tid >> 6;
  int wr = wid >> 1, wc = wid & 1;
  int fr = lane & 15, fq = lane >> 4;
  f32x4 acc[4][4] = {};
  for (int k0 = 0; k0 < CDIM; k0 += 32) {
    #pragma unroll
    for (int rnd = 0; rnd < 2; rnd++) {
      int idx = tid + rnd*256;
      int row = idx >> 2, slot = idx & 3;
      uint4 va = make_uint4(0,0,0,0);
      if (m0 + row < MQ) va = *(const uint4*)(Abf + (size_t)(m0+row)*CDIM + k0 + slot*8);
      *(uint4*)&As[row][slot*8] = va;
      uint4 vb = make_uint4(0,0,0,0);
      if (n0 + row < DIP) vb = *(const uint4*)(Wbf + (size_t)(n0+row)*CDIM + k0 + slot*8);
      *(uint4*)&Bs[row][slot*8] = vb;
    }
    __syncthreads();
    bf16x8 fa[4], fb[4];
    #pragma unroll
    for (int i = 0; i < 4; i++) {
      fa[i] = *(const bf16x8*)&As[wr*64 + i*16 + fr][fq*8];
      fb[i] = *(const bf16x8*)&Bs[wc*64 + i*16 + fr][fq*8];
    }
    #pragma unroll
    for (int i = 0; i < 4; i++)
      #pragma unroll
      for (int j = 0; j < 4; j++)
        acc[i][j] = __builtin_amdgcn_mfma_f32_16x16x32_bf16(fa[i], fb[j], acc[i][j], 0, 0, 0);
    __syncthreads();
  }
  #pragma unroll
  for (int i = 0; i < 4; i++) {
    #pragma unroll
    for (int j = 0; j < 4; j++) {
      #pragma unroll
      for (int r = 0; r < 4; r++) {
        int grow = m0 + wr*64 + i*16 + fq*4 + r;
        int gcol = n0 + wc*64 + j*16 + fr;
        if (grow < MQ && gcol < DIP) Cout[(size_t)grow*DIP + gcol] = acc[i][j][r];
      }
    }
  }
}

// ---------------- K3: dt = softplus(dt_raw + bias) ----------------
__global__ __launch_bounds__(256) void k_dt(
    const float* __restrict__ zx, const float* __restrict__ dt_bias,
    float* __restrict__ dtb)
{
  int i = blockIdx.x*256 + threadIdx.x;
  if (i >= MQ*NH) return;
  int m = i >> 3, h = i & 7;
  float v = zx[(size_t)m*DIP + (DI + CONVD) + h] + dt_bias[h];
  float sp = (v > 20.f) ? v : log1pf(expf(v));
  dtb[i] = sp;
}

// ---------------- K4: depthwise causal conv(4) + bias + SiLU ----------------
__global__ __launch_bounds__(256) void k_conv(
    const float* __restrict__ zx, const float* __restrict__ cw,
    const float* __restrict__ cb, float* __restrict__ xc)
{
  int c = blockIdx.x*256 + threadIdx.x;
  if (c >= CONVD) return;
  int m = blockIdx.y;
  int l = m % LQ;
  float acc = cb[c];
  #pragma unroll
  for (int j = 0; j < 4; j++) {
    int ls = l - 3 + j;
    if (ls >= 0) acc = fmaf(zx[(size_t)(m-3+j)*DIP + DI + c], cw[c*4+j], acc);
  }
  float sv = acc / (1.f + expf(-acc));
  xc[(size_t)m*CONVD + c] = sv;
}

// ---------------- K5a: per-chunk inclusive cumsum of dt*A ----------------
__global__ __launch_bounds__(QC) void k_cumsum(
    const float* __restrict__ dtb, const float* __restrict__ A_log,
    float* __restrict__ cs, float* __restrict__ Dc)
{
  int c = blockIdx.x, h = blockIdx.y, b = blockIdx.z;
  int l = threadIdx.x;
  int gl = c*QC + l;
  int len = LQ - c*QC; if (len > QC) len = QC;
  float A = -expf(A_log[h]);
  float a = (gl < LQ) ? dtb[((size_t)(b*LQ+gl))*NH + h] * A : 0.f;
  __shared__ float sm[QC];
  sm[l] = a;
  __syncthreads();
  for (int off = 1; off < QC; off <<= 1) {
    float v = (l >= off) ? sm[l-off] : 0.f;
    __syncthreads();
    sm[l] += v;
    __syncthreads();
  }
  cs[((size_t)(b*NH+h)*NC + c)*QC + l] = sm[l];
  if (l == len-1) Dc[(b*NH+h)*NC + c] = expf(sm[l]);
}

// ---------------- K5b: per-chunk end-state S = sum_i w_i * x_i (x) B_i ----------------
__global__ __launch_bounds__(256) void k_chunk_state(
    const float* __restrict__ xc, const float* __restrict__ dtb,
    const float* __restrict__ cs, float* __restrict__ Sbuf)
{
  int c = blockIdx.x, h = blockIdx.y, b = blockIdx.z;
  int len = LQ - c*QC; if (len > QC) len = QC;
  int t = threadIdx.x;
  int m0 = b*LQ + c*QC;
  __shared__ float Xs[QC][HD+1];
  __shared__ float Bs[QC][DS+1];
  __shared__ float ws[QC];
  const float* csb = cs + ((size_t)(b*NH+h)*NC + c)*QC;
  float s_end = csb[len-1];
  for (int idx = t; idx < len*HD; idx += 256) {
    int i = idx / HD, p = idx % HD;
    Xs[i][p] = xc[((size_t)(m0+i))*CONVD + h*HD + p];
  }
  for (int idx = t; idx < len*DS; idx += 256) {
    int i = idx >> 5, n = idx & 31;
    Bs[i][n] = xc[((size_t)(m0+i))*CONVD + DI + n];
  }
  if (t < len) ws[t] = expf(s_end - csb[t]) * dtb[((size_t)(m0+t))*NH + h];
  __syncthreads();
  int n = t & 31, pb = t >> 5;
  float acc[10] = {};
  for (int i = 0; i < len; i++) {
    float bw = ws[i] * Bs[i][n];
    #pragma unroll
    for (int k = 0; k < 10; k++) acc[k] = fmaf(bw, Xs[i][pb + 8*k], acc[k]);
  }
  size_t base = ((size_t)(b*NC + c)*NH + h)*(HD*DS);
  #pragma unroll
  for (int k = 0; k < 10; k++) Sbuf[base + (size_t)(pb + 8*k)*DS + n] = acc[k];
}

// ---------------- K5c: tiny sequential scan over chunk states ----------------
__global__ __launch_bounds__(256) void k_state_scan(
    const float* __restrict__ Sbuf, const float* __restrict__ Dc,
    float* __restrict__ H0)
{
  int tid = blockIdx.x*256 + threadIdx.x;
  int pn = tid % (HD*DS);
  int bh = tid / (HD*DS);
  int b = bh >> 3, h = bh & 7;
  float hst = 0.f;
  for (int c = 0; c < NC; c++) {
    size_t idx = ((size_t)(b*NC + c)*NH + h)*(HD*DS) + pn;
    H0[idx] = hst;
    hst = hst * Dc[bh*NC + c] + Sbuf[idx];
  }
}

// ---------------- K5d: per-chunk outputs via MFMA: inter + intra, Dp skip, z-gate ----------------
__global__ __launch_bounds__(256) void k_chunk_y_mfma(
    const float* __restrict__ xc, const float* __restrict__ zx,
    const float* __restrict__ dtb, const float* __restrict__ cs,
    const float* __restrict__ H0, const float* __restrict__ Dp,
    float* __restrict__ yg)
{
  int c = blockIdx.x, h = blockIdx.y, b = blockIdx.z;
  int len = LQ - c*QC; if (len > QC) len = QC;
  int t = threadIdx.x;
  int lane = t & 63, wid = t >> 6;
  int fr = lane & 15, fq = lane >> 4;
  int m0 = b*LQ + c*QC;

  __shared__ unsigned short Cls[QC][40];   // C rows (bf16), cols 0..31
  __shared__ unsigned short Bls[QC][40];   // B rows (bf16)
  __shared__ unsigned short XT[HD][136];   // X^T: [p][token]
  __shared__ unsigned short H0s[HD][40];   // H0 rows p, cols n
  __shared__ unsigned short Ws[QC][40];    // decay-weight sub-tile (cols = 32 tokens)
  __shared__ float slA[QC], dtlA[QC], elA[QC];

  const float* csb = cs + ((size_t)(b*NH+h)*NC + c)*QC;

  for (int idx = t; idx < QC*DS; idx += 256) {
    int i = idx >> 5, n = idx & 31;
    float cv = 0.f, bv = 0.f;
    if (i < len) {
      const float* rowp = xc + (size_t)(m0+i)*CONVD;
      cv = rowp[DI + DS + n];
      bv = rowp[DI + n];
    }
    Cls[i][n] = f2bf(cv);
    Bls[i][n] = f2bf(bv);
  }
  for (int idx = t; idx < HD*QC; idx += 256) {
    int p = idx % HD, i = idx / HD;
    float v = (i < len) ? xc[(size_t)(m0+i)*CONVD + h*HD + p] : 0.f;
    XT[p][i] = f2bf(v);
  }
  {
    size_t hb = ((size_t)(b*NC + c)*NH + h)*(HD*DS);
    for (int idx = t; idx < HD*DS; idx += 256)
      H0s[idx >> 5][idx & 31] = f2bf(H0[hb + idx]);
  }
  if (t < QC) {
    float s = csb[t];
    slA[t] = s;
    elA[t] = expf(s);
    dtlA[t] = (c*QC + t < LQ) ? dtb[((size_t)(m0+t))*NH + h] : 0.f;
  }
  __syncthreads();

  // C A-fragments for this wave's 32 rows (reused for inter and all G sub-tiles)
  bf16x8 fa[2];
  #pragma unroll
  for (int it = 0; it < 2; it++)
    fa[it] = *(const bf16x8*)&Cls[wid*32 + it*16 + fr][fq*8];

  // inter-chunk term: acc = C @ H0^T, then scale row l by exp(s_l)
  f32x4 acc[2][5];
  #pragma unroll
  for (int it = 0; it < 2; it++) {
    #pragma unroll
    for (int j = 0; j < 5; j++) {
      bf16x8 fb = *(const bf16x8*)&H0s[j*16 + fr][fq*8];
      f32x4 z = {};
      acc[it][j] = __builtin_amdgcn_mfma_f32_16x16x32_bf16(fa[it], fb, z, 0, 0, 0);
    }
  }
  #pragma unroll
  for (int it = 0; it < 2; it++)
    #pragma unroll
    for (int r = 0; r < 4; r++) {
      float el = elA[wid*32 + it*16 + fq*4 + r];
      #pragma unroll
      for (int j = 0; j < 5; j++) acc[it][j][r] *= el;
    }

  // intra-chunk: 4 sub-tiles of 32 tokens
  for (int sc = 0; sc < 4; sc++) {
    int i0 = sc*32;
    // G = C @ Bsub^T -> mask * exp(s_l - s_i) * dt_i -> Ws (bf16)
    #pragma unroll
    for (int it = 0; it < 2; it++) {
      #pragma unroll
      for (int jt = 0; jt < 2; jt++) {
        bf16x8 fb = *(const bf16x8*)&Bls[i0 + jt*16 + fr][fq*8];
        f32x4 z = {};
        f32x4 g = __builtin_amdgcn_mfma_f32_16x16x32_bf16(fa[it], fb, z, 0, 0, 0);
        int col = i0 + jt*16 + fr;
        float sc_col = slA[col], dt_col = dtlA[col];
        #pragma unroll
        for (int r = 0; r < 4; r++) {
          int row = wid*32 + it*16 + fq*4 + r;
          float v = 0.f;
          if (col <= row)
            v = g[r] * expf(slA[row] - sc_col) * dt_col;
          Ws[row][jt*16 + fr] = f2bf(v);
        }
      }
    }
    __syncthreads();
    // acc += Ws @ Xsub (K=32)
    #pragma unroll
    for (int it = 0; it < 2; it++) {
      bf16x8 wa = *(const bf16x8*)&Ws[wid*32 + it*16 + fr][fq*8];
      #pragma unroll
      for (int j = 0; j < 5; j++) {
        bf16x8 xb = *(const bf16x8*)&XT[j*16 + fr][i0 + fq*8];
        acc[it][j] = __builtin_amdgcn_mfma_f32_16x16x32_bf16(wa, xb, acc[it][j], 0, 0, 0);
      }
    }
    __syncthreads();
  }

  // epilogue: Dp skip + z-gate, store yg
  float dpv = Dp[h];
  #pragma unroll
  for (int it = 0; it < 2; it++) {
    #pragma unroll
    for (int r = 0; r < 4; r++) {
      int l = wid*32 + it*16 + fq*4 + r;
      if (l >= len) continue;
      size_t m = m0 + l;
      #pragma unroll
      for (int j = 0; j < 5; j++) {
        int cc = h*HD + j*16 + fr;
        float xv = xc[m*CONVD + cc];
        float y = acc[it][j][r] + xv*dpv;
        float zv = zx[m*DIP + cc];
        y *= zv / (1.f + expf(-zv));
        yg[m*DI + cc] = y;
      }
    }
  }
}

// ---------------- K6: RMS + scale, emit bf16 A for GEMM2 ----------------
__global__ __launch_bounds__(256) void k_rms_scale(
    const float* __restrict__ yg, const float* __restrict__ rsw,
    unsigned short* __restrict__ ygh)
{
  int m = blockIdx.x;
  int t = threadIdx.x;
  const float* row = yg + (size_t)m*DI;
  float v0 = row[t];
  float v1 = row[t+256];
  float v2 = (t < 128) ? row[t+512] : 0.f;
  float ss = v0*v0 + v1*v1 + v2*v2;
  ss = warp_sum(ss);
  __shared__ float r[4];
  int w = t >> 6, lane = t & 63;
  if (lane == 0) r[w] = ss;
  __syncthreads();
  float tot = r[0] + r[1] + r[2] + r[3];
  float rsv = rsqrtf(tot*(1.0f/DI) + 1e-5f);
  ygh[(size_t)m*DI + t]       = f2bf(v0 * rsv * rsw[t]);
  ygh[(size_t)m*DI + t + 256] = f2bf(v1 * rsv * rsw[t+256]);
  if (t < 128)
    ygh[(size_t)m*DI + t + 512] = f2bf(v2 * rsv * rsw[t+512]);
}

// ---------------- K7: out^T = w2 @ ygh^T via MFMA, coalesced transposed store ----------------
__global__ __launch_bounds__(256) void k_gemm2_mfma(
    const unsigned short* __restrict__ W2h, const unsigned short* __restrict__ Ygh,
    float* __restrict__ out)
{
  __shared__ unsigned short As[128][40];
  __shared__ unsigned short Bs[128][40];
  int c0 = blockIdx.y * 128;   // out channel tile (over 320)
  int t0 = blockIdx.x * 128;   // token tile (over MQ)
  int tid = threadIdx.x;
  int lane = tid & 63, wid = tid >> 6;
  int wr = wid >> 1, wc = wid & 1;
  int fr = lane & 15, fq = lane >> 4;
  f32x4 acc[4][4] = {};
  for (int k0 = 0; k0 < DI; k0 += 32) {
    #pragma unroll
    for (int rnd = 0; rnd < 2; rnd++) {
      int idx = tid + rnd*256;
      int row = idx >> 2, slot = idx & 3;
      uint4 va = make_uint4(0,0,0,0);
      if (c0 + row < CDIM) va = *(const uint4*)(W2h + (size_t)(c0+row)*DI + k0 + slot*8);
      *(uint4*)&As[row][slot*8] = va;
      uint4 vb = make_uint4(0,0,0,0);
      if (t0 + row < MQ) vb = *(const uint4*)(Ygh + (size_t)(t0+row)*DI + k0 + slot*8);
      *(uint4*)&Bs[row][slot*8] = vb;
    }
    __syncthreads();
    bf16x8 fa[4], fb[4];
    #pragma unroll
    for (int i = 0; i < 4; i++) {
      fa[i] = *(const bf16x8*)&As[wr*64 + i*16 + fr][fq*8];
      fb[i] = *(const bf16x8*)&Bs[wc*64 + i*16 + fr][fq*8];
    }
    #pragma unroll
    for (int i = 0; i < 4; i++)
      #pragma unroll
      for (int j = 0; j < 4; j++)
        acc[i][j] = __builtin_amdgcn_mfma_f32_16x16x32_bf16(fa[i], fb[j], acc[i][j], 0, 0, 0);
    __syncthreads();
  }
  #pragma unroll
  for (int i = 0; i < 4; i++) {
    #pragma unroll
    for (int j = 0; j < 4; j++) {
      #pragma unroll
      for (int r = 0; r < 4; r++) {
        int ch  = c0 + wr*64 + i*16 + fq*4 + r;
        int tok = t0 + wc*64 + j*16 + fr;
        if (ch < CDIM && tok < MQ) {
          int b = tok / LQ, l = tok % LQ;
          if (l < NTQ)
            out[((size_t)(b*CDIM + ch))*NTQ + l] = acc[i][j][r];
        }
      }
    }
  }
}

extern "C" void kernel_launch(void* const* d_in, const int* in_sizes, int n_in,
                              void* d_out, int out_size, void* d_ws, size_t ws_size,
                              hipStream_t stream)
{
  const float* x       = (const float*)d_in[0];
  const float* pc      = (const float*)d_in[1];
  const float* lnw     = (const float*)d_in[2];
  const float* lnb     = (const float*)d_in[3];
  const float* w1      = (const float*)d_in[4];
  const float* cw      = (const float*)d_in[5];
  const float* cb      = (const float*)d_in[6];
  const float* dt_bias = (const float*)d_in[7];
  const float* A_log   = (const float*)d_in[8];
  const float* Dp      = (const float*)d_in[9];
  const float* rsw     = (const float*)d_in[10];
  const float* w2      = (const float*)d_in[11];
  const float* pg      = (const float*)d_in[12];
  const float* pew     = (const float*)d_in[13];
  const float* nap     = (const float*)d_in[14];
  const int*   plab    = (const int*)d_in[15];
  float* out = (float*)d_out;

  unsigned short* xnh = (unsigned short*)d_ws;                      // MQ*CDIM bf16
  float* zx  = (float*)(xnh + (size_t)MQ*CDIM);                     // MQ*DIP f32
  float* xc  = zx  + (size_t)MQ*DIP;                                // MQ*CONVD f32
  float* dtb = xc  + (size_t)MQ*CONVD;                              // MQ*NH
  float* cs  = dtb + (size_t)MQ*NH;                                 // B*NH*NC*QC
  float* Dc  = cs  + (size_t)BQ*NH*NC*QC;                           // B*NH*NC
  float* Sb  = Dc  + (size_t)BQ*NH*NC;                              // B*NC*NH*HD*DS
  float* H0  = Sb  + (size_t)BQ*NC*NH*HD*DS;
  float* yg  = H0  + (size_t)BQ*NC*NH*HD*DS;                        // MQ*DI f32
  unsigned short* w1h = (unsigned short*)(yg + (size_t)MQ*DI);      // DIP*CDIM bf16
  unsigned short* w2h = w1h + (size_t)DIP*CDIM;                     // CDIM*DI bf16
  unsigned short* ygh = (unsigned short*)xc;  // alias: xc dead after k_chunk_y

  k_f2bf<<<(DIP*CDIM + 255)/256, 256, 0, stream>>>(w1, w1h, DIP*CDIM);
  k_f2bf<<<(CDIM*DI + 255)/256, 256, 0, stream>>>(w2, w2h, CDIM*DI);
  k_seq_ln<<<MQ, 320, 0, stream>>>(x, pc, lnw, lnb, pg, pew, nap, plab, xnh);
  dim3 g1(11, 129);
  k_gemm1_mfma<<<g1, 256, 0, stream>>>(xnh, w1h, zx);
  k_dt<<<(MQ*NH + 255)/256, 256, 0, stream>>>(zx, dt_bias, dtb);
  dim3 g4(3, MQ);
  k_conv<<<g4, 256, 0, stream>>>(zx, cw, cb, xc);
  dim3 gc(NC, NH, BQ);
  k_cumsum<<<gc, QC, 0, stream>>>(dtb, A_log, cs, Dc);
  k_chunk_state<<<gc, 256, 0, stream>>>(xc, dtb, cs, Sb);
  k_state_scan<<<(BQ*NH*HD*DS)/256, 256, 0, stream>>>(Sb, Dc, H0);
  k_chunk_y_mfma<<<gc, 256, 0, stream>>>(xc, zx, dtb, cs, H0, Dp, yg);
  k_rms_scale<<<MQ, 256, 0, stream>>>(yg, rsw, ygh);
  dim3 g7(129, 3);
  k_gemm2_mfma<<<g7, 256, 0, stream>>>(w2h, ygh, out);
}

// Round 5
// 293.184 us; speedup vs baseline: 13.0878x; 1.1388x over previous
//
#include <hip/hip_runtime.h>
#include <math.h>

#define BQ 4
#define LQ 4104
#define NTQ 4096
#define CDIM 320
#define DIP 1352
#define DI 640
#define CONVD 704
#define NH 8
#define HD 80
#define DS 32
#define MQ (BQ*LQ)   // 16416
#define QC 128       // chunk length
#define NC 33        // ceil(LQ/QC)

typedef __attribute__((ext_vector_type(8))) short bf16x8;
typedef __attribute__((ext_vector_type(4))) float f32x4;

__device__ __forceinline__ unsigned short f2bf(float f){
  union { float f; unsigned u; } v; v.f = f;
  unsigned r = v.u + 0x7FFFu + ((v.u >> 16) & 1u);
  return (unsigned short)(r >> 16);
}
__device__ __forceinline__ float bf2f(unsigned short u){
  union { unsigned u; float f; } v; v.u = ((unsigned)u) << 16;
  return v.f;
}
__device__ __forceinline__ float warp_sum(float v){
  #pragma unroll
  for (int o = 32; o; o >>= 1) v += __shfl_xor(v, o);
  return v;
}

// ---------------- K0: f32 -> bf16 bulk convert ----------------
__global__ __launch_bounds__(256) void k_f2bf(
    const float* __restrict__ s, unsigned short* __restrict__ d, int n)
{
  int i = blockIdx.x*256 + threadIdx.x;
  if (i < n) d[i] = f2bf(s[i]);
}

// ---------------- K1a: image tokens LayerNorm, coalesced, emit bf16 ----------------
__global__ __launch_bounds__(256) void k_img_ln(
    const float* __restrict__ x, const float* __restrict__ lnw,
    const float* __restrict__ lnb, unsigned short* __restrict__ xnh)
{
  int b = blockIdx.y;
  int l0 = blockIdx.x * 64;
  int t = threadIdx.x;
  int lt = t & 63, cq = t >> 6;      // 4 channel-lanes x 64 tokens
  const float* xb = x + ((size_t)b*CDIM)*NTQ;

  float s = 0.f, s2 = 0.f;
  for (int c = cq; c < CDIM; c += 4) {
    float v = xb[(size_t)c*NTQ + l0 + lt];
    s += v; s2 = fmaf(v, v, s2);
  }
  __shared__ float sA[4][64], s2A[4][64];
  sA[cq][lt] = s; s2A[cq][lt] = s2;
  __syncthreads();
  float ts  = sA[0][lt]+sA[1][lt]+sA[2][lt]+sA[3][lt];
  float ts2 = s2A[0][lt]+s2A[1][lt]+s2A[2][lt]+s2A[3][lt];
  float mu   = ts*(1.0f/CDIM);
  float rsig = rsqrtf(ts2*(1.0f/CDIM) - mu*mu + 1e-5f);

  __shared__ unsigned T32[64][34];   // [token][channel-pair], 2 bf16 per uint
  for (int cc = 0; cc < 10; cc++) {  // 32-channel groups
    #pragma unroll
    for (int it = 0; it < 4; it++) {
      int pairI = cq*4 + it;
      int c = cc*32 + pairI*2;
      float v0 = xb[(size_t)c*NTQ + l0 + lt];
      float v1 = xb[(size_t)(c+1)*NTQ + l0 + lt];
      unsigned u0 = f2bf((v0 - mu)*rsig*lnw[c]   + lnb[c]);
      unsigned u1 = f2bf((v1 - mu)*rsig*lnw[c+1] + lnb[c+1]);
      T32[lt][pairI] = u0 | (u1 << 16);
    }
    __syncthreads();
    #pragma unroll
    for (int it2 = 0; it2 < 2; it2++) {
      int idx = t + 256*it2;
      int row = idx >> 3, slot = idx & 7;
      *(uint2*)&xnh[((size_t)(b*LQ) + l0 + row)*CDIM + cc*32 + slot*4] =
          *(const uint2*)&T32[row][slot*2];
    }
    __syncthreads();
  }
}

// ---------------- K1b: point tokens + LayerNorm ----------------
__global__ __launch_bounds__(320) void k_pt_ln(
    const float* __restrict__ pcoords, const float* __restrict__ lnw,
    const float* __restrict__ lnb, const float* __restrict__ pgauss,
    const float* __restrict__ pemb_w, const float* __restrict__ nap,
    const int* __restrict__ plabels, unsigned short* __restrict__ xnh)
{
  int j = blockIdx.x, b = blockIdx.y;
  int c = threadIdx.x;
  int f = (c < 160) ? c : c - 160;
  float p0 = pcoords[(b*8+j)*3+0]*(2.0f/16.0f) - 1.0f;
  float p1 = pcoords[(b*8+j)*3+1]*(2.0f/16.0f) - 1.0f;
  float p2 = pcoords[(b*8+j)*3+2]*(2.0f/16.0f) - 1.0f;
  float pe = 6.283185307179586f*(p0*pgauss[f] + p1*pgauss[160+f] + p2*pgauss[320+f]);
  float pv = (c < 160) ? sinf(pe) : cosf(pe);
  int lab = plabels[b*8+j];
  float val;
  if (lab == -1) val = nap[c];
  else {
    int safe = lab < 0 ? 0 : (lab > 1 ? 1 : lab);
    val = pv + pemb_w[safe*CDIM + c];
  }
  float s  = warp_sum(val);
  float s2 = warp_sum(val*val);
  __shared__ float r1[5], r2[5];
  int w = threadIdx.x >> 6, lane = threadIdx.x & 63;
  if (lane == 0) { r1[w] = s; r2[w] = s2; }
  __syncthreads();
  float ts = 0.f, ts2 = 0.f;
  #pragma unroll
  for (int i = 0; i < 5; i++) { ts += r1[i]; ts2 += r2[i]; }
  float mu  = ts * (1.0f/CDIM);
  float var = ts2 * (1.0f/CDIM) - mu*mu;
  float rsig = rsqrtf(var + 1e-5f);
  xnh[((size_t)b*LQ + NTQ + j)*CDIM + c] = f2bf((val - mu)*rsig*lnw[c] + lnb[c]);
}

// ---------------- K2: zx = xn @ w1^T via MFMA (M x 1352, K=320) ----------------
__global__ __launch_bounds__(256) void k_gemm1_mfma(
    const unsigned short* __restrict__ Abf, const unsigned short* __restrict__ Wbf,
    float* __restrict__ Cout)
{
  __shared__ unsigned short As[128][40];
  __shared__ unsigned short Bs[128][40];
  int m0 = blockIdx.y * 128;
  int n0 = blockIdx.x * 128;
  int tid = threadIdx.x;
  int lane = tid & 63, wid = tid >> 6;
  int wr = wid >> 1, wc = wid & 1;
  int fr = lane & 15, fq = lane >> 4;
  f32x4 acc[4][4] = {};
  for (int k0 = 0; k0 < CDIM; k0 += 32) {
    #pragma unroll
    for (int rnd = 0; rnd < 2; rnd++) {
      int idx = tid + rnd*256;
      int row = idx >> 2, slot = idx & 3;
      uint4 va = make_uint4(0,0,0,0);
      if (m0 + row < MQ) va = *(const uint4*)(Abf + (size_t)(m0+row)*CDIM + k0 + slot*8);
      *(uint4*)&As[row][slot*8] = va;
      uint4 vb = make_uint4(0,0,0,0);
      if (n0 + row < DIP) vb = *(const uint4*)(Wbf + (size_t)(n0+row)*CDIM + k0 + slot*8);
      *(uint4*)&Bs[row][slot*8] = vb;
    }
    __syncthreads();
    bf16x8 fa[4], fb[4];
    #pragma unroll
    for (int i = 0; i < 4; i++) {
      fa[i] = *(const bf16x8*)&As[wr*64 + i*16 + fr][fq*8];
      fb[i] = *(const bf16x8*)&Bs[wc*64 + i*16 + fr][fq*8];
    }
    #pragma unroll
    for (int i = 0; i < 4; i++)
      #pragma unroll
      for (int j = 0; j < 4; j++)
        acc[i][j] = __builtin_amdgcn_mfma_f32_16x16x32_bf16(fa[i], fb[j], acc[i][j], 0, 0, 0);
    __syncthreads();
  }
  #pragma unroll
  for (int i = 0; i < 4; i++) {
    #pragma unroll
    for (int j = 0; j < 4; j++) {
      #pragma unroll
      for (int r = 0; r < 4; r++) {
        int grow = m0 + wr*64 + i*16 + fq*4 + r;
        int gcol = n0 + wc*64 + j*16 + fr;
        if (grow < MQ && gcol < DIP) Cout[(size_t)grow*DIP + gcol] = acc[i][j][r];
      }
    }
  }
}

// ---------------- K4: depthwise causal conv(4) + bias + SiLU -> bf16 ----------------
__global__ __launch_bounds__(256) void k_conv(
    const float* __restrict__ zx, const float* __restrict__ cw,
    const float* __restrict__ cb, unsigned short* __restrict__ xcb)
{
  int c = blockIdx.x*256 + threadIdx.x;
  if (c >= CONVD) return;
  int m = blockIdx.y;
  int l = m % LQ;
  float acc = cb[c];
  #pragma unroll
  for (int j = 0; j < 4; j++) {
    int ls = l - 3 + j;
    if (ls >= 0) acc = fmaf(zx[(size_t)(m-3+j)*DIP + DI + c], cw[c*4+j], acc);
  }
  float sv = acc / (1.f + expf(-acc));
  xcb[(size_t)m*CONVD + c] = f2bf(sv);
}

// ---------------- K5a: softplus(dt)+cumsum(dt*A) fused ----------------
__global__ __launch_bounds__(QC) void k_cumsum(
    const float* __restrict__ zx, const float* __restrict__ dt_bias,
    const float* __restrict__ A_log, float* __restrict__ dtb,
    float* __restrict__ cs, float* __restrict__ Dc)
{
  int c = blockIdx.x, h = blockIdx.y, b = blockIdx.z;
  int l = threadIdx.x;
  int gl = c*QC + l;
  int len = LQ - c*QC; if (len > QC) len = QC;
  float A = -expf(A_log[h]);
  float a = 0.f;
  if (gl < LQ) {
    float v = zx[((size_t)(b*LQ+gl))*DIP + (DI + CONVD) + h] + dt_bias[h];
    float sp = (v > 20.f) ? v : log1pf(expf(v));
    dtb[((size_t)(b*LQ+gl))*NH + h] = sp;
    a = sp * A;
  }
  __shared__ float sm[QC];
  sm[l] = a;
  __syncthreads();
  for (int off = 1; off < QC; off <<= 1) {
    float v = (l >= off) ? sm[l-off] : 0.f;
    __syncthreads();
    sm[l] += v;
    __syncthreads();
  }
  cs[((size_t)(b*NH+h)*NC + c)*QC + l] = sm[l];
  if (l == len-1) Dc[(b*NH+h)*NC + c] = expf(sm[l]);
}

// ---------------- K5b: chunk end-state via MFMA: S[p][n] = sum_i X[i][p]*(w_i B[i][n]) ----------------
__global__ __launch_bounds__(256) void k_chunk_state_mfma(
    const unsigned short* __restrict__ xcb, const float* __restrict__ dtb,
    const float* __restrict__ cs, float* __restrict__ Sbuf)
{
  int c = blockIdx.x, h = blockIdx.y, b = blockIdx.z;
  int len = LQ - c*QC; if (len > QC) len = QC;
  int t = threadIdx.x;
  int lane = t & 63, wid = t >> 6;
  int fr = lane & 15, fq = lane >> 4;
  int m0 = b*LQ + c*QC;

  __shared__ unsigned short XT[HD][136];
  __shared__ unsigned short BwT[DS][136];
  __shared__ float ws[QC];
  const float* csb = cs + ((size_t)(b*NH+h)*NC + c)*QC;

  for (int idx = t; idx < HD*QC; idx += 256) {
    int p = idx % HD, i = idx / HD;
    XT[p][i] = (i < len) ? xcb[(size_t)(m0+i)*CONVD + h*HD + p] : (unsigned short)0;
  }
  if (t < QC) {
    float s_end = csb[len-1];
    ws[t] = (t < len) ? __expf(s_end - csb[t]) * dtb[((size_t)(m0+t))*NH + h] : 0.f;
  }
  __syncthreads();
  for (int idx = t; idx < DS*QC; idx += 256) {
    int i = idx >> 5, n = idx & 31;
    float v = (i < len) ? bf2f(xcb[(size_t)(m0+i)*CONVD + DI + n]) * ws[i] : 0.f;
    BwT[n][i] = f2bf(v);
  }
  __syncthreads();

  size_t base = ((size_t)(b*NC + c)*NH + h)*(HD*DS);
  for (int tp = wid; tp < 10; tp += 4) {
    int pi = tp >> 1, ni = tp & 1;
    f32x4 acc = {};
    #pragma unroll
    for (int ks = 0; ks < 4; ks++) {
      bf16x8 fa = *(const bf16x8*)&XT[pi*16 + fr][ks*32 + fq*8];
      bf16x8 fb = *(const bf16x8*)&BwT[ni*16 + fr][ks*32 + fq*8];
      acc = __builtin_amdgcn_mfma_f32_16x16x32_bf16(fa, fb, acc, 0, 0, 0);
    }
    #pragma unroll
    for (int r = 0; r < 4; r++)
      Sbuf[base + (size_t)(pi*16 + fq*4 + r)*DS + ni*16 + fr] = acc[r];
  }
}

// ---------------- K5c: sequential scan over chunk states (in-place: H0 == Sbuf ok) ----------------
__global__ __launch_bounds__(256) void k_state_scan(
    float* __restrict__ Sbuf, const float* __restrict__ Dc,
    float* __restrict__ H0)
{
  int tid = blockIdx.x*256 + threadIdx.x;
  int pn = tid % (HD*DS);
  int bh = tid / (HD*DS);
  int b = bh >> 3, h = bh & 7;
  float hst = 0.f;
  for (int c = 0; c < NC; c++) {
    size_t idx = ((size_t)(b*NC + c)*NH + h)*(HD*DS) + pn;
    float sv = Sbuf[idx];
    H0[idx] = hst;
    hst = hst * Dc[bh*NC + c] + sv;
  }
}

// ---------------- K5d: per-chunk outputs via MFMA ----------------
__global__ __launch_bounds__(256) void k_chunk_y_mfma(
    const unsigned short* __restrict__ xcb, const float* __restrict__ zx,
    const float* __restrict__ dtb, const float* __restrict__ cs,
    const float* __restrict__ H0, const float* __restrict__ Dp,
    float* __restrict__ yg)
{
  int c = blockIdx.x, h = blockIdx.y, b = blockIdx.z;
  int len = LQ - c*QC; if (len > QC) len = QC;
  int t = threadIdx.x;
  int lane = t & 63, wid = t >> 6;
  int fr = lane & 15, fq = lane >> 4;
  int m0 = b*LQ + c*QC;

  __shared__ unsigned short CW[QC][40];    // C rows; reused as decay-weight tile
  __shared__ unsigned short Bls[QC][40];
  __shared__ unsigned short XT[HD][136];
  __shared__ unsigned short H0s[HD][40];
  __shared__ float slA[QC], dtlA[QC], elA[QC];

  const float* csb = cs + ((size_t)(b*NH+h)*NC + c)*QC;

  for (int idx = t; idx < QC*DS; idx += 256) {
    int i = idx >> 5, n = idx & 31;
    unsigned short cv = 0, bv = 0;
    if (i < len) {
      const unsigned short* rp = xcb + (size_t)(m0+i)*CONVD;
      cv = rp[DI + DS + n];
      bv = rp[DI + n];
    }
    CW[i][n] = cv;
    Bls[i][n] = bv;
  }
  for (int idx = t; idx < HD*QC; idx += 256) {
    int p = idx % HD, i = idx / HD;
    XT[p][i] = (i < len) ? xcb[(size_t)(m0+i)*CONVD + h*HD + p] : (unsigned short)0;
  }
  {
    size_t hb = ((size_t)(b*NC + c)*NH + h)*(HD*DS);
    for (int idx = t; idx < HD*DS; idx += 256)
      H0s[idx >> 5][idx & 31] = f2bf(H0[hb + idx]);
  }
  if (t < QC) {
    float s = csb[t];
    slA[t] = s;
    elA[t] = __expf(s);
    dtlA[t] = (c*QC + t < LQ) ? dtb[((size_t)(m0+t))*NH + h] : 0.f;
  }
  __syncthreads();   // the only barrier

  // A-fragments of C for this wave's 32 output rows
  bf16x8 fa[2];
  #pragma unroll
  for (int it = 0; it < 2; it++)
    fa[it] = *(const bf16x8*)&CW[wid*32 + it*16 + fr][fq*8];

  // inter-chunk term: C @ H0^T scaled by exp(s_l)
  f32x4 acc[2][5];
  #pragma unroll
  for (int it = 0; it < 2; it++) {
    #pragma unroll
    for (int j = 0; j < 5; j++) {
      bf16x8 fb = *(const bf16x8*)&H0s[j*16 + fr][fq*8];
      f32x4 z = {};
      acc[it][j] = __builtin_amdgcn_mfma_f32_16x16x32_bf16(fa[it], fb, z, 0, 0, 0);
    }
  }
  #pragma unroll
  for (int it = 0; it < 2; it++)
    #pragma unroll
    for (int r = 0; r < 4; r++) {
      float el = elA[wid*32 + it*16 + fq*4 + r];
      #pragma unroll
      for (int j = 0; j < 5; j++) acc[it][j][r] *= el;
    }

  // intra-chunk: 4 sub-tiles of 32 tokens; wave-private rows of CW (no barriers needed)
  for (int sc = 0; sc < 4; sc++) {
    int i0 = sc*32;
    #pragma unroll
    for (int it = 0; it < 2; it++) {
      #pragma unroll
      for (int jt = 0; jt < 2; jt++) {
        bf16x8 fb = *(const bf16x8*)&Bls[i0 + jt*16 + fr][fq*8];
        f32x4 z = {};
        f32x4 g = __builtin_amdgcn_mfma_f32_16x16x32_bf16(fa[it], fb, z, 0, 0, 0);
        int col = i0 + jt*16 + fr;
        float sc_col = slA[col], dt_col = dtlA[col];
        #pragma unroll
        for (int r = 0; r < 4; r++) {
          int row = wid*32 + it*16 + fq*4 + r;
          float v = 0.f;
          if (col <= row)
            v = g[r] * __expf(slA[row] - sc_col) * dt_col;
          CW[row][jt*16 + fr] = f2bf(v);
        }
      }
    }
    #pragma unroll
    for (int it = 0; it < 2; it++) {
      bf16x8 wa = *(const bf16x8*)&CW[wid*32 + it*16 + fr][fq*8];
      #pragma unroll
      for (int j = 0; j < 5; j++) {
        bf16x8 xb = *(const bf16x8*)&XT[j*16 + fr][i0 + fq*8];
        acc[it][j] = __builtin_amdgcn_mfma_f32_16x16x32_bf16(wa, xb, acc[it][j], 0, 0, 0);
      }
    }
  }

  // epilogue: Dp skip + z-gate
  float dpv = Dp[h];
  #pragma unroll
  for (int it = 0; it < 2; it++) {
    #pragma unroll
    for (int r = 0; r < 4; r++) {
      int l = wid*32 + it*16 + fq*4 + r;
      if (l >= len) continue;
      size_t m = m0 + l;
      #pragma unroll
      for (int j = 0; j < 5; j++) {
        int cc = h*HD + j*16 + fr;
        float xv = bf2f(xcb[m*CONVD + cc]);
        float y = acc[it][j][r] + xv*dpv;
        float zv = zx[m*DIP + cc];
        y *= zv / (1.f + expf(-zv));
        yg[m*DI + cc] = y;
      }
    }
  }
}

// ---------------- K6: RMS + scale, emit bf16 A for GEMM2 ----------------
__global__ __launch_bounds__(256) void k_rms_scale(
    const float* __restrict__ yg, const float* __restrict__ rsw,
    unsigned short* __restrict__ ygh)
{
  int m = blockIdx.x;
  int t = threadIdx.x;
  const float* row = yg + (size_t)m*DI;
  float v0 = row[t];
  float v1 = row[t+256];
  float v2 = (t < 128) ? row[t+512] : 0.f;
  float ss = v0*v0 + v1*v1 + v2*v2;
  ss = warp_sum(ss);
  __shared__ float r[4];
  int w = t >> 6, lane = t & 63;
  if (lane == 0) r[w] = ss;
  __syncthreads();
  float tot = r[0] + r[1] + r[2] + r[3];
  float rsv = rsqrtf(tot*(1.0f/DI) + 1e-5f);
  ygh[(size_t)m*DI + t]       = f2bf(v0 * rsv * rsw[t]);
  ygh[(size_t)m*DI + t + 256] = f2bf(v1 * rsv * rsw[t+256]);
  if (t < 128)
    ygh[(size_t)m*DI + t + 512] = f2bf(v2 * rsv * rsw[t+512]);
}

// ---------------- K7: out^T = w2 @ ygh^T via MFMA, coalesced transposed store ----------------
__global__ __launch_bounds__(256) void k_gemm2_mfma(
    const unsigned short* __restrict__ W2h, const unsigned short* __restrict__ Ygh,
    float* __restrict__ out)
{
  __shared__ unsigned short As[128][40];
  __shared__ unsigned short Bs[128][40];
  int c0 = blockIdx.y * 128;
  int t0 = blockIdx.x * 128;
  int tid = threadIdx.x;
  int lane = tid & 63, wid = tid >> 6;
  int wr = wid >> 1, wc = wid & 1;
  int fr = lane & 15, fq = lane >> 4;
  f32x4 acc[4][4] = {};
  for (int k0 = 0; k0 < DI; k0 += 32) {
    #pragma unroll
    for (int rnd = 0; rnd < 2; rnd++) {
      int idx = tid + rnd*256;
      int row = idx >> 2, slot = idx & 3;
      uint4 va = make_uint4(0,0,0,0);
      if (c0 + row < CDIM) va = *(const uint4*)(W2h + (size_t)(c0+row)*DI + k0 + slot*8);
      *(uint4*)&As[row][slot*8] = va;
      uint4 vb = make_uint4(0,0,0,0);
      if (t0 + row < MQ) vb = *(const uint4*)(Ygh + (size_t)(t0+row)*DI + k0 + slot*8);
      *(uint4*)&Bs[row][slot*8] = vb;
    }
    __syncthreads();
    bf16x8 fa[4], fb[4];
    #pragma unroll
    for (int i = 0; i < 4; i++) {
      fa[i] = *(const bf16x8*)&As[wr*64 + i*16 + fr][fq*8];
      fb[i] = *(const bf16x8*)&Bs[wc*64 + i*16 + fr][fq*8];
    }
    #pragma unroll
    for (int i = 0; i < 4; i++)
      #pragma unroll
      for (int j = 0; j < 4; j++)
        acc[i][j] = __builtin_amdgcn_mfma_f32_16x16x32_bf16(fa[i], fb[j], acc[i][j], 0, 0, 0);
    __syncthreads();
  }
  #pragma unroll
  for (int i = 0; i < 4; i++) {
    #pragma unroll
    for (int j = 0; j < 4; j++) {
      #pragma unroll
      for (int r = 0; r < 4; r++) {
        int ch  = c0 + wr*64 + i*16 + fq*4 + r;
        int tok = t0 + wc*64 + j*16 + fr;
        if (ch < CDIM && tok < MQ) {
          int b = tok / LQ, l = tok % LQ;
          if (l < NTQ)
            out[((size_t)(b*CDIM + ch))*NTQ + l] = acc[i][j][r];
        }
      }
    }
  }
}

extern "C" void kernel_launch(void* const* d_in, const int* in_sizes, int n_in,
                              void* d_out, int out_size, void* d_ws, size_t ws_size,
                              hipStream_t stream)
{
  const float* x       = (const float*)d_in[0];
  const float* pc      = (const float*)d_in[1];
  const float* lnw     = (const float*)d_in[2];
  const float* lnb     = (const float*)d_in[3];
  const float* w1      = (const float*)d_in[4];
  const float* cw      = (const float*)d_in[5];
  const float* cb      = (const float*)d_in[6];
  const float* dt_bias = (const float*)d_in[7];
  const float* A_log   = (const float*)d_in[8];
  const float* Dp      = (const float*)d_in[9];
  const float* rsw     = (const float*)d_in[10];
  const float* w2      = (const float*)d_in[11];
  const float* pg      = (const float*)d_in[12];
  const float* pew     = (const float*)d_in[13];
  const float* nap     = (const float*)d_in[14];
  const int*   plab    = (const int*)d_in[15];
  float* out = (float*)d_out;

  unsigned short* xnh = (unsigned short*)d_ws;                      // MQ*CDIM bf16
  float* zx  = (float*)(xnh + (size_t)MQ*CDIM);                     // MQ*DIP f32
  unsigned short* xcb = (unsigned short*)(zx + (size_t)MQ*DIP);     // MQ*CONVD bf16
  float* dtb = (float*)(xcb + (size_t)MQ*CONVD);                    // MQ*NH
  float* cs  = dtb + (size_t)MQ*NH;                                 // B*NH*NC*QC
  float* Dc  = cs  + (size_t)BQ*NH*NC*QC;                           // B*NH*NC
  float* Sb  = Dc  + (size_t)BQ*NH*NC;                              // B*NC*NH*HD*DS
  float* H0  = Sb;                                                  // in-place alias
  float* yg  = Sb  + (size_t)BQ*NC*NH*HD*DS;                        // MQ*DI f32
  unsigned short* w1h = (unsigned short*)(yg + (size_t)MQ*DI);      // DIP*CDIM bf16
  unsigned short* w2h = w1h + (size_t)DIP*CDIM;                     // CDIM*DI bf16
  unsigned short* ygh = xcb;  // alias: xcb dead after k_chunk_y_mfma

  k_f2bf<<<(DIP*CDIM + 255)/256, 256, 0, stream>>>(w1, w1h, DIP*CDIM);
  k_f2bf<<<(CDIM*DI + 255)/256, 256, 0, stream>>>(w2, w2h, CDIM*DI);
  dim3 gi(NTQ/64, BQ);
  k_img_ln<<<gi, 256, 0, stream>>>(x, lnw, lnb, xnh);
  dim3 gp(8, BQ);
  k_pt_ln<<<gp, 320, 0, stream>>>(pc, lnw, lnb, pg, pew, nap, plab, xnh);
  dim3 g1(11, 129);
  k_gemm1_mfma<<<g1, 256, 0, stream>>>(xnh, w1h, zx);
  dim3 g4(3, MQ);
  k_conv<<<g4, 256, 0, stream>>>(zx, cw, cb, xcb);
  dim3 gc(NC, NH, BQ);
  k_cumsum<<<gc, QC, 0, stream>>>(zx, dt_bias, A_log, dtb, cs, Dc);
  k_chunk_state_mfma<<<gc, 256, 0, stream>>>(xcb, dtb, cs, Sb);
  k_state_scan<<<(BQ*NH*HD*DS)/256, 256, 0, stream>>>(Sb, Dc, H0);
  k_chunk_y_mfma<<<gc, 256, 0, stream>>>(xcb, zx, dtb, cs, H0, Dp, yg);
  k_rms_scale<<<MQ, 256, 0, stream>>>(yg, rsw, ygh);
  dim3 g7(129, 3);
  k_gemm2_mfma<<<g7, 256, 0, stream>>>(w2h, ygh, out);
}

// Round 6
// 240.337 us; speedup vs baseline: 15.9656x; 1.2199x over previous
//
#include <hip/hip_runtime.h>
#include <math.h>

#define BQ 4
#define LQ 4104
#define NTQ 4096
#define CDIM 320
#define DIP 1352
#define DI 640
#define CONVD 704
#define NH 8
#define HD 80
#define DS 32
#define MQ (BQ*LQ)   // 16416
#define QC 128       // chunk length
#define NC 33        // ceil(LQ/QC)

typedef __attribute__((ext_vector_type(8))) short bf16x8;
typedef __attribute__((ext_vector_type(4))) float f32x4;

__device__ __forceinline__ unsigned short f2bf(float f){
  union { float f; unsigned u; } v; v.f = f;
  unsigned r = v.u + 0x7FFFu + ((v.u >> 16) & 1u);
  return (unsigned short)(r >> 16);
}
__device__ __forceinline__ float bf2f(unsigned short u){
  union { unsigned u; float f; } v; v.u = ((unsigned)u) << 16;
  return v.f;
}
__device__ __forceinline__ float warp_sum(float v){
  #pragma unroll
  for (int o = 32; o; o >>= 1) v += __shfl_xor(v, o);
  return v;
}

// ---------------- K0: both weight matrices f32 -> bf16 in one launch ----------------
__global__ __launch_bounds__(256) void k_f2bf2(
    const float* __restrict__ s1, unsigned short* __restrict__ d1, int n1,
    const float* __restrict__ s2, unsigned short* __restrict__ d2, int n2)
{
  int i = blockIdx.x*256 + threadIdx.x;
  if (i < n1) d1[i] = f2bf(s1[i]);
  else if (i - n1 < n2) d2[i - n1] = f2bf(s2[i - n1]);
}

// ---------------- K1a: image tokens LayerNorm, single-pass (bf16 LDS cache) ----------------
__global__ __launch_bounds__(256) void k_img_ln(
    const float* __restrict__ x, const float* __restrict__ lnw,
    const float* __restrict__ lnb, unsigned short* __restrict__ xnh)
{
  int b = blockIdx.y;
  int l0 = blockIdx.x * 64;
  int t = threadIdx.x;
  int lt = t & 63, cq = t >> 6;      // 4 channel-lanes x 64 tokens
  const float* xb = x + ((size_t)b*CDIM)*NTQ;

  __shared__ unsigned short XC[CDIM][66];
  __shared__ float sA[4][64], s2A[4][64];
  __shared__ float muA[64], rsA[64];

  float s = 0.f, s2 = 0.f;
  for (int c = cq; c < CDIM; c += 4) {
    float v = xb[(size_t)c*NTQ + l0 + lt];
    s += v; s2 = fmaf(v, v, s2);
    XC[c][lt] = f2bf(v);
  }
  sA[cq][lt] = s; s2A[cq][lt] = s2;
  __syncthreads();
  if (t < 64) {
    float ts  = sA[0][t]+sA[1][t]+sA[2][t]+sA[3][t];
    float ts2 = s2A[0][t]+s2A[1][t]+s2A[2][t]+s2A[3][t];
    float mu = ts*(1.0f/CDIM);
    muA[t] = mu;
    rsA[t] = rsqrtf(ts2*(1.0f/CDIM) - mu*mu + 1e-5f);
  }
  __syncthreads();
  for (int idx = t; idx < 64*80; idx += 256) {
    int ch4 = idx % 80, tok = idx / 80;
    int c0 = ch4*4;
    float mu = muA[tok], rs = rsA[tok];
    float4 wv = *(const float4*)(lnw + c0);
    float4 bv = *(const float4*)(lnb + c0);
    unsigned short o[4];
    o[0] = f2bf((bf2f(XC[c0+0][tok]) - mu)*rs*wv.x + bv.x);
    o[1] = f2bf((bf2f(XC[c0+1][tok]) - mu)*rs*wv.y + bv.y);
    o[2] = f2bf((bf2f(XC[c0+2][tok]) - mu)*rs*wv.z + bv.z);
    o[3] = f2bf((bf2f(XC[c0+3][tok]) - mu)*rs*wv.w + bv.w);
    *(uint2*)&xnh[((size_t)(b*LQ) + l0 + tok)*CDIM + c0] = *(const uint2*)o;
  }
}

// ---------------- K1b: point tokens + LayerNorm ----------------
__global__ __launch_bounds__(320) void k_pt_ln(
    const float* __restrict__ pcoords, const float* __restrict__ lnw,
    const float* __restrict__ lnb, const float* __restrict__ pgauss,
    const float* __restrict__ pemb_w, const float* __restrict__ nap,
    const int* __restrict__ plabels, unsigned short* __restrict__ xnh)
{
  int j = blockIdx.x, b = blockIdx.y;
  int c = threadIdx.x;
  int f = (c < 160) ? c : c - 160;
  float p0 = pcoords[(b*8+j)*3+0]*(2.0f/16.0f) - 1.0f;
  float p1 = pcoords[(b*8+j)*3+1]*(2.0f/16.0f) - 1.0f;
  float p2 = pcoords[(b*8+j)*3+2]*(2.0f/16.0f) - 1.0f;
  float pe = 6.283185307179586f*(p0*pgauss[f] + p1*pgauss[160+f] + p2*pgauss[320+f]);
  float pv = (c < 160) ? sinf(pe) : cosf(pe);
  int lab = plabels[b*8+j];
  float val;
  if (lab == -1) val = nap[c];
  else {
    int safe = lab < 0 ? 0 : (lab > 1 ? 1 : lab);
    val = pv + pemb_w[safe*CDIM + c];
  }
  float s  = warp_sum(val);
  float s2 = warp_sum(val*val);
  __shared__ float r1[5], r2[5];
  int w = threadIdx.x >> 6, lane = threadIdx.x & 63;
  if (lane == 0) { r1[w] = s; r2[w] = s2; }
  __syncthreads();
  float ts = 0.f, ts2 = 0.f;
  #pragma unroll
  for (int i = 0; i < 5; i++) { ts += r1[i]; ts2 += r2[i]; }
  float mu  = ts * (1.0f/CDIM);
  float var = ts2 * (1.0f/CDIM) - mu*mu;
  float rsig = rsqrtf(var + 1e-5f);
  xnh[((size_t)b*LQ + NTQ + j)*CDIM + c] = f2bf((val - mu)*rsig*lnw[c] + lnb[c]);
}

// ---------------- K2: zxh = xn @ w1^T via MFMA, bf16 out + f32 dt side-buffer ----------------
__global__ __launch_bounds__(256) void k_gemm1_mfma(
    const unsigned short* __restrict__ Abf, const unsigned short* __restrict__ Wbf,
    unsigned short* __restrict__ zxh, float* __restrict__ dtraw)
{
  __shared__ unsigned short As[128][40];
  __shared__ unsigned short Bs[128][40];
  int m0 = blockIdx.y * 128;
  int n0 = blockIdx.x * 128;
  int tid = threadIdx.x;
  int lane = tid & 63, wid = tid >> 6;
  int wr = wid >> 1, wc = wid & 1;
  int fr = lane & 15, fq = lane >> 4;
  f32x4 acc[4][4] = {};
  for (int k0 = 0; k0 < CDIM; k0 += 32) {
    #pragma unroll
    for (int rnd = 0; rnd < 2; rnd++) {
      int idx = tid + rnd*256;
      int row = idx >> 2, slot = idx & 3;
      uint4 va = make_uint4(0,0,0,0);
      if (m0 + row < MQ) va = *(const uint4*)(Abf + (size_t)(m0+row)*CDIM + k0 + slot*8);
      *(uint4*)&As[row][slot*8] = va;
      uint4 vb = make_uint4(0,0,0,0);
      if (n0 + row < DIP) vb = *(const uint4*)(Wbf + (size_t)(n0+row)*CDIM + k0 + slot*8);
      *(uint4*)&Bs[row][slot*8] = vb;
    }
    __syncthreads();
    bf16x8 fa[4], fb[4];
    #pragma unroll
    for (int i = 0; i < 4; i++) {
      fa[i] = *(const bf16x8*)&As[wr*64 + i*16 + fr][fq*8];
      fb[i] = *(const bf16x8*)&Bs[wc*64 + i*16 + fr][fq*8];
    }
    #pragma unroll
    for (int i = 0; i < 4; i++)
      #pragma unroll
      for (int j = 0; j < 4; j++)
        acc[i][j] = __builtin_amdgcn_mfma_f32_16x16x32_bf16(fa[i], fb[j], acc[i][j], 0, 0, 0);
    __syncthreads();
  }
  #pragma unroll
  for (int i = 0; i < 4; i++) {
    #pragma unroll
    for (int j = 0; j < 4; j++) {
      #pragma unroll
      for (int r = 0; r < 4; r++) {
        int grow = m0 + wr*64 + i*16 + fq*4 + r;
        int gcol = n0 + wc*64 + j*16 + fr;
        if (grow < MQ && gcol < DIP) {
          float v = acc[i][j][r];
          zxh[(size_t)grow*DIP + gcol] = f2bf(v);
          if (gcol >= DI + CONVD)
            dtraw[(size_t)grow*NH + (gcol - (DI + CONVD))] = v;
        }
      }
    }
  }
}

// ---------------- K4: depthwise causal conv(4) + bias + SiLU, bf16 in/out, 4 ch/thread ----------------
__global__ __launch_bounds__(256) void k_conv(
    const unsigned short* __restrict__ zxh, const float* __restrict__ cw,
    const float* __restrict__ cb, unsigned short* __restrict__ xcb)
{
  int gid = blockIdx.x*256 + threadIdx.x;
  if (gid >= MQ*(CONVD/4)) return;
  int c4 = gid % (CONVD/4);
  int m = gid / (CONVD/4);
  int c0 = c4*4;
  int l = m % LQ;
  float4 cbv = *(const float4*)(cb + c0);
  float a0 = cbv.x, a1 = cbv.y, a2 = cbv.z, a3 = cbv.w;
  float4 w0 = *(const float4*)(cw + (c0+0)*4);
  float4 w1 = *(const float4*)(cw + (c0+1)*4);
  float4 w2 = *(const float4*)(cw + (c0+2)*4);
  float4 w3 = *(const float4*)(cw + (c0+3)*4);
  const float* w0p = (const float*)&w0;
  const float* w1p = (const float*)&w1;
  const float* w2p = (const float*)&w2;
  const float* w3p = (const float*)&w3;
  #pragma unroll
  for (int j = 0; j < 4; j++) {
    int ls = l - 3 + j;
    if (ls < 0) continue;
    uint2 u = *(const uint2*)(zxh + (size_t)(m-3+j)*DIP + DI + c0);
    a0 = fmaf(bf2f((unsigned short)(u.x & 0xffff)), w0p[j], a0);
    a1 = fmaf(bf2f((unsigned short)(u.x >> 16)),    w1p[j], a1);
    a2 = fmaf(bf2f((unsigned short)(u.y & 0xffff)), w2p[j], a2);
    a3 = fmaf(bf2f((unsigned short)(u.y >> 16)),    w3p[j], a3);
  }
  unsigned short o[4];
  o[0] = f2bf(a0 / (1.f + __expf(-a0)));
  o[1] = f2bf(a1 / (1.f + __expf(-a1)));
  o[2] = f2bf(a2 / (1.f + __expf(-a2)));
  o[3] = f2bf(a3 / (1.f + __expf(-a3)));
  *(uint2*)(xcb + (size_t)m*CONVD + c0) = *(const uint2*)o;
}

// ---------------- K5a: softplus(dt)+cumsum(dt*A) fused ----------------
__global__ __launch_bounds__(QC) void k_cumsum(
    const float* __restrict__ dtraw, const float* __restrict__ dt_bias,
    const float* __restrict__ A_log, float* __restrict__ dtb,
    float* __restrict__ cs, float* __restrict__ Dc)
{
  int c = blockIdx.x, h = blockIdx.y, b = blockIdx.z;
  int l = threadIdx.x;
  int gl = c*QC + l;
  int len = LQ - c*QC; if (len > QC) len = QC;
  float A = -expf(A_log[h]);
  float a = 0.f;
  if (gl < LQ) {
    float v = dtraw[((size_t)(b*LQ+gl))*NH + h] + dt_bias[h];
    float sp = (v > 20.f) ? v : log1pf(expf(v));
    dtb[((size_t)(b*LQ+gl))*NH + h] = sp;
    a = sp * A;
  }
  __shared__ float sm[QC];
  sm[l] = a;
  __syncthreads();
  for (int off = 1; off < QC; off <<= 1) {
    float v = (l >= off) ? sm[l-off] : 0.f;
    __syncthreads();
    sm[l] += v;
    __syncthreads();
  }
  cs[((size_t)(b*NH+h)*NC + c)*QC + l] = sm[l];
  if (l == len-1) Dc[(b*NH+h)*NC + c] = expf(sm[l]);
}

// ---------------- K5b: chunk end-state via MFMA ----------------
__global__ __launch_bounds__(256) void k_chunk_state_mfma(
    const unsigned short* __restrict__ xcb, const float* __restrict__ dtb,
    const float* __restrict__ cs, float* __restrict__ Sbuf)
{
  int c = blockIdx.x, h = blockIdx.y, b = blockIdx.z;
  int len = LQ - c*QC; if (len > QC) len = QC;
  int t = threadIdx.x;
  int lane = t & 63, wid = t >> 6;
  int fr = lane & 15, fq = lane >> 4;
  int m0 = b*LQ + c*QC;

  __shared__ unsigned short XT[HD][136];
  __shared__ unsigned short BwT[DS][136];
  __shared__ float ws[QC];
  const float* csb = cs + ((size_t)(b*NH+h)*NC + c)*QC;

  for (int idx = t; idx < HD*QC; idx += 256) {
    int p = idx % HD, i = idx / HD;
    XT[p][i] = (i < len) ? xcb[(size_t)(m0+i)*CONVD + h*HD + p] : (unsigned short)0;
  }
  if (t < QC) {
    float s_end = csb[len-1];
    ws[t] = (t < len) ? __expf(s_end - csb[t]) * dtb[((size_t)(m0+t))*NH + h] : 0.f;
  }
  __syncthreads();
  for (int idx = t; idx < DS*QC; idx += 256) {
    int i = idx >> 5, n = idx & 31;
    float v = (i < len) ? bf2f(xcb[(size_t)(m0+i)*CONVD + DI + n]) * ws[i] : 0.f;
    BwT[n][i] = f2bf(v);
  }
  __syncthreads();

  size_t base = ((size_t)(b*NC + c)*NH + h)*(HD*DS);
  for (int tp = wid; tp < 10; tp += 4) {
    int pi = tp >> 1, ni = tp & 1;
    f32x4 acc = {};
    #pragma unroll
    for (int ks = 0; ks < 4; ks++) {
      bf16x8 fa = *(const bf16x8*)&XT[pi*16 + fr][ks*32 + fq*8];
      bf16x8 fb = *(const bf16x8*)&BwT[ni*16 + fr][ks*32 + fq*8];
      acc = __builtin_amdgcn_mfma_f32_16x16x32_bf16(fa, fb, acc, 0, 0, 0);
    }
    #pragma unroll
    for (int r = 0; r < 4; r++)
      Sbuf[base + (size_t)(pi*16 + fq*4 + r)*DS + ni*16 + fr] = acc[r];
  }
}

// ---------------- K5c: sequential scan over chunk states (in-place H0) ----------------
__global__ __launch_bounds__(256) void k_state_scan(
    float* __restrict__ Sbuf, const float* __restrict__ Dc,
    float* __restrict__ H0)
{
  int tid = blockIdx.x*256 + threadIdx.x;
  int pn = tid % (HD*DS);
  int bh = tid / (HD*DS);
  int b = bh >> 3, h = bh & 7;
  float hst = 0.f;
  for (int c = 0; c < NC; c++) {
    size_t idx = ((size_t)(b*NC + c)*NH + h)*(HD*DS) + pn;
    float sv = Sbuf[idx];
    H0[idx] = hst;
    hst = hst * Dc[bh*NC + c] + sv;
  }
}

// ---------------- K5d: per-chunk outputs v3: direct-global fragments, minimal LDS ----------------
__global__ __launch_bounds__(256) void k_chunk_y_mfma(
    const unsigned short* __restrict__ xcb, const unsigned short* __restrict__ zxh,
    const float* __restrict__ dtb, const float* __restrict__ cs,
    const float* __restrict__ H0, const float* __restrict__ Dp,
    unsigned short* __restrict__ ygb)
{
  int c = blockIdx.x, h = blockIdx.y, b = blockIdx.z;
  int len = LQ - c*QC; if (len > QC) len = QC;
  int t = threadIdx.x;
  int lane = t & 63, wid = t >> 6;
  int fr = lane & 15, fq = lane >> 4;
  int m0 = b*LQ + c*QC;

  __shared__ unsigned short XT[HD*136];      // [p][i], padded rows
  __shared__ unsigned short Wt[4*32*32];     // per-wave swizzled W tile
  __shared__ float slA[QC], dtlA[QC], elA[QC];

  const float* csb = cs + ((size_t)(b*NH+h)*NC + c)*QC;

  // stage X^T (vectorized along p: 8 channels per uint4)
  for (int idx = t; idx < (HD/8)*QC; idx += 256) {   // 1280
    int pg = idx % 10, i = idx / 10;
    uint4 v = make_uint4(0,0,0,0);
    if (i < len)
      v = *(const uint4*)(xcb + (size_t)(m0+i)*CONVD + h*HD + pg*8);
    union { uint4 u; unsigned short us[8]; } cv; cv.u = v;
    #pragma unroll
    for (int e = 0; e < 8; e++)
      XT[(pg*8+e)*136 + i] = cv.us[e];
  }
  if (t < QC) {
    float s = csb[t];
    slA[t] = s;
    elA[t] = __expf(s);
    dtlA[t] = (t < len) ? dtb[((size_t)(m0+t))*NH + h] : 0.f;
  }
  __syncthreads();   // the only barrier

  // C fragments: direct global
  bf16x8 fa[2];
  #pragma unroll
  for (int it = 0; it < 2; it++) {
    int row = wid*32 + it*16 + fr;
    bf16x8 v = {};
    if (row < len)
      v = *(const bf16x8*)(xcb + (size_t)(m0+row)*CONVD + DI + DS + fq*8);
    fa[it] = v;
  }

  // inter-chunk: C @ H0^T (H0 fragments direct global, f32->bf16 in-register)
  size_t hb = ((size_t)(b*NC + c)*NH + h)*(HD*DS);
  f32x4 acc[2][5];
  #pragma unroll
  for (int j = 0; j < 5; j++) {
    int p = j*16 + fr;
    const float* hp = H0 + hb + (size_t)p*DS + fq*8;
    float4 ha = *(const float4*)hp;
    float4 hbv = *(const float4*)(hp + 4);
    bf16x8 fb;
    fb[0]=(short)f2bf(ha.x);  fb[1]=(short)f2bf(ha.y);
    fb[2]=(short)f2bf(ha.z);  fb[3]=(short)f2bf(ha.w);
    fb[4]=(short)f2bf(hbv.x); fb[5]=(short)f2bf(hbv.y);
    fb[6]=(short)f2bf(hbv.z); fb[7]=(short)f2bf(hbv.w);
    #pragma unroll
    for (int it = 0; it < 2; it++) {
      f32x4 z = {};
      acc[it][j] = __builtin_amdgcn_mfma_f32_16x16x32_bf16(fa[it], fb, z, 0, 0, 0);
    }
  }
  #pragma unroll
  for (int it = 0; it < 2; it++)
    #pragma unroll
    for (int r = 0; r < 4; r++) {
      float el = elA[wid*32 + it*16 + fq*4 + r];
      #pragma unroll
      for (int j = 0; j < 5; j++) acc[it][j][r] *= el;
    }

  // intra-chunk: 4 sub-tiles of 32 tokens; B fragments direct global
  int wbase = wid << 10;
  for (int sc4 = 0; sc4 < 4; sc4++) {
    int i0 = sc4*32;
    #pragma unroll
    for (int jt = 0; jt < 2; jt++) {
      int col = i0 + jt*16 + fr;
      bf16x8 fbv = {};
      if (col < len)
        fbv = *(const bf16x8*)(xcb + (size_t)(m0+col)*CONVD + DI + fq*8);
      float sc_col = slA[col], dt_col = dtlA[col];
      #pragma unroll
      for (int it = 0; it < 2; it++) {
        f32x4 z = {};
        f32x4 g = __builtin_amdgcn_mfma_f32_16x16x32_bf16(fa[it], fbv, z, 0, 0, 0);
        #pragma unroll
        for (int r = 0; r < 4; r++) {
          int lr = it*16 + fq*4 + r;
          int row = wid*32 + lr;
          float v = 0.f;
          if (col <= row)
            v = g[r] * __expf(slA[row] - sc_col) * dt_col;
          int lc = jt*16 + fr;
          int slot = (lc >> 3) ^ (lr & 3);
          Wt[wbase + (lr<<5) + (slot<<3) + (lc&7)] = f2bf(v);
        }
      }
    }
    // PV: acc += W @ X^T  (same-wave LDS write->read, in-order, no barrier)
    #pragma unroll
    for (int it = 0; it < 2; it++) {
      int lr2 = it*16 + fr;
      bf16x8 wa = *(const bf16x8*)&Wt[wbase + (lr2<<5) + ((fq ^ (lr2&3))<<3)];
      #pragma unroll
      for (int j = 0; j < 5; j++) {
        int p = j*16 + fr;
        bf16x8 xb = *(const bf16x8*)&XT[p*136 + i0 + fq*8];
        acc[it][j] = __builtin_amdgcn_mfma_f32_16x16x32_bf16(wa, xb, acc[it][j], 0, 0, 0);
      }
    }
  }

  // epilogue: Dp skip (x from XT) + z-gate (bf16), bf16 store
  float dpv = Dp[h];
  #pragma unroll
  for (int it = 0; it < 2; it++) {
    #pragma unroll
    for (int r = 0; r < 4; r++) {
      int l = wid*32 + it*16 + fq*4 + r;
      if (l >= len) continue;
      size_t m = m0 + l;
      #pragma unroll
      for (int j = 0; j < 5; j++) {
        int p = j*16 + fr;
        int cc = h*HD + p;
        float xv = bf2f(XT[p*136 + l]);
        float y = acc[it][j][r] + xv*dpv;
        float zv = bf2f(zxh[m*DIP + cc]);
        y *= zv / (1.f + __expf(-zv));
        ygb[m*DI + cc] = f2bf(y);
      }
    }
  }
}

// ---------------- K6: RMS + scale, in-place on bf16 ----------------
__global__ __launch_bounds__(256) void k_rms_scale(
    unsigned short* __restrict__ ygb, const float* __restrict__ rsw)
{
  int m = blockIdx.x;
  int t = threadIdx.x;
  unsigned short* row = ygb + (size_t)m*DI;
  float v0=0.f, v1=0.f, v2=0.f, v3=0.f;
  float ss = 0.f;
  if (t < 160) {
    uint2 u = *(const uint2*)(row + t*4);
    v0 = bf2f((unsigned short)(u.x & 0xffff));
    v1 = bf2f((unsigned short)(u.x >> 16));
    v2 = bf2f((unsigned short)(u.y & 0xffff));
    v3 = bf2f((unsigned short)(u.y >> 16));
    ss = v0*v0 + v1*v1 + v2*v2 + v3*v3;
  }
  ss = warp_sum(ss);
  __shared__ float rsh[4];
  if ((t & 63) == 0) rsh[t>>6] = ss;
  __syncthreads();
  float tot = rsh[0] + rsh[1] + rsh[2] + rsh[3];
  float rsv = rsqrtf(tot*(1.0f/DI) + 1e-5f);
  if (t < 160) {
    float4 wv = *(const float4*)(rsw + t*4);
    unsigned short o[4];
    o[0] = f2bf(v0*rsv*wv.x);
    o[1] = f2bf(v1*rsv*wv.y);
    o[2] = f2bf(v2*rsv*wv.z);
    o[3] = f2bf(v3*rsv*wv.w);
    *(uint2*)(row + t*4) = *(const uint2*)o;
  }
}

// ---------------- K7: out^T = w2 @ ygb^T via MFMA, coalesced transposed store ----------------
__global__ __launch_bounds__(256) void k_gemm2_mfma(
    const unsigned short* __restrict__ W2h, const unsigned short* __restrict__ Ygh,
    float* __restrict__ out)
{
  __shared__ unsigned short As[128][40];
  __shared__ unsigned short Bs[128][40];
  int c0 = blockIdx.y * 128;
  int t0 = blockIdx.x * 128;
  int tid = threadIdx.x;
  int lane = tid & 63, wid = tid >> 6;
  int wr = wid >> 1, wc = wid & 1;
  int fr = lane & 15, fq = lane >> 4;
  f32x4 acc[4][4] = {};
  for (int k0 = 0; k0 < DI; k0 += 32) {
    #pragma unroll
    for (int rnd = 0; rnd < 2; rnd++) {
      int idx = tid + rnd*256;
      int row = idx >> 2, slot = idx & 3;
      uint4 va = make_uint4(0,0,0,0);
      if (c0 + row < CDIM) va = *(const uint4*)(W2h + (size_t)(c0+row)*DI + k0 + slot*8);
      *(uint4*)&As[row][slot*8] = va;
      uint4 vb = make_uint4(0,0,0,0);
      if (t0 + row < MQ) vb = *(const uint4*)(Ygh + (size_t)(t0+row)*DI + k0 + slot*8);
      *(uint4*)&Bs[row][slot*8] = vb;
    }
    __syncthreads();
    bf16x8 fa[4], fb[4];
    #pragma unroll
    for (int i = 0; i < 4; i++) {
      fa[i] = *(const bf16x8*)&As[wr*64 + i*16 + fr][fq*8];
      fb[i] = *(const bf16x8*)&Bs[wc*64 + i*16 + fr][fq*8];
    }
    #pragma unroll
    for (int i = 0; i < 4; i++)
      #pragma unroll
      for (int j = 0; j < 4; j++)
        acc[i][j] = __builtin_amdgcn_mfma_f32_16x16x32_bf16(fa[i], fb[j], acc[i][j], 0, 0, 0);
    __syncthreads();
  }
  #pragma unroll
  for (int i = 0; i < 4; i++) {
    #pragma unroll
    for (int j = 0; j < 4; j++) {
      #pragma unroll
      for (int r = 0; r < 4; r++) {
        int ch  = c0 + wr*64 + i*16 + fq*4 + r;
        int tok = t0 + wc*64 + j*16 + fr;
        if (ch < CDIM && tok < MQ) {
          int b = tok / LQ, l = tok % LQ;
          if (l < NTQ)
            out[((size_t)(b*CDIM + ch))*NTQ + l] = acc[i][j][r];
        }
      }
    }
  }
}

extern "C" void kernel_launch(void* const* d_in, const int* in_sizes, int n_in,
                              void* d_out, int out_size, void* d_ws, size_t ws_size,
                              hipStream_t stream)
{
  const float* x       = (const float*)d_in[0];
  const float* pc      = (const float*)d_in[1];
  const float* lnw     = (const float*)d_in[2];
  const float* lnb     = (const float*)d_in[3];
  const float* w1      = (const float*)d_in[4];
  const float* cw      = (const float*)d_in[5];
  const float* cb      = (const float*)d_in[6];
  const float* dt_bias = (const float*)d_in[7];
  const float* A_log   = (const float*)d_in[8];
  const float* Dp      = (const float*)d_in[9];
  const float* rsw     = (const float*)d_in[10];
  const float* w2      = (const float*)d_in[11];
  const float* pg      = (const float*)d_in[12];
  const float* pew     = (const float*)d_in[13];
  const float* nap     = (const float*)d_in[14];
  const int*   plab    = (const int*)d_in[15];
  float* out = (float*)d_out;

  unsigned short* xnh  = (unsigned short*)d_ws;                     // MQ*CDIM bf16
  unsigned short* zxh  = xnh + (size_t)MQ*CDIM;                     // MQ*DIP bf16
  float* dtraw = (float*)(zxh + (size_t)MQ*DIP);                    // MQ*NH f32
  unsigned short* xcb  = (unsigned short*)(dtraw + (size_t)MQ*NH);  // MQ*CONVD bf16
  float* dtb = (float*)(xcb + (size_t)MQ*CONVD);                    // MQ*NH f32
  float* cs  = dtb + (size_t)MQ*NH;                                 // B*NH*NC*QC
  float* Dc  = cs  + (size_t)BQ*NH*NC*QC;                           // B*NH*NC
  float* Sb  = Dc  + (size_t)BQ*NH*NC;                              // B*NC*NH*HD*DS
  float* H0  = Sb;                                                  // in-place alias
  unsigned short* ygb = (unsigned short*)(Sb + (size_t)BQ*NC*NH*HD*DS); // MQ*DI bf16
  unsigned short* w1h = ygb + (size_t)MQ*DI;                        // DIP*CDIM bf16
  unsigned short* w2h = w1h + (size_t)DIP*CDIM;                     // CDIM*DI bf16

  k_f2bf2<<<(DIP*CDIM + CDIM*DI + 255)/256, 256, 0, stream>>>(
      w1, w1h, DIP*CDIM, w2, w2h, CDIM*DI);
  dim3 gi(NTQ/64, BQ);
  k_img_ln<<<gi, 256, 0, stream>>>(x, lnw, lnb, xnh);
  dim3 gp(8, BQ);
  k_pt_ln<<<gp, 320, 0, stream>>>(pc, lnw, lnb, pg, pew, nap, plab, xnh);
  dim3 g1(11, 129);
  k_gemm1_mfma<<<g1, 256, 0, stream>>>(xnh, w1h, zxh, dtraw);
  k_conv<<<(MQ*(CONVD/4) + 255)/256, 256, 0, stream>>>(zxh, cw, cb, xcb);
  dim3 gc(NC, NH, BQ);
  k_cumsum<<<gc, QC, 0, stream>>>(dtraw, dt_bias, A_log, dtb, cs, Dc);
  k_chunk_state_mfma<<<gc, 256, 0, stream>>>(xcb, dtb, cs, Sb);
  k_state_scan<<<(BQ*NH*HD*DS)/256, 256, 0, stream>>>(Sb, Dc, H0);
  k_chunk_y_mfma<<<gc, 256, 0, stream>>>(xcb, zxh, dtb, cs, H0, Dp, ygb);
  k_rms_scale<<<MQ, 256, 0, stream>>>(ygb, rsw);
  dim3 g7(129, 3);
  k_gemm2_mfma<<<g7, 256, 0, stream>>>(w2h, ygb, out);
}

// Round 7
// 221.264 us; speedup vs baseline: 17.3419x; 1.0862x over previous
//
#include <hip/hip_runtime.h>
#include <math.h>

#define BQ 4
#define LQ 4104
#define NTQ 4096
#define CDIM 320
#define DIP 1352
#define DI 640
#define CONVD 704
#define NH 8
#define HD 80
#define DS 32
#define MQ (BQ*LQ)   // 16416
#define QC 128       // chunk length
#define NC 33        // ceil(LQ/QC)

typedef __attribute__((ext_vector_type(8))) short bf16x8;
typedef __attribute__((ext_vector_type(4))) float f32x4;

__device__ __forceinline__ unsigned short f2bf(float f){
  union { float f; unsigned u; } v; v.f = f;
  unsigned r = v.u + 0x7FFFu + ((v.u >> 16) & 1u);
  return (unsigned short)(r >> 16);
}
__device__ __forceinline__ float bf2f(unsigned short u){
  union { unsigned u; float f; } v; v.u = ((unsigned)u) << 16;
  return v.f;
}
__device__ __forceinline__ float warp_sum(float v){
  #pragma unroll
  for (int o = 32; o; o >>= 1) v += __shfl_xor(v, o);
  return v;
}
__device__ __forceinline__ void gload16(const unsigned short* g, unsigned short* l){
  __builtin_amdgcn_global_load_lds(
      (const __attribute__((address_space(1))) unsigned int*)g,
      (__attribute__((address_space(3))) unsigned int*)l, 16, 0, 0);
}

// ---------------- K0: both weight matrices f32 -> bf16 in one launch ----------------
__global__ __launch_bounds__(256) void k_f2bf2(
    const float* __restrict__ s1, unsigned short* __restrict__ d1, int n1,
    const float* __restrict__ s2, unsigned short* __restrict__ d2, int n2)
{
  int i = blockIdx.x*256 + threadIdx.x;
  if (i < n1) d1[i] = f2bf(s1[i]);
  else if (i - n1 < n2) d2[i - n1] = f2bf(s2[i - n1]);
}

// ---------------- K1a: image tokens LayerNorm, single-pass (bf16 LDS cache) ----------------
__global__ __launch_bounds__(256) void k_img_ln(
    const float* __restrict__ x, const float* __restrict__ lnw,
    const float* __restrict__ lnb, unsigned short* __restrict__ xnh)
{
  int b = blockIdx.y;
  int l0 = blockIdx.x * 64;
  int t = threadIdx.x;
  int lt = t & 63, cq = t >> 6;
  const float* xb = x + ((size_t)b*CDIM)*NTQ;

  __shared__ unsigned short XC[CDIM][66];
  __shared__ float sA[4][64], s2A[4][64];
  __shared__ float muA[64], rsA[64];

  float s = 0.f, s2 = 0.f;
  for (int c = cq; c < CDIM; c += 4) {
    float v = xb[(size_t)c*NTQ + l0 + lt];
    s += v; s2 = fmaf(v, v, s2);
    XC[c][lt] = f2bf(v);
  }
  sA[cq][lt] = s; s2A[cq][lt] = s2;
  __syncthreads();
  if (t < 64) {
    float ts  = sA[0][t]+sA[1][t]+sA[2][t]+sA[3][t];
    float ts2 = s2A[0][t]+s2A[1][t]+s2A[2][t]+s2A[3][t];
    float mu = ts*(1.0f/CDIM);
    muA[t] = mu;
    rsA[t] = rsqrtf(ts2*(1.0f/CDIM) - mu*mu + 1e-5f);
  }
  __syncthreads();
  for (int idx = t; idx < 64*80; idx += 256) {
    int ch4 = idx % 80, tok = idx / 80;
    int c0 = ch4*4;
    float mu = muA[tok], rs = rsA[tok];
    float4 wv = *(const float4*)(lnw + c0);
    float4 bv = *(const float4*)(lnb + c0);
    unsigned short o[4];
    o[0] = f2bf((bf2f(XC[c0+0][tok]) - mu)*rs*wv.x + bv.x);
    o[1] = f2bf((bf2f(XC[c0+1][tok]) - mu)*rs*wv.y + bv.y);
    o[2] = f2bf((bf2f(XC[c0+2][tok]) - mu)*rs*wv.z + bv.z);
    o[3] = f2bf((bf2f(XC[c0+3][tok]) - mu)*rs*wv.w + bv.w);
    *(uint2*)&xnh[((size_t)(b*LQ) + l0 + tok)*CDIM + c0] = *(const uint2*)o;
  }
}

// ---------------- K1b: point tokens + LayerNorm ----------------
__global__ __launch_bounds__(320) void k_pt_ln(
    const float* __restrict__ pcoords, const float* __restrict__ lnw,
    const float* __restrict__ lnb, const float* __restrict__ pgauss,
    const float* __restrict__ pemb_w, const float* __restrict__ nap,
    const int* __restrict__ plabels, unsigned short* __restrict__ xnh)
{
  int j = blockIdx.x, b = blockIdx.y;
  int c = threadIdx.x;
  int f = (c < 160) ? c : c - 160;
  float p0 = pcoords[(b*8+j)*3+0]*(2.0f/16.0f) - 1.0f;
  float p1 = pcoords[(b*8+j)*3+1]*(2.0f/16.0f) - 1.0f;
  float p2 = pcoords[(b*8+j)*3+2]*(2.0f/16.0f) - 1.0f;
  float pe = 6.283185307179586f*(p0*pgauss[f] + p1*pgauss[160+f] + p2*pgauss[320+f]);
  float pv = (c < 160) ? sinf(pe) : cosf(pe);
  int lab = plabels[b*8+j];
  float val;
  if (lab == -1) val = nap[c];
  else {
    int safe = lab < 0 ? 0 : (lab > 1 ? 1 : lab);
    val = pv + pemb_w[safe*CDIM + c];
  }
  float s  = warp_sum(val);
  float s2 = warp_sum(val*val);
  __shared__ float r1[5], r2[5];
  int w = threadIdx.x >> 6, lane = threadIdx.x & 63;
  if (lane == 0) { r1[w] = s; r2[w] = s2; }
  __syncthreads();
  float ts = 0.f, ts2 = 0.f;
  #pragma unroll
  for (int i = 0; i < 5; i++) { ts += r1[i]; ts2 += r2[i]; }
  float mu  = ts * (1.0f/CDIM);
  float var = ts2 * (1.0f/CDIM) - mu*mu;
  float rsig = rsqrtf(var + 1e-5f);
  xnh[((size_t)b*LQ + NTQ + j)*CDIM + c] = f2bf((val - mu)*rsig*lnw[c] + lnb[c]);
}

// ---------------- K2: zxh = xn @ w1^T via MFMA + global_load_lds, XCD-swizzled ----------------
__global__ __launch_bounds__(256) void k_gemm1_mfma(
    const unsigned short* __restrict__ Abf, const unsigned short* __restrict__ Wbf,
    unsigned short* __restrict__ zxh, float* __restrict__ dtraw)
{
  __shared__ unsigned short As[128*32];
  __shared__ unsigned short Bs[128*32];
  // bijective XCD swizzle: nwg = 129*11 = 1419 = 8*177 + 3
  int id = blockIdx.x;
  int xcd = id & 7, pos = id >> 3;
  const int q = 177, r = 3;
  int swz = (xcd < r ? xcd*(q+1) : r*(q+1) + (xcd-r)*q) + pos;
  int m0 = (swz / 11) * 128;
  int n0 = (swz % 11) * 128;
  int tid = threadIdx.x;
  int lane = tid & 63, wid = tid >> 6;
  int wr = wid >> 1, wc = wid & 1;
  int fr = lane & 15, fq = lane >> 4;

  int srow = lane >> 2;          // 0..15 within 16-row segment
  int scol = (lane & 3) * 8;     // bf16 element offset (16B granules)

  f32x4 acc[4][4] = {};
  for (int k0 = 0; k0 < CDIM; k0 += 32) {
    #pragma unroll
    for (int i = 0; i < 2; i++) {
      int seg = wid + i*4;               // wave-uniform, 0..7
      int rowA = seg*16 + srow;
      int ga = m0 + rowA; if (ga > MQ-1) ga = MQ-1;
      gload16(Abf + (size_t)ga*CDIM + k0 + scol, &As[seg*512]);
      int gb = n0 + rowA; if (gb > DIP-1) gb = DIP-1;
      gload16(Wbf + (size_t)gb*CDIM + k0 + scol, &Bs[seg*512]);
    }
    __syncthreads();
    bf16x8 fa[4], fb[4];
    #pragma unroll
    for (int i = 0; i < 4; i++) {
      fa[i] = *(const bf16x8*)&As[(wr*64 + i*16 + fr)*32 + fq*8];
      fb[i] = *(const bf16x8*)&Bs[(wc*64 + i*16 + fr)*32 + fq*8];
    }
    #pragma unroll
    for (int i = 0; i < 4; i++)
      #pragma unroll
      for (int j = 0; j < 4; j++)
        acc[i][j] = __builtin_amdgcn_mfma_f32_16x16x32_bf16(fa[i], fb[j], acc[i][j], 0, 0, 0);
    __syncthreads();
  }
  #pragma unroll
  for (int i = 0; i < 4; i++) {
    #pragma unroll
    for (int j = 0; j < 4; j++) {
      #pragma unroll
      for (int rr = 0; rr < 4; rr++) {
        int grow = m0 + wr*64 + i*16 + fq*4 + rr;
        int gcol = n0 + wc*64 + j*16 + fr;
        if (grow < MQ && gcol < DIP) {
          float v = acc[i][j][rr];
          zxh[(size_t)grow*DIP + gcol] = f2bf(v);
          if (gcol >= DI + CONVD)
            dtraw[(size_t)grow*NH + (gcol - (DI + CONVD))] = v;
        }
      }
    }
  }
}

// ---------------- K4: depthwise causal conv(4) + bias + SiLU, bf16 in/out ----------------
__global__ __launch_bounds__(256) void k_conv(
    const unsigned short* __restrict__ zxh, const float* __restrict__ cw,
    const float* __restrict__ cb, unsigned short* __restrict__ xcb)
{
  int gid = blockIdx.x*256 + threadIdx.x;
  if (gid >= MQ*(CONVD/4)) return;
  int c4 = gid % (CONVD/4);
  int m = gid / (CONVD/4);
  int c0 = c4*4;
  int l = m % LQ;
  float4 cbv = *(const float4*)(cb + c0);
  float a0 = cbv.x, a1 = cbv.y, a2 = cbv.z, a3 = cbv.w;
  float4 w0 = *(const float4*)(cw + (c0+0)*4);
  float4 w1 = *(const float4*)(cw + (c0+1)*4);
  float4 w2 = *(const float4*)(cw + (c0+2)*4);
  float4 w3 = *(const float4*)(cw + (c0+3)*4);
  const float* w0p = (const float*)&w0;
  const float* w1p = (const float*)&w1;
  const float* w2p = (const float*)&w2;
  const float* w3p = (const float*)&w3;
  #pragma unroll
  for (int j = 0; j < 4; j++) {
    int ls = l - 3 + j;
    if (ls < 0) continue;
    uint2 u = *(const uint2*)(zxh + (size_t)(m-3+j)*DIP + DI + c0);
    a0 = fmaf(bf2f((unsigned short)(u.x & 0xffff)), w0p[j], a0);
    a1 = fmaf(bf2f((unsigned short)(u.x >> 16)),    w1p[j], a1);
    a2 = fmaf(bf2f((unsigned short)(u.y & 0xffff)), w2p[j], a2);
    a3 = fmaf(bf2f((unsigned short)(u.y >> 16)),    w3p[j], a3);
  }
  unsigned short o[4];
  o[0] = f2bf(a0 / (1.f + __expf(-a0)));
  o[1] = f2bf(a1 / (1.f + __expf(-a1)));
  o[2] = f2bf(a2 / (1.f + __expf(-a2)));
  o[3] = f2bf(a3 / (1.f + __expf(-a3)));
  *(uint2*)(xcb + (size_t)m*CONVD + c0) = *(const uint2*)o;
}

// ---------------- K5ab: fused softplus+cumsum + chunk end-state MFMA ----------------
__global__ __launch_bounds__(256) void k_cumsum_state(
    const float* __restrict__ dtraw, const float* __restrict__ dt_bias,
    const float* __restrict__ A_log, const unsigned short* __restrict__ xcb,
    float* __restrict__ dtb, float* __restrict__ cs, float* __restrict__ Dc,
    float* __restrict__ Sbuf)
{
  int c = blockIdx.x, h = blockIdx.y, b = blockIdx.z;
  int len = LQ - c*QC; if (len > QC) len = QC;
  int t = threadIdx.x;
  int lane = t & 63, wid = t >> 6;
  int fr = lane & 15, fq = lane >> 4;
  int m0 = b*LQ + c*QC;

  __shared__ unsigned short XT[HD][136];
  __shared__ unsigned short BwT[DS][136];
  __shared__ float sm[QC], dtl[QC], ws[QC];

  // issue X^T staging loads early (latency hides under the scan barriers)
  for (int idx = t; idx < HD*QC; idx += 256) {
    int p = idx % HD, i = idx / HD;
    XT[p][i] = (i < len) ? xcb[(size_t)(m0+i)*CONVD + h*HD + p] : (unsigned short)0;
  }

  float A = -expf(A_log[h]);
  if (t < QC) {
    float sp = 0.f;
    if (t < len) {
      float v = dtraw[((size_t)(m0+t))*NH + h] + dt_bias[h];
      sp = (v > 20.f) ? v : log1pf(expf(v));
      dtb[((size_t)(m0+t))*NH + h] = sp;
    }
    dtl[t] = sp;
    sm[t] = sp * A;
  }
  __syncthreads();
  for (int off = 1; off < QC; off <<= 1) {
    float v = 0.f;
    if (t < QC && t >= off) v = sm[t-off];
    __syncthreads();
    if (t < QC) sm[t] += v;
    __syncthreads();
  }
  if (t < QC) cs[((size_t)(b*NH+h)*NC + c)*QC + t] = sm[t];
  if (t == len-1) Dc[(b*NH+h)*NC + c] = expf(sm[t]);
  if (t < QC) ws[t] = (t < len) ? __expf(sm[len-1] - sm[t]) * dtl[t] : 0.f;
  __syncthreads();
  for (int idx = t; idx < DS*QC; idx += 256) {
    int i = idx >> 5, n = idx & 31;
    float v = (i < len) ? bf2f(xcb[(size_t)(m0+i)*CONVD + DI + n]) * ws[i] : 0.f;
    BwT[n][i] = f2bf(v);
  }
  __syncthreads();

  size_t base = ((size_t)(b*NC + c)*NH + h)*(HD*DS);
  for (int tp = wid; tp < 10; tp += 4) {
    int pi = tp >> 1, ni = tp & 1;
    f32x4 acc = {};
    #pragma unroll
    for (int ks = 0; ks < 4; ks++) {
      bf16x8 fa = *(const bf16x8*)&XT[pi*16 + fr][ks*32 + fq*8];
      bf16x8 fb = *(const bf16x8*)&BwT[ni*16 + fr][ks*32 + fq*8];
      acc = __builtin_amdgcn_mfma_f32_16x16x32_bf16(fa, fb, acc, 0, 0, 0);
    }
    #pragma unroll
    for (int rr = 0; rr < 4; rr++)
      Sbuf[base + (size_t)(pi*16 + fq*4 + rr)*DS + ni*16 + fr] = acc[rr];
  }
}

// ---------------- K5c: sequential scan over chunk states (in-place H0) ----------------
__global__ __launch_bounds__(256) void k_state_scan(
    float* __restrict__ Sbuf, const float* __restrict__ Dc,
    float* __restrict__ H0)
{
  int tid = blockIdx.x*256 + threadIdx.x;
  int pn = tid % (HD*DS);
  int bh = tid / (HD*DS);
  int b = bh >> 3, h = bh & 7;
  float hst = 0.f;
  for (int c = 0; c < NC; c++) {
    size_t idx = ((size_t)(b*NC + c)*NH + h)*(HD*DS) + pn;
    float sv = Sbuf[idx];
    H0[idx] = hst;
    hst = hst * Dc[bh*NC + c] + sv;
  }
}

// ---------------- K5d: per-chunk outputs: direct-global fragments, minimal LDS ----------------
__global__ __launch_bounds__(256) void k_chunk_y_mfma(
    const unsigned short* __restrict__ xcb, const unsigned short* __restrict__ zxh,
    const float* __restrict__ dtb, const float* __restrict__ cs,
    const float* __restrict__ H0, const float* __restrict__ Dp,
    unsigned short* __restrict__ ygb)
{
  int c = blockIdx.x, h = blockIdx.y, b = blockIdx.z;
  int len = LQ - c*QC; if (len > QC) len = QC;
  int t = threadIdx.x;
  int lane = t & 63, wid = t >> 6;
  int fr = lane & 15, fq = lane >> 4;
  int m0 = b*LQ + c*QC;

  __shared__ unsigned short XT[HD*136];
  __shared__ unsigned short Wt[4*32*32];
  __shared__ float slA[QC], dtlA[QC], elA[QC];

  const float* csb = cs + ((size_t)(b*NH+h)*NC + c)*QC;

  for (int idx = t; idx < (HD/8)*QC; idx += 256) {
    int pg = idx % 10, i = idx / 10;
    uint4 v = make_uint4(0,0,0,0);
    if (i < len)
      v = *(const uint4*)(xcb + (size_t)(m0+i)*CONVD + h*HD + pg*8);
    union { uint4 u; unsigned short us[8]; } cv; cv.u = v;
    #pragma unroll
    for (int e = 0; e < 8; e++)
      XT[(pg*8+e)*136 + i] = cv.us[e];
  }
  if (t < QC) {
    float s = csb[t];
    slA[t] = s;
    elA[t] = __expf(s);
    dtlA[t] = (t < len) ? dtb[((size_t)(m0+t))*NH + h] : 0.f;
  }
  __syncthreads();

  bf16x8 fa[2];
  #pragma unroll
  for (int it = 0; it < 2; it++) {
    int row = wid*32 + it*16 + fr;
    bf16x8 v = {};
    if (row < len)
      v = *(const bf16x8*)(xcb + (size_t)(m0+row)*CONVD + DI + DS + fq*8);
    fa[it] = v;
  }

  size_t hb = ((size_t)(b*NC + c)*NH + h)*(HD*DS);
  f32x4 acc[2][5];
  #pragma unroll
  for (int j = 0; j < 5; j++) {
    int p = j*16 + fr;
    const float* hp = H0 + hb + (size_t)p*DS + fq*8;
    float4 ha = *(const float4*)hp;
    float4 hbv = *(const float4*)(hp + 4);
    bf16x8 fb;
    fb[0]=(short)f2bf(ha.x);  fb[1]=(short)f2bf(ha.y);
    fb[2]=(short)f2bf(ha.z);  fb[3]=(short)f2bf(ha.w);
    fb[4]=(short)f2bf(hbv.x); fb[5]=(short)f2bf(hbv.y);
    fb[6]=(short)f2bf(hbv.z); fb[7]=(short)f2bf(hbv.w);
    #pragma unroll
    for (int it = 0; it < 2; it++) {
      f32x4 z = {};
      acc[it][j] = __builtin_amdgcn_mfma_f32_16x16x32_bf16(fa[it], fb, z, 0, 0, 0);
    }
  }
  #pragma unroll
  for (int it = 0; it < 2; it++)
    #pragma unroll
    for (int rr = 0; rr < 4; rr++) {
      float el = elA[wid*32 + it*16 + fq*4 + rr];
      #pragma unroll
      for (int j = 0; j < 5; j++) acc[it][j][rr] *= el;
    }

  int wbase = wid << 10;
  for (int sc4 = 0; sc4 < 4; sc4++) {
    int i0 = sc4*32;
    #pragma unroll
    for (int jt = 0; jt < 2; jt++) {
      int col = i0 + jt*16 + fr;
      bf16x8 fbv = {};
      if (col < len)
        fbv = *(const bf16x8*)(xcb + (size_t)(m0+col)*CONVD + DI + fq*8);
      float sc_col = slA[col], dt_col = dtlA[col];
      #pragma unroll
      for (int it = 0; it < 2; it++) {
        f32x4 z = {};
        f32x4 g = __builtin_amdgcn_mfma_f32_16x16x32_bf16(fa[it], fbv, z, 0, 0, 0);
        #pragma unroll
        for (int rr = 0; rr < 4; rr++) {
          int lr = it*16 + fq*4 + rr;
          int row = wid*32 + lr;
          float v = 0.f;
          if (col <= row)
            v = g[rr] * __expf(slA[row] - sc_col) * dt_col;
          int lc = jt*16 + fr;
          int slot = (lc >> 3) ^ (lr & 3);
          Wt[wbase + (lr<<5) + (slot<<3) + (lc&7)] = f2bf(v);
        }
      }
    }
    #pragma unroll
    for (int it = 0; it < 2; it++) {
      int lr2 = it*16 + fr;
      bf16x8 wa = *(const bf16x8*)&Wt[wbase + (lr2<<5) + ((fq ^ (lr2&3))<<3)];
      #pragma unroll
      for (int j = 0; j < 5; j++) {
        int p = j*16 + fr;
        bf16x8 xb = *(const bf16x8*)&XT[p*136 + i0 + fq*8];
        acc[it][j] = __builtin_amdgcn_mfma_f32_16x16x32_bf16(wa, xb, acc[it][j], 0, 0, 0);
      }
    }
  }

  float dpv = Dp[h];
  #pragma unroll
  for (int it = 0; it < 2; it++) {
    #pragma unroll
    for (int rr = 0; rr < 4; rr++) {
      int l = wid*32 + it*16 + fq*4 + rr;
      if (l >= len) continue;
      size_t m = m0 + l;
      #pragma unroll
      for (int j = 0; j < 5; j++) {
        int p = j*16 + fr;
        int cc = h*HD + p;
        float xv = bf2f(XT[p*136 + l]);
        float y = acc[it][j][rr] + xv*dpv;
        float zv = bf2f(zxh[m*DIP + cc]);
        y *= zv / (1.f + __expf(-zv));
        ygb[m*DI + cc] = f2bf(y);
      }
    }
  }
}

// ---------------- K6: RMS + scale, in-place on bf16 ----------------
__global__ __launch_bounds__(256) void k_rms_scale(
    unsigned short* __restrict__ ygb, const float* __restrict__ rsw)
{
  int m = blockIdx.x;
  int t = threadIdx.x;
  unsigned short* row = ygb + (size_t)m*DI;
  float v0=0.f, v1=0.f, v2=0.f, v3=0.f;
  float ss = 0.f;
  if (t < 160) {
    uint2 u = *(const uint2*)(row + t*4);
    v0 = bf2f((unsigned short)(u.x & 0xffff));
    v1 = bf2f((unsigned short)(u.x >> 16));
    v2 = bf2f((unsigned short)(u.y & 0xffff));
    v3 = bf2f((unsigned short)(u.y >> 16));
    ss = v0*v0 + v1*v1 + v2*v2 + v3*v3;
  }
  ss = warp_sum(ss);
  __shared__ float rsh[4];
  if ((t & 63) == 0) rsh[t>>6] = ss;
  __syncthreads();
  float tot = rsh[0] + rsh[1] + rsh[2] + rsh[3];
  float rsv = rsqrtf(tot*(1.0f/DI) + 1e-5f);
  if (t < 160) {
    float4 wv = *(const float4*)(rsw + t*4);
    unsigned short o[4];
    o[0] = f2bf(v0*rsv*wv.x);
    o[1] = f2bf(v1*rsv*wv.y);
    o[2] = f2bf(v2*rsv*wv.z);
    o[3] = f2bf(v3*rsv*wv.w);
    *(uint2*)(row + t*4) = *(const uint2*)o;
  }
}

// ---------------- K7: out^T = w2 @ ygb^T via MFMA + global_load_lds, XCD-swizzled ----------------
__global__ __launch_bounds__(256) void k_gemm2_mfma(
    const unsigned short* __restrict__ W2h, const unsigned short* __restrict__ Ygh,
    float* __restrict__ out)
{
  __shared__ unsigned short As[128*32];
  __shared__ unsigned short Bs[128*32];
  // bijective XCD swizzle: nwg = 129*3 = 387 = 8*48 + 3
  int id = blockIdx.x;
  int xcd = id & 7, pos = id >> 3;
  const int q = 48, r = 3;
  int swz = (xcd < r ? xcd*(q+1) : r*(q+1) + (xcd-r)*q) + pos;
  int c0 = (swz % 3) * 128;   // out-channel tile (over 320)
  int t0 = (swz / 3) * 128;   // token tile
  int tid = threadIdx.x;
  int lane = tid & 63, wid = tid >> 6;
  int wr = wid >> 1, wc = wid & 1;
  int fr = lane & 15, fq = lane >> 4;

  int srow = lane >> 2;
  int scol = (lane & 3) * 8;

  f32x4 acc[4][4] = {};
  for (int k0 = 0; k0 < DI; k0 += 32) {
    #pragma unroll
    for (int i = 0; i < 2; i++) {
      int seg = wid + i*4;
      int rowA = seg*16 + srow;
      int ga = c0 + rowA; if (ga > CDIM-1) ga = CDIM-1;
      gload16(W2h + (size_t)ga*DI + k0 + scol, &As[seg*512]);
      int gb = t0 + rowA; if (gb > MQ-1) gb = MQ-1;
      gload16(Ygh + (size_t)gb*DI + k0 + scol, &Bs[seg*512]);
    }
    __syncthreads();
    bf16x8 fa[4], fb[4];
    #pragma unroll
    for (int i = 0; i < 4; i++) {
      fa[i] = *(const bf16x8*)&As[(wr*64 + i*16 + fr)*32 + fq*8];
      fb[i] = *(const bf16x8*)&Bs[(wc*64 + i*16 + fr)*32 + fq*8];
    }
    #pragma unroll
    for (int i = 0; i < 4; i++)
      #pragma unroll
      for (int j = 0; j < 4; j++)
        acc[i][j] = __builtin_amdgcn_mfma_f32_16x16x32_bf16(fa[i], fb[j], acc[i][j], 0, 0, 0);
    __syncthreads();
  }
  #pragma unroll
  for (int i = 0; i < 4; i++) {
    #pragma unroll
    for (int j = 0; j < 4; j++) {
      #pragma unroll
      for (int rr = 0; rr < 4; rr++) {
        int ch  = c0 + wr*64 + i*16 + fq*4 + rr;
        int tok = t0 + wc*64 + j*16 + fr;
        if (ch < CDIM && tok < MQ) {
          int b = tok / LQ, l = tok % LQ;
          if (l < NTQ)
            out[((size_t)(b*CDIM + ch))*NTQ + l] = acc[i][j][rr];
        }
      }
    }
  }
}

extern "C" void kernel_launch(void* const* d_in, const int* in_sizes, int n_in,
                              void* d_out, int out_size, void* d_ws, size_t ws_size,
                              hipStream_t stream)
{
  const float* x       = (const float*)d_in[0];
  const float* pc      = (const float*)d_in[1];
  const float* lnw     = (const float*)d_in[2];
  const float* lnb     = (const float*)d_in[3];
  const float* w1      = (const float*)d_in[4];
  const float* cw      = (const float*)d_in[5];
  const float* cb      = (const float*)d_in[6];
  const float* dt_bias = (const float*)d_in[7];
  const float* A_log   = (const float*)d_in[8];
  const float* Dp      = (const float*)d_in[9];
  const float* rsw     = (const float*)d_in[10];
  const float* w2      = (const float*)d_in[11];
  const float* pg      = (const float*)d_in[12];
  const float* pew     = (const float*)d_in[13];
  const float* nap     = (const float*)d_in[14];
  const int*   plab    = (const int*)d_in[15];
  float* out = (float*)d_out;

  unsigned short* xnh  = (unsigned short*)d_ws;                     // MQ*CDIM bf16
  unsigned short* zxh  = xnh + (size_t)MQ*CDIM;                     // MQ*DIP bf16
  float* dtraw = (float*)(zxh + (size_t)MQ*DIP);                    // MQ*NH f32
  unsigned short* xcb  = (unsigned short*)(dtraw + (size_t)MQ*NH);  // MQ*CONVD bf16
  float* dtb = (float*)(xcb + (size_t)MQ*CONVD);                    // MQ*NH f32
  float* cs  = dtb + (size_t)MQ*NH;                                 // B*NH*NC*QC
  float* Dc  = cs  + (size_t)BQ*NH*NC*QC;                           // B*NH*NC
  float* Sb  = Dc  + (size_t)BQ*NH*NC;                              // B*NC*NH*HD*DS
  float* H0  = Sb;                                                  // in-place alias
  unsigned short* ygb = (unsigned short*)(Sb + (size_t)BQ*NC*NH*HD*DS); // MQ*DI bf16
  unsigned short* w1h = ygb + (size_t)MQ*DI;                        // DIP*CDIM bf16
  unsigned short* w2h = w1h + (size_t)DIP*CDIM;                     // CDIM*DI bf16

  k_f2bf2<<<(DIP*CDIM + CDIM*DI + 255)/256, 256, 0, stream>>>(
      w1, w1h, DIP*CDIM, w2, w2h, CDIM*DI);
  dim3 gi(NTQ/64, BQ);
  k_img_ln<<<gi, 256, 0, stream>>>(x, lnw, lnb, xnh);
  dim3 gp(8, BQ);
  k_pt_ln<<<gp, 320, 0, stream>>>(pc, lnw, lnb, pg, pew, nap, plab, xnh);
  k_gemm1_mfma<<<129*11, 256, 0, stream>>>(xnh, w1h, zxh, dtraw);
  k_conv<<<(MQ*(CONVD/4) + 255)/256, 256, 0, stream>>>(zxh, cw, cb, xcb);
  dim3 gc(NC, NH, BQ);
  k_cumsum_state<<<gc, 256, 0, stream>>>(dtraw, dt_bias, A_log, xcb, dtb, cs, Dc, Sb);
  k_state_scan<<<(BQ*NH*HD*DS)/256, 256, 0, stream>>>(Sb, Dc, H0);
  k_chunk_y_mfma<<<gc, 256, 0, stream>>>(xcb, zxh, dtb, cs, H0, Dp, ygb);
  k_rms_scale<<<MQ, 256, 0, stream>>>(ygb, rsw);
  k_gemm2_mfma<<<129*3, 256, 0, stream>>>(w2h, ygb, out);
}

// Round 8
// 185.356 us; speedup vs baseline: 20.7014x; 1.1937x over previous
//
#include <hip/hip_runtime.h>
#include <math.h>

#define BQ 4
#define LQ 4104
#define NTQ 4096
#define CDIM 320
#define DIP 1352
#define DI 640
#define CONVD 704
#define NH 8
#define HD 80
#define DS 32
#define MQ (BQ*LQ)   // 16416
#define QC 64        // chunk length
#define NC 65        // ceil(LQ/QC): 64 full + tail 8

typedef __attribute__((ext_vector_type(8))) short bf16x8;
typedef __attribute__((ext_vector_type(4))) float f32x4;

__device__ __forceinline__ unsigned short f2bf(float f){
  union { float f; unsigned u; } v; v.f = f;
  unsigned r = v.u + 0x7FFFu + ((v.u >> 16) & 1u);
  return (unsigned short)(r >> 16);
}
__device__ __forceinline__ float bf2f(unsigned short u){
  union { unsigned u; float f; } v; v.u = ((unsigned)u) << 16;
  return v.f;
}
__device__ __forceinline__ float warp_sum(float v){
  #pragma unroll
  for (int o = 32; o; o >>= 1) v += __shfl_xor(v, o);
  return v;
}
__device__ __forceinline__ void gload16(const unsigned short* g, unsigned short* l){
  __builtin_amdgcn_global_load_lds(
      (const __attribute__((address_space(1))) unsigned int*)g,
      (__attribute__((address_space(3))) unsigned int*)l, 16, 0, 0);
}
// swizzled element index for [rows][QC=64] bf16 tiles: spreads b128 row-strided
// reads uniformly over the 8 16B slots of each 128B bank sweep
__device__ __forceinline__ int swz64(int p, int i){
  return p*QC + (i ^ ((p & 7) << 3));
}

// ---------------- K0: both weight matrices f32 -> bf16 in one launch ----------------
__global__ __launch_bounds__(256) void k_f2bf2(
    const float* __restrict__ s1, unsigned short* __restrict__ d1, int n1,
    const float* __restrict__ s2, unsigned short* __restrict__ d2, int n2)
{
  int i = blockIdx.x*256 + threadIdx.x;
  if (i < n1) d1[i] = f2bf(s1[i]);
  else if (i - n1 < n2) d2[i - n1] = f2bf(s2[i - n1]);
}

// ---------------- K1a: image tokens LayerNorm, single-pass (bf16 LDS cache) ----------------
__global__ __launch_bounds__(256) void k_img_ln(
    const float* __restrict__ x, const float* __restrict__ lnw,
    const float* __restrict__ lnb, unsigned short* __restrict__ xnh)
{
  int b = blockIdx.y;
  int l0 = blockIdx.x * 64;
  int t = threadIdx.x;
  int lt = t & 63, cq = t >> 6;
  const float* xb = x + ((size_t)b*CDIM)*NTQ;

  __shared__ unsigned short XC[CDIM][66];
  __shared__ float sA[4][64], s2A[4][64];
  __shared__ float muA[64], rsA[64];

  float s = 0.f, s2 = 0.f;
  for (int c = cq; c < CDIM; c += 4) {
    float v = xb[(size_t)c*NTQ + l0 + lt];
    s += v; s2 = fmaf(v, v, s2);
    XC[c][lt] = f2bf(v);
  }
  sA[cq][lt] = s; s2A[cq][lt] = s2;
  __syncthreads();
  if (t < 64) {
    float ts  = sA[0][t]+sA[1][t]+sA[2][t]+sA[3][t];
    float ts2 = s2A[0][t]+s2A[1][t]+s2A[2][t]+s2A[3][t];
    float mu = ts*(1.0f/CDIM);
    muA[t] = mu;
    rsA[t] = rsqrtf(ts2*(1.0f/CDIM) - mu*mu + 1e-5f);
  }
  __syncthreads();
  for (int idx = t; idx < 64*80; idx += 256) {
    int ch4 = idx % 80, tok = idx / 80;
    int c0 = ch4*4;
    float mu = muA[tok], rs = rsA[tok];
    float4 wv = *(const float4*)(lnw + c0);
    float4 bv = *(const float4*)(lnb + c0);
    unsigned short o[4];
    o[0] = f2bf((bf2f(XC[c0+0][tok]) - mu)*rs*wv.x + bv.x);
    o[1] = f2bf((bf2f(XC[c0+1][tok]) - mu)*rs*wv.y + bv.y);
    o[2] = f2bf((bf2f(XC[c0+2][tok]) - mu)*rs*wv.z + bv.z);
    o[3] = f2bf((bf2f(XC[c0+3][tok]) - mu)*rs*wv.w + bv.w);
    *(uint2*)&xnh[((size_t)(b*LQ) + l0 + tok)*CDIM + c0] = *(const uint2*)o;
  }
}

// ---------------- K1b: point tokens + LayerNorm ----------------
__global__ __launch_bounds__(320) void k_pt_ln(
    const float* __restrict__ pcoords, const float* __restrict__ lnw,
    const float* __restrict__ lnb, const float* __restrict__ pgauss,
    const float* __restrict__ pemb_w, const float* __restrict__ nap,
    const int* __restrict__ plabels, unsigned short* __restrict__ xnh)
{
  int j = blockIdx.x, b = blockIdx.y;
  int c = threadIdx.x;
  int f = (c < 160) ? c : c - 160;
  float p0 = pcoords[(b*8+j)*3+0]*(2.0f/16.0f) - 1.0f;
  float p1 = pcoords[(b*8+j)*3+1]*(2.0f/16.0f) - 1.0f;
  float p2 = pcoords[(b*8+j)*3+2]*(2.0f/16.0f) - 1.0f;
  float pe = 6.283185307179586f*(p0*pgauss[f] + p1*pgauss[160+f] + p2*pgauss[320+f]);
  float pv = (c < 160) ? sinf(pe) : cosf(pe);
  int lab = plabels[b*8+j];
  float val;
  if (lab == -1) val = nap[c];
  else {
    int safe = lab < 0 ? 0 : (lab > 1 ? 1 : lab);
    val = pv + pemb_w[safe*CDIM + c];
  }
  float s  = warp_sum(val);
  float s2 = warp_sum(val*val);
  __shared__ float r1[5], r2[5];
  int w = threadIdx.x >> 6, lane = threadIdx.x & 63;
  if (lane == 0) { r1[w] = s; r2[w] = s2; }
  __syncthreads();
  float ts = 0.f, ts2 = 0.f;
  #pragma unroll
  for (int i = 0; i < 5; i++) { ts += r1[i]; ts2 += r2[i]; }
  float mu  = ts * (1.0f/CDIM);
  float var = ts2 * (1.0f/CDIM) - mu*mu;
  float rsig = rsqrtf(var + 1e-5f);
  xnh[((size_t)b*LQ + NTQ + j)*CDIM + c] = f2bf((val - mu)*rsig*lnw[c] + lnb[c]);
}

// ---------------- K2: zxh = xn @ w1^T via MFMA + global_load_lds, XCD-swizzled ----------------
__global__ __launch_bounds__(256) void k_gemm1_mfma(
    const unsigned short* __restrict__ Abf, const unsigned short* __restrict__ Wbf,
    unsigned short* __restrict__ zxh, float* __restrict__ dtraw)
{
  __shared__ unsigned short As[128*32];
  __shared__ unsigned short Bs[128*32];
  int id = blockIdx.x;
  int xcd = id & 7, pos = id >> 3;
  const int q = 177, r = 3;
  int swz = (xcd < r ? xcd*(q+1) : r*(q+1) + (xcd-r)*q) + pos;
  int m0 = (swz / 11) * 128;
  int n0 = (swz % 11) * 128;
  int tid = threadIdx.x;
  int lane = tid & 63, wid = tid >> 6;
  int wr = wid >> 1, wc = wid & 1;
  int fr = lane & 15, fq = lane >> 4;

  int srow = lane >> 2;
  int scol = (lane & 3) * 8;

  f32x4 acc[4][4] = {};
  for (int k0 = 0; k0 < CDIM; k0 += 32) {
    #pragma unroll
    for (int i = 0; i < 2; i++) {
      int seg = wid + i*4;
      int rowA = seg*16 + srow;
      int ga = m0 + rowA; if (ga > MQ-1) ga = MQ-1;
      gload16(Abf + (size_t)ga*CDIM + k0 + scol, &As[seg*512]);
      int gb = n0 + rowA; if (gb > DIP-1) gb = DIP-1;
      gload16(Wbf + (size_t)gb*CDIM + k0 + scol, &Bs[seg*512]);
    }
    __syncthreads();
    bf16x8 fa[4], fb[4];
    #pragma unroll
    for (int i = 0; i < 4; i++) {
      fa[i] = *(const bf16x8*)&As[(wr*64 + i*16 + fr)*32 + fq*8];
      fb[i] = *(const bf16x8*)&Bs[(wc*64 + i*16 + fr)*32 + fq*8];
    }
    #pragma unroll
    for (int i = 0; i < 4; i++)
      #pragma unroll
      for (int j = 0; j < 4; j++)
        acc[i][j] = __builtin_amdgcn_mfma_f32_16x16x32_bf16(fa[i], fb[j], acc[i][j], 0, 0, 0);
    __syncthreads();
  }
  #pragma unroll
  for (int i = 0; i < 4; i++) {
    #pragma unroll
    for (int j = 0; j < 4; j++) {
      #pragma unroll
      for (int rr = 0; rr < 4; rr++) {
        int grow = m0 + wr*64 + i*16 + fq*4 + rr;
        int gcol = n0 + wc*64 + j*16 + fr;
        if (grow < MQ && gcol < DIP) {
          float v = acc[i][j][rr];
          zxh[(size_t)grow*DIP + gcol] = f2bf(v);
          if (gcol >= DI + CONVD)
            dtraw[(size_t)grow*NH + (gcol - (DI + CONVD))] = v;
        }
      }
    }
  }
}

// ---------------- K4: depthwise causal conv(4) + SiLU, register-tiled x8 tokens ----------------
__global__ __launch_bounds__(256) void k_conv(
    const unsigned short* __restrict__ zxh, const float* __restrict__ cw,
    const float* __restrict__ cb, unsigned short* __restrict__ xcb)
{
  const int nC4 = CONVD/4;            // 176
  int gid = blockIdx.x*256 + threadIdx.x;
  if (gid >= (MQ/8)*nC4) return;
  int c4 = gid % nC4;
  int mb = gid / nC4;
  int m0 = mb*8;                      // octets never cross batch boundary (4104 % 8 == 0)
  int l0 = m0 % LQ;
  int c0 = c4*4;
  float4 cbv = *(const float4*)(cb + c0);
  float4 w0 = *(const float4*)(cw + (c0+0)*4);
  float4 w1 = *(const float4*)(cw + (c0+1)*4);
  float4 w2 = *(const float4*)(cw + (c0+2)*4);
  float4 w3 = *(const float4*)(cw + (c0+3)*4);
  const float* wp[4] = {(const float*)&w0, (const float*)&w1,
                        (const float*)&w2, (const float*)&w3};
  float vals[11][4];
  #pragma unroll
  for (int r = 0; r < 11; r++) {
    int ls = l0 - 3 + r;
    uint2 u = make_uint2(0,0);
    if (ls >= 0)
      u = *(const uint2*)(zxh + (size_t)(m0-3+r)*DIP + DI + c0);
    vals[r][0] = bf2f((unsigned short)(u.x & 0xffff));
    vals[r][1] = bf2f((unsigned short)(u.x >> 16));
    vals[r][2] = bf2f((unsigned short)(u.y & 0xffff));
    vals[r][3] = bf2f((unsigned short)(u.y >> 16));
  }
  const float* cbp = (const float*)&cbv;
  #pragma unroll
  for (int u = 0; u < 8; u++) {
    unsigned short o[4];
    #pragma unroll
    for (int ch = 0; ch < 4; ch++) {
      float a = cbp[ch];
      #pragma unroll
      for (int j = 0; j < 4; j++)
        a = fmaf(vals[u+j][ch], wp[ch][j], a);
      o[ch] = f2bf(a / (1.f + __expf(-a)));
    }
    *(uint2*)(xcb + (size_t)(m0+u)*CONVD + c0) = *(const uint2*)o;
  }
}

// ---------------- K5ab: fused softplus+cumsum + chunk end-state MFMA ----------------
__global__ __launch_bounds__(256) void k_cumsum_state(
    const float* __restrict__ dtraw, const float* __restrict__ dt_bias,
    const float* __restrict__ A_log, const unsigned short* __restrict__ xcb,
    float* __restrict__ dtb, float* __restrict__ cs, float* __restrict__ Dc,
    float* __restrict__ Sbuf)
{
  int c = blockIdx.x, h = blockIdx.y, b = blockIdx.z;
  int len = LQ - c*QC; if (len > QC) len = QC;
  int t = threadIdx.x;
  int lane = t & 63, wid = t >> 6;
  int fr = lane & 15, fq = lane >> 4;
  int m0 = b*LQ + c*QC;

  __shared__ unsigned short XT[HD*QC];    // swizzled
  __shared__ unsigned short BwT[DS*QC];   // swizzled
  __shared__ float sm[QC], dtl[QC], ws[QC];

  // stage X^T early
  for (int idx = t; idx < (HD/8)*QC; idx += 256) {   // 640
    int pg = idx % 10, i = idx / 10;
    uint4 v = make_uint4(0,0,0,0);
    if (i < len)
      v = *(const uint4*)(xcb + (size_t)(m0+i)*CONVD + h*HD + pg*8);
    union { uint4 u; unsigned short us[8]; } cv; cv.u = v;
    #pragma unroll
    for (int e = 0; e < 8; e++)
      XT[swz64(pg*8+e, i)] = cv.us[e];
  }

  float A = -expf(A_log[h]);
  if (t < QC) {
    float sp = 0.f;
    if (t < len) {
      float v = dtraw[((size_t)(m0+t))*NH + h] + dt_bias[h];
      sp = (v > 20.f) ? v : log1pf(expf(v));
      dtb[((size_t)(m0+t))*NH + h] = sp;
    }
    dtl[t] = sp;
    sm[t] = sp * A;
  }
  __syncthreads();
  for (int off = 1; off < QC; off <<= 1) {
    float v = 0.f;
    if (t < QC && t >= off) v = sm[t-off];
    __syncthreads();
    if (t < QC) sm[t] += v;
    __syncthreads();
  }
  if (t < QC) cs[((size_t)(b*NH+h)*NC + c)*QC + t] = sm[t];
  if (t == len-1) Dc[(b*NH+h)*NC + c] = expf(sm[t]);
  if (t < QC) ws[t] = (t < len) ? __expf(sm[len-1] - sm[t]) * dtl[t] : 0.f;
  __syncthreads();
  for (int idx = t; idx < DS*QC; idx += 256) {   // 2048
    int n = idx & 31, i = idx >> 5;
    float v = (i < len) ? bf2f(xcb[(size_t)(m0+i)*CONVD + DI + n]) * ws[i] : 0.f;
    BwT[swz64(n, i)] = f2bf(v);
  }
  __syncthreads();

  size_t base = ((size_t)(b*NC + c)*NH + h)*(HD*DS);
  for (int tp = wid; tp < 10; tp += 4) {
    int pi = tp >> 1, ni = tp & 1;
    f32x4 acc = {};
    #pragma unroll
    for (int ks = 0; ks < 2; ks++) {
      bf16x8 fa = *(const bf16x8*)&XT[swz64(pi*16 + fr, ks*32 + fq*8)];
      bf16x8 fb = *(const bf16x8*)&BwT[swz64(ni*16 + fr, ks*32 + fq*8)];
      acc = __builtin_amdgcn_mfma_f32_16x16x32_bf16(fa, fb, acc, 0, 0, 0);
    }
    #pragma unroll
    for (int rr = 0; rr < 4; rr++)
      Sbuf[base + (size_t)(pi*16 + fq*4 + rr)*DS + ni*16 + fr] = acc[rr];
  }
}

// ---------------- K5c: sequential scan over chunk states (in-place H0) ----------------
__global__ __launch_bounds__(256) void k_state_scan(
    float* __restrict__ Sbuf, const float* __restrict__ Dc,
    float* __restrict__ H0)
{
  int tid = blockIdx.x*256 + threadIdx.x;
  int pn = tid % (HD*DS);
  int bh = tid / (HD*DS);
  int b = bh >> 3, h = bh & 7;
  float hst = 0.f;
  for (int c = 0; c < NC; c++) {
    size_t idx = ((size_t)(b*NC + c)*NH + h)*(HD*DS) + pn;
    float sv = Sbuf[idx];
    H0[idx] = hst;
    hst = hst * Dc[bh*NC + c] + sv;
  }
}

// ---------------- K5d: per-chunk outputs (QC=64): 4 waves x 16 rows ----------------
__global__ __launch_bounds__(256) void k_chunk_y_mfma(
    const unsigned short* __restrict__ xcb, const unsigned short* __restrict__ zxh,
    const float* __restrict__ dtb, const float* __restrict__ cs,
    const float* __restrict__ H0, const float* __restrict__ Dp,
    unsigned short* __restrict__ ygb)
{
  int c = blockIdx.x, h = blockIdx.y, b = blockIdx.z;
  int len = LQ - c*QC; if (len > QC) len = QC;
  int t = threadIdx.x;
  int lane = t & 63, wid = t >> 6;
  int fr = lane & 15, fq = lane >> 4;
  int m0 = b*LQ + c*QC;

  __shared__ unsigned short XT[HD*QC];     // swizzled
  __shared__ unsigned short Wt[4*16*32];   // per-wave swizzled W tile
  __shared__ float slA[QC], dtlA[QC], elA[QC];

  const float* csb = cs + ((size_t)(b*NH+h)*NC + c)*QC;

  for (int idx = t; idx < (HD/8)*QC; idx += 256) {   // 640
    int pg = idx % 10, i = idx / 10;
    uint4 v = make_uint4(0,0,0,0);
    if (i < len)
      v = *(const uint4*)(xcb + (size_t)(m0+i)*CONVD + h*HD + pg*8);
    union { uint4 u; unsigned short us[8]; } cv; cv.u = v;
    #pragma unroll
    for (int e = 0; e < 8; e++)
      XT[swz64(pg*8+e, i)] = cv.us[e];
  }
  if (t < QC) {
    float s = csb[t];
    slA[t] = s;
    elA[t] = __expf(s);
    dtlA[t] = (t < len) ? dtb[((size_t)(m0+t))*NH + h] : 0.f;
  }
  __syncthreads();   // the only barrier

  // C fragment: this wave's 16 output rows, direct global
  int row16 = wid*16 + fr;
  bf16x8 fa = {};
  if (row16 < len)
    fa = *(const bf16x8*)(xcb + (size_t)(m0+row16)*CONVD + DI + DS + fq*8);

  // inter-chunk: C @ H0^T (H0 direct global, f32->bf16 in-register), scale exp(s_l)
  size_t hb = ((size_t)(b*NC + c)*NH + h)*(HD*DS);
  f32x4 acc[5];
  #pragma unroll
  for (int j = 0; j < 5; j++) {
    int p = j*16 + fr;
    const float* hp = H0 + hb + (size_t)p*DS + fq*8;
    float4 ha = *(const float4*)hp;
    float4 hbv = *(const float4*)(hp + 4);
    bf16x8 fb;
    fb[0]=(short)f2bf(ha.x);  fb[1]=(short)f2bf(ha.y);
    fb[2]=(short)f2bf(ha.z);  fb[3]=(short)f2bf(ha.w);
    fb[4]=(short)f2bf(hbv.x); fb[5]=(short)f2bf(hbv.y);
    fb[6]=(short)f2bf(hbv.z); fb[7]=(short)f2bf(hbv.w);
    f32x4 z = {};
    acc[j] = __builtin_amdgcn_mfma_f32_16x16x32_bf16(fa, fb, z, 0, 0, 0);
  }
  #pragma unroll
  for (int rr = 0; rr < 4; rr++) {
    float el = elA[wid*16 + fq*4 + rr];
    #pragma unroll
    for (int j = 0; j < 5; j++) acc[j][rr] *= el;
  }

  // intra-chunk: 2 sub-tiles of 32 tokens; B fragments direct global
  int wbase = wid << 9;   // 16*32 per wave
  for (int sc = 0; sc < 2; sc++) {
    int i0 = sc*32;
    #pragma unroll
    for (int jt = 0; jt < 2; jt++) {
      int col = i0 + jt*16 + fr;
      bf16x8 fbv = {};
      if (col < len)
        fbv = *(const bf16x8*)(xcb + (size_t)(m0+col)*CONVD + DI + fq*8);
      float sc_col = slA[col], dt_col = dtlA[col];
      f32x4 z = {};
      f32x4 g = __builtin_amdgcn_mfma_f32_16x16x32_bf16(fa, fbv, z, 0, 0, 0);
      #pragma unroll
      for (int rr = 0; rr < 4; rr++) {
        int lr = fq*4 + rr;
        int row = wid*16 + lr;
        float v = 0.f;
        if (col <= row)
          v = g[rr] * __expf(slA[row] - sc_col) * dt_col;
        int lc = jt*16 + fr;
        int slot = (lc >> 3) ^ (lr & 3);
        Wt[wbase + (lr<<5) + (slot<<3) + (lc&7)] = f2bf(v);
      }
    }
    // PV: acc += W @ X^T (same-wave LDS write->read, in-order)
    bf16x8 wa = *(const bf16x8*)&Wt[wbase + (fr<<5) + ((fq ^ (fr&3))<<3)];
    #pragma unroll
    for (int j = 0; j < 5; j++) {
      int p = j*16 + fr;
      bf16x8 xb = *(const bf16x8*)&XT[swz64(p, i0 + fq*8)];
      acc[j] = __builtin_amdgcn_mfma_f32_16x16x32_bf16(wa, xb, acc[j], 0, 0, 0);
    }
  }

  // epilogue: Dp skip (x from XT) + z-gate, bf16 store
  float dpv = Dp[h];
  #pragma unroll
  for (int rr = 0; rr < 4; rr++) {
    int l = wid*16 + fq*4 + rr;
    if (l >= len) continue;
    size_t m = m0 + l;
    #pragma unroll
    for (int j = 0; j < 5; j++) {
      int p = j*16 + fr;
      int cc = h*HD + p;
      float xv = bf2f(XT[swz64(p, l)]);
      float y = acc[j][rr] + xv*dpv;
      float zv = bf2f(zxh[m*DIP + cc]);
      y *= zv / (1.f + __expf(-zv));
      ygb[m*DI + cc] = f2bf(y);
    }
  }
}

// ---------------- K6: RMS + scale, in-place on bf16 ----------------
__global__ __launch_bounds__(256) void k_rms_scale(
    unsigned short* __restrict__ ygb, const float* __restrict__ rsw)
{
  int m = blockIdx.x;
  int t = threadIdx.x;
  unsigned short* row = ygb + (size_t)m*DI;
  float v0=0.f, v1=0.f, v2=0.f, v3=0.f;
  float ss = 0.f;
  if (t < 160) {
    uint2 u = *(const uint2*)(row + t*4);
    v0 = bf2f((unsigned short)(u.x & 0xffff));
    v1 = bf2f((unsigned short)(u.x >> 16));
    v2 = bf2f((unsigned short)(u.y & 0xffff));
    v3 = bf2f((unsigned short)(u.y >> 16));
    ss = v0*v0 + v1*v1 + v2*v2 + v3*v3;
  }
  ss = warp_sum(ss);
  __shared__ float rsh[4];
  if ((t & 63) == 0) rsh[t>>6] = ss;
  __syncthreads();
  float tot = rsh[0] + rsh[1] + rsh[2] + rsh[3];
  float rsv = rsqrtf(tot*(1.0f/DI) + 1e-5f);
  if (t < 160) {
    float4 wv = *(const float4*)(rsw + t*4);
    unsigned short o[4];
    o[0] = f2bf(v0*rsv*wv.x);
    o[1] = f2bf(v1*rsv*wv.y);
    o[2] = f2bf(v2*rsv*wv.z);
    o[3] = f2bf(v3*rsv*wv.w);
    *(uint2*)(row + t*4) = *(const uint2*)o;
  }
}

// ---------------- K7: out^T = w2 @ ygb^T via MFMA + global_load_lds, XCD-swizzled ----------------
__global__ __launch_bounds__(256) void k_gemm2_mfma(
    const unsigned short* __restrict__ W2h, const unsigned short* __restrict__ Ygh,
    float* __restrict__ out)
{
  __shared__ unsigned short As[128*32];
  __shared__ unsigned short Bs[128*32];
  int id = blockIdx.x;
  int xcd = id & 7, pos = id >> 3;
  const int q = 48, r = 3;
  int swz = (xcd < r ? xcd*(q+1) : r*(q+1) + (xcd-r)*q) + pos;
  int c0 = (swz % 3) * 128;
  int t0 = (swz / 3) * 128;
  int tid = threadIdx.x;
  int lane = tid & 63, wid = tid >> 6;
  int wr = wid >> 1, wc = wid & 1;
  int fr = lane & 15, fq = lane >> 4;

  int srow = lane >> 2;
  int scol = (lane & 3) * 8;

  f32x4 acc[4][4] = {};
  for (int k0 = 0; k0 < DI; k0 += 32) {
    #pragma unroll
    for (int i = 0; i < 2; i++) {
      int seg = wid + i*4;
      int rowA = seg*16 + srow;
      int ga = c0 + rowA; if (ga > CDIM-1) ga = CDIM-1;
      gload16(W2h + (size_t)ga*DI + k0 + scol, &As[seg*512]);
      int gb = t0 + rowA; if (gb > MQ-1) gb = MQ-1;
      gload16(Ygh + (size_t)gb*DI + k0 + scol, &Bs[seg*512]);
    }
    __syncthreads();
    bf16x8 fa[4], fb[4];
    #pragma unroll
    for (int i = 0; i < 4; i++) {
      fa[i] = *(const bf16x8*)&As[(wr*64 + i*16 + fr)*32 + fq*8];
      fb[i] = *(const bf16x8*)&Bs[(wc*64 + i*16 + fr)*32 + fq*8];
    }
    #pragma unroll
    for (int i = 0; i < 4; i++)
      #pragma unroll
      for (int j = 0; j < 4; j++)
        acc[i][j] = __builtin_amdgcn_mfma_f32_16x16x32_bf16(fa[i], fb[j], acc[i][j], 0, 0, 0);
    __syncthreads();
  }
  #pragma unroll
  for (int i = 0; i < 4; i++) {
    #pragma unroll
    for (int j = 0; j < 4; j++) {
      #pragma unroll
      for (int rr = 0; rr < 4; rr++) {
        int ch  = c0 + wr*64 + i*16 + fq*4 + rr;
        int tok = t0 + wc*64 + j*16 + fr;
        if (ch < CDIM && tok < MQ) {
          int b = tok / LQ, l = tok % LQ;
          if (l < NTQ)
            out[((size_t)(b*CDIM + ch))*NTQ + l] = acc[i][j][rr];
        }
      }
    }
  }
}

extern "C" void kernel_launch(void* const* d_in, const int* in_sizes, int n_in,
                              void* d_out, int out_size, void* d_ws, size_t ws_size,
                              hipStream_t stream)
{
  const float* x       = (const float*)d_in[0];
  const float* pc      = (const float*)d_in[1];
  const float* lnw     = (const float*)d_in[2];
  const float* lnb     = (const float*)d_in[3];
  const float* w1      = (const float*)d_in[4];
  const float* cw      = (const float*)d_in[5];
  const float* cb      = (const float*)d_in[6];
  const float* dt_bias = (const float*)d_in[7];
  const float* A_log   = (const float*)d_in[8];
  const float* Dp      = (const float*)d_in[9];
  const float* rsw     = (const float*)d_in[10];
  const float* w2      = (const float*)d_in[11];
  const float* pg      = (const float*)d_in[12];
  const float* pew     = (const float*)d_in[13];
  const float* nap     = (const float*)d_in[14];
  const int*   plab    = (const int*)d_in[15];
  float* out = (float*)d_out;

  unsigned short* xnh  = (unsigned short*)d_ws;                     // MQ*CDIM bf16
  unsigned short* zxh  = xnh + (size_t)MQ*CDIM;                     // MQ*DIP bf16
  float* dtraw = (float*)(zxh + (size_t)MQ*DIP);                    // MQ*NH f32
  unsigned short* xcb  = (unsigned short*)(dtraw + (size_t)MQ*NH);  // MQ*CONVD bf16
  float* dtb = (float*)(xcb + (size_t)MQ*CONVD);                    // MQ*NH f32
  float* cs  = dtb + (size_t)MQ*NH;                                 // B*NH*NC*QC
  float* Dc  = cs  + (size_t)BQ*NH*NC*QC;                           // B*NH*NC
  float* Sb  = Dc  + (size_t)BQ*NH*NC;                              // B*NC*NH*HD*DS
  float* H0  = Sb;                                                  // in-place alias
  unsigned short* ygb = (unsigned short*)(Sb + (size_t)BQ*NC*NH*HD*DS); // MQ*DI bf16
  unsigned short* w1h = ygb + (size_t)MQ*DI;                        // DIP*CDIM bf16
  unsigned short* w2h = w1h + (size_t)DIP*CDIM;                     // CDIM*DI bf16

  k_f2bf2<<<(DIP*CDIM + CDIM*DI + 255)/256, 256, 0, stream>>>(
      w1, w1h, DIP*CDIM, w2, w2h, CDIM*DI);
  dim3 gi(NTQ/64, BQ);
  k_img_ln<<<gi, 256, 0, stream>>>(x, lnw, lnb, xnh);
  dim3 gp(8, BQ);
  k_pt_ln<<<gp, 320, 0, stream>>>(pc, lnw, lnb, pg, pew, nap, plab, xnh);
  k_gemm1_mfma<<<129*11, 256, 0, stream>>>(xnh, w1h, zxh, dtraw);
  k_conv<<<((MQ/8)*(CONVD/4) + 255)/256, 256, 0, stream>>>(zxh, cw, cb, xcb);
  dim3 gc(NC, NH, BQ);
  k_cumsum_state<<<gc, 256, 0, stream>>>(dtraw, dt_bias, A_log, xcb, dtb, cs, Dc, Sb);
  k_state_scan<<<(BQ*NH*HD*DS)/256, 256, 0, stream>>>(Sb, Dc, H0);
  k_chunk_y_mfma<<<gc, 256, 0, stream>>>(xcb, zxh, dtb, cs, H0, Dp, ygb);
  k_rms_scale<<<MQ, 256, 0, stream>>>(ygb, rsw);
  k_gemm2_mfma<<<129*3, 256, 0, stream>>>(w2h, ygb, out);
}

// Round 9
// 167.041 us; speedup vs baseline: 22.9711x; 1.1096x over previous
//
#include <hip/hip_runtime.h>
#include <math.h>

#define BQ 4
#define LQ 4104
#define NTQ 4096
#define CDIM 320
#define DIP 1352
#define DI 640
#define CONVD 704
#define NH 8
#define HD 80
#define DS 32
#define MQ (BQ*LQ)   // 16416
#define QC 64        // chunk length
#define NC 65        // ceil(LQ/QC)

typedef __attribute__((ext_vector_type(8))) short bf16x8;
typedef __attribute__((ext_vector_type(4))) float f32x4;

__device__ __forceinline__ unsigned short f2bf(float f){
  union { float f; unsigned u; } v; v.f = f;
  unsigned r = v.u + 0x7FFFu + ((v.u >> 16) & 1u);
  return (unsigned short)(r >> 16);
}
__device__ __forceinline__ float bf2f(unsigned short u){
  union { unsigned u; float f; } v; v.u = ((unsigned)u) << 16;
  return v.f;
}
__device__ __forceinline__ float warp_sum(float v){
  #pragma unroll
  for (int o = 32; o; o >>= 1) v += __shfl_xor(v, o);
  return v;
}
__device__ __forceinline__ void gload16(const unsigned short* g, unsigned short* l){
  __builtin_amdgcn_global_load_lds(
      (const __attribute__((address_space(1))) unsigned int*)g,
      (__attribute__((address_space(3))) unsigned int*)l, 16, 0, 0);
}
__device__ __forceinline__ int swz64(int p, int i){
  return p*QC + (i ^ ((p & 7) << 3));
}

// ---------------- K0: weights f32 -> bf16 ----------------
__global__ __launch_bounds__(256) void k_f2bf2(
    const float* __restrict__ s1, unsigned short* __restrict__ d1, int n1,
    const float* __restrict__ s2, unsigned short* __restrict__ d2, int n2)
{
  int i = blockIdx.x*256 + threadIdx.x;
  if (i < n1) d1[i] = f2bf(s1[i]);
  else if (i - n1 < n2) d2[i - n1] = f2bf(s2[i - n1]);
}

// ---------------- K1pre: zero the LN stats accumulators ----------------
__global__ __launch_bounds__(256) void k_zero(float* __restrict__ p, int n)
{
  int i = blockIdx.x*256 + threadIdx.x;
  if (i < n) p[i] = 0.f;
}

// ---------------- K1a: LN stats via channel-sliced atomics ----------------
__global__ __launch_bounds__(256) void k_stats(
    const float* __restrict__ x, float* __restrict__ muS, float* __restrict__ s2S)
{
  int b = blockIdx.z;
  int cs0 = blockIdx.y * 40;
  int tok = blockIdx.x*256 + threadIdx.x;
  const float* xb = x + ((size_t)b*CDIM)*NTQ;
  float s = 0.f, s2 = 0.f;
  #pragma unroll 8
  for (int c = cs0; c < cs0 + 40; c++) {
    float v = xb[(size_t)c*NTQ + tok];
    s += v; s2 = fmaf(v, v, s2);
  }
  atomicAdd(&muS[b*NTQ + tok], s);
  atomicAdd(&s2S[b*NTQ + tok], s2);
}

// ---------------- K1b: normalize + transpose -> xnh bf16 ----------------
__global__ __launch_bounds__(256) void k_norm_t(
    const float* __restrict__ x, const float* __restrict__ muS,
    const float* __restrict__ s2S, const float* __restrict__ lnw,
    const float* __restrict__ lnb, unsigned short* __restrict__ xnh)
{
  int b = blockIdx.z;
  int c0 = blockIdx.y * 64;
  int t0 = blockIdx.x * 64;
  int t = threadIdx.x;
  int lt = t & 63, cg = t >> 6;
  const float* xb = x + ((size_t)b*CDIM)*NTQ;

  __shared__ unsigned short T[64][72];
  __shared__ float muL[64], rsL[64];
  if (t < 64) {
    float s  = muS[b*NTQ + t0 + t];
    float s2 = s2S[b*NTQ + t0 + t];
    float mu = s*(1.0f/CDIM);
    muL[t] = mu;
    rsL[t] = rsqrtf(s2*(1.0f/CDIM) - mu*mu + 1e-5f);
  }
  __syncthreads();
  float mu = muL[lt], rs = rsL[lt];
  #pragma unroll
  for (int c = cg; c < 64; c += 4) {
    float v = xb[(size_t)(c0+c)*NTQ + t0 + lt];
    T[lt][c] = f2bf((v - mu)*rs*lnw[c0+c] + lnb[c0+c]);
  }
  __syncthreads();
  #pragma unroll
  for (int i = 0; i < 4; i++) {
    int idx = t + 256*i;
    int tok = idx >> 4, cq = idx & 15;
    *(uint2*)&xnh[((size_t)(b*LQ) + t0 + tok)*CDIM + c0 + cq*4] =
        *(const uint2*)&T[tok][cq*4];
  }
}

// ---------------- K1c: point tokens + LayerNorm ----------------
__global__ __launch_bounds__(320) void k_pt_ln(
    const float* __restrict__ pcoords, const float* __restrict__ lnw,
    const float* __restrict__ lnb, const float* __restrict__ pgauss,
    const float* __restrict__ pemb_w, const float* __restrict__ nap,
    const int* __restrict__ plabels, unsigned short* __restrict__ xnh)
{
  int j = blockIdx.x, b = blockIdx.y;
  int c = threadIdx.x;
  int f = (c < 160) ? c : c - 160;
  float p0 = pcoords[(b*8+j)*3+0]*(2.0f/16.0f) - 1.0f;
  float p1 = pcoords[(b*8+j)*3+1]*(2.0f/16.0f) - 1.0f;
  float p2 = pcoords[(b*8+j)*3+2]*(2.0f/16.0f) - 1.0f;
  float pe = 6.283185307179586f*(p0*pgauss[f] + p1*pgauss[160+f] + p2*pgauss[320+f]);
  float pv = (c < 160) ? sinf(pe) : cosf(pe);
  int lab = plabels[b*8+j];
  float val;
  if (lab == -1) val = nap[c];
  else {
    int safe = lab < 0 ? 0 : (lab > 1 ? 1 : lab);
    val = pv + pemb_w[safe*CDIM + c];
  }
  float s  = warp_sum(val);
  float s2 = warp_sum(val*val);
  __shared__ float r1[5], r2[5];
  int w = threadIdx.x >> 6, lane = threadIdx.x & 63;
  if (lane == 0) { r1[w] = s; r2[w] = s2; }
  __syncthreads();
  float ts = 0.f, ts2 = 0.f;
  #pragma unroll
  for (int i = 0; i < 5; i++) { ts += r1[i]; ts2 += r2[i]; }
  float mu  = ts * (1.0f/CDIM);
  float var = ts2 * (1.0f/CDIM) - mu*mu;
  float rsig = rsqrtf(var + 1e-5f);
  xnh[((size_t)b*LQ + NTQ + j)*CDIM + c] = f2bf((val - mu)*rsig*lnw[c] + lnb[c]);
}

// ---------------- K2: zxh = xn @ w1^T via MFMA + global_load_lds ----------------
__global__ __launch_bounds__(256) void k_gemm1_mfma(
    const unsigned short* __restrict__ Abf, const unsigned short* __restrict__ Wbf,
    unsigned short* __restrict__ zxh, float* __restrict__ dtraw)
{
  __shared__ unsigned short As[128*32];
  __shared__ unsigned short Bs[128*32];
  int id = blockIdx.x;
  int xcd = id & 7, pos = id >> 3;
  const int q = 177, r = 3;
  int swz = (xcd < r ? xcd*(q+1) : r*(q+1) + (xcd-r)*q) + pos;
  int m0 = (swz / 11) * 128;
  int n0 = (swz % 11) * 128;
  int tid = threadIdx.x;
  int lane = tid & 63, wid = tid >> 6;
  int wr = wid >> 1, wc = wid & 1;
  int fr = lane & 15, fq = lane >> 4;

  int srow = lane >> 2;
  int scol = (lane & 3) * 8;

  f32x4 acc[4][4] = {};
  for (int k0 = 0; k0 < CDIM; k0 += 32) {
    #pragma unroll
    for (int i = 0; i < 2; i++) {
      int seg = wid + i*4;
      int rowA = seg*16 + srow;
      int ga = m0 + rowA; if (ga > MQ-1) ga = MQ-1;
      gload16(Abf + (size_t)ga*CDIM + k0 + scol, &As[seg*512]);
      int gb = n0 + rowA; if (gb > DIP-1) gb = DIP-1;
      gload16(Wbf + (size_t)gb*CDIM + k0 + scol, &Bs[seg*512]);
    }
    __syncthreads();
    bf16x8 fa[4], fb[4];
    #pragma unroll
    for (int i = 0; i < 4; i++) {
      fa[i] = *(const bf16x8*)&As[(wr*64 + i*16 + fr)*32 + fq*8];
      fb[i] = *(const bf16x8*)&Bs[(wc*64 + i*16 + fr)*32 + fq*8];
    }
    #pragma unroll
    for (int i = 0; i < 4; i++)
      #pragma unroll
      for (int j = 0; j < 4; j++)
        acc[i][j] = __builtin_amdgcn_mfma_f32_16x16x32_bf16(fa[i], fb[j], acc[i][j], 0, 0, 0);
    __syncthreads();
  }
  #pragma unroll
  for (int i = 0; i < 4; i++) {
    #pragma unroll
    for (int j = 0; j < 4; j++) {
      #pragma unroll
      for (int rr = 0; rr < 4; rr++) {
        int grow = m0 + wr*64 + i*16 + fq*4 + rr;
        int gcol = n0 + wc*64 + j*16 + fr;
        if (grow < MQ && gcol < DIP) {
          float v = acc[i][j][rr];
          zxh[(size_t)grow*DIP + gcol] = f2bf(v);
          if (gcol >= DI + CONVD)
            dtraw[(size_t)grow*NH + (gcol - (DI + CONVD))] = v;
        }
      }
    }
  }
}

// ---------------- K4: depthwise causal conv(4) + SiLU, register-tiled x8 tokens ----------------
__global__ __launch_bounds__(256) void k_conv(
    const unsigned short* __restrict__ zxh, const float* __restrict__ cw,
    const float* __restrict__ cb, unsigned short* __restrict__ xcb)
{
  const int nC4 = CONVD/4;
  int gid = blockIdx.x*256 + threadIdx.x;
  if (gid >= (MQ/8)*nC4) return;
  int c4 = gid % nC4;
  int mb = gid / nC4;
  int m0 = mb*8;
  int l0 = m0 % LQ;
  int c0 = c4*4;
  float4 cbv = *(const float4*)(cb + c0);
  float4 w0 = *(const float4*)(cw + (c0+0)*4);
  float4 w1 = *(const float4*)(cw + (c0+1)*4);
  float4 w2 = *(const float4*)(cw + (c0+2)*4);
  float4 w3 = *(const float4*)(cw + (c0+3)*4);
  const float* wp[4] = {(const float*)&w0, (const float*)&w1,
                        (const float*)&w2, (const float*)&w3};
  float vals[11][4];
  #pragma unroll
  for (int r = 0; r < 11; r++) {
    int ls = l0 - 3 + r;
    uint2 u = make_uint2(0,0);
    if (ls >= 0)
      u = *(const uint2*)(zxh + (size_t)(m0-3+r)*DIP + DI + c0);
    vals[r][0] = bf2f((unsigned short)(u.x & 0xffff));
    vals[r][1] = bf2f((unsigned short)(u.x >> 16));
    vals[r][2] = bf2f((unsigned short)(u.y & 0xffff));
    vals[r][3] = bf2f((unsigned short)(u.y >> 16));
  }
  const float* cbp = (const float*)&cbv;
  #pragma unroll
  for (int u = 0; u < 8; u++) {
    unsigned short o[4];
    #pragma unroll
    for (int ch = 0; ch < 4; ch++) {
      float a = cbp[ch];
      #pragma unroll
      for (int j = 0; j < 4; j++)
        a = fmaf(vals[u+j][ch], wp[ch][j], a);
      o[ch] = f2bf(a / (1.f + __expf(-a)));
    }
    *(uint2*)(xcb + (size_t)(m0+u)*CONVD + c0) = *(const uint2*)o;
  }
}

// ---------------- K5ab: fused softplus+cumsum + chunk end-state MFMA ----------------
__global__ __launch_bounds__(256) void k_cumsum_state(
    const float* __restrict__ dtraw, const float* __restrict__ dt_bias,
    const float* __restrict__ A_log, const unsigned short* __restrict__ xcb,
    float* __restrict__ dtb, float* __restrict__ cs, float* __restrict__ Dc,
    float* __restrict__ Sbuf)
{
  int c = blockIdx.x, h = blockIdx.y, b = blockIdx.z;
  int len = LQ - c*QC; if (len > QC) len = QC;
  int t = threadIdx.x;
  int lane = t & 63, wid = t >> 6;
  int fr = lane & 15, fq = lane >> 4;
  int m0 = b*LQ + c*QC;

  __shared__ unsigned short XT[HD*QC];
  __shared__ unsigned short BwT[DS*QC];
  __shared__ float sm[QC], dtl[QC], ws[QC];

  for (int idx = t; idx < (HD/8)*QC; idx += 256) {
    int pg = idx % 10, i = idx / 10;
    uint4 v = make_uint4(0,0,0,0);
    if (i < len)
      v = *(const uint4*)(xcb + (size_t)(m0+i)*CONVD + h*HD + pg*8);
    union { uint4 u; unsigned short us[8]; } cv; cv.u = v;
    #pragma unroll
    for (int e = 0; e < 8; e++)
      XT[swz64(pg*8+e, i)] = cv.us[e];
  }

  float A = -expf(A_log[h]);
  if (t < QC) {
    float sp = 0.f;
    if (t < len) {
      float v = dtraw[((size_t)(m0+t))*NH + h] + dt_bias[h];
      sp = (v > 20.f) ? v : log1pf(expf(v));
      dtb[((size_t)(m0+t))*NH + h] = sp;
    }
    dtl[t] = sp;
    sm[t] = sp * A;
  }
  __syncthreads();
  for (int off = 1; off < QC; off <<= 1) {
    float v = 0.f;
    if (t < QC && t >= off) v = sm[t-off];
    __syncthreads();
    if (t < QC) sm[t] += v;
    __syncthreads();
  }
  if (t < QC) cs[((size_t)(b*NH+h)*NC + c)*QC + t] = sm[t];
  if (t == len-1) Dc[(b*NH+h)*NC + c] = expf(sm[t]);
  if (t < QC) ws[t] = (t < len) ? __expf(sm[len-1] - sm[t]) * dtl[t] : 0.f;
  __syncthreads();
  for (int idx = t; idx < DS*QC; idx += 256) {
    int n = idx & 31, i = idx >> 5;
    float v = (i < len) ? bf2f(xcb[(size_t)(m0+i)*CONVD + DI + n]) * ws[i] : 0.f;
    BwT[swz64(n, i)] = f2bf(v);
  }
  __syncthreads();

  size_t base = ((size_t)(b*NC + c)*NH + h)*(HD*DS);
  for (int tp = wid; tp < 10; tp += 4) {
    int pi = tp >> 1, ni = tp & 1;
    f32x4 acc = {};
    #pragma unroll
    for (int ks = 0; ks < 2; ks++) {
      bf16x8 fa = *(const bf16x8*)&XT[swz64(pi*16 + fr, ks*32 + fq*8)];
      bf16x8 fb = *(const bf16x8*)&BwT[swz64(ni*16 + fr, ks*32 + fq*8)];
      acc = __builtin_amdgcn_mfma_f32_16x16x32_bf16(fa, fb, acc, 0, 0, 0);
    }
    #pragma unroll
    for (int rr = 0; rr < 4; rr++)
      Sbuf[base + (size_t)(pi*16 + fq*4 + rr)*DS + ni*16 + fr] = acc[rr];
  }
}

// ---------------- K5c: sequential scan over chunk states (in-place H0) ----------------
__global__ __launch_bounds__(256) void k_state_scan(
    float* __restrict__ Sbuf, const float* __restrict__ Dc,
    float* __restrict__ H0)
{
  int tid = blockIdx.x*256 + threadIdx.x;
  int pn = tid % (HD*DS);
  int bh = tid / (HD*DS);
  int b = bh >> 3, h = bh & 7;
  float hst = 0.f;
  for (int c = 0; c < NC; c++) {
    size_t idx = ((size_t)(b*NC + c)*NH + h)*(HD*DS) + pn;
    float sv = Sbuf[idx];
    H0[idx] = hst;
    hst = hst * Dc[bh*NC + c] + sv;
  }
}

// ---------------- K5d: per-chunk outputs (QC=64): 4 waves x 16 rows ----------------
__global__ __launch_bounds__(256) void k_chunk_y_mfma(
    const unsigned short* __restrict__ xcb, const unsigned short* __restrict__ zxh,
    const float* __restrict__ dtb, const float* __restrict__ cs,
    const float* __restrict__ H0, const float* __restrict__ Dp,
    unsigned short* __restrict__ ygb)
{
  int c = blockIdx.x, h = blockIdx.y, b = blockIdx.z;
  int len = LQ - c*QC; if (len > QC) len = QC;
  int t = threadIdx.x;
  int lane = t & 63, wid = t >> 6;
  int fr = lane & 15, fq = lane >> 4;
  int m0 = b*LQ + c*QC;

  __shared__ unsigned short XT[HD*QC];
  __shared__ unsigned short Wt[4*16*32];
  __shared__ float slA[QC], dtlA[QC], elA[QC];

  const float* csb = cs + ((size_t)(b*NH+h)*NC + c)*QC;

  for (int idx = t; idx < (HD/8)*QC; idx += 256) {
    int pg = idx % 10, i = idx / 10;
    uint4 v = make_uint4(0,0,0,0);
    if (i < len)
      v = *(const uint4*)(xcb + (size_t)(m0+i)*CONVD + h*HD + pg*8);
    union { uint4 u; unsigned short us[8]; } cv; cv.u = v;
    #pragma unroll
    for (int e = 0; e < 8; e++)
      XT[swz64(pg*8+e, i)] = cv.us[e];
  }
  if (t < QC) {
    float s = csb[t];
    slA[t] = s;
    elA[t] = __expf(s);
    dtlA[t] = (t < len) ? dtb[((size_t)(m0+t))*NH + h] : 0.f;
  }
  __syncthreads();

  int row16 = wid*16 + fr;
  bf16x8 fa = {};
  if (row16 < len)
    fa = *(const bf16x8*)(xcb + (size_t)(m0+row16)*CONVD + DI + DS + fq*8);

  size_t hb = ((size_t)(b*NC + c)*NH + h)*(HD*DS);
  f32x4 acc[5];
  #pragma unroll
  for (int j = 0; j < 5; j++) {
    int p = j*16 + fr;
    const float* hp = H0 + hb + (size_t)p*DS + fq*8;
    float4 ha = *(const float4*)hp;
    float4 hbv = *(const float4*)(hp + 4);
    bf16x8 fb;
    fb[0]=(short)f2bf(ha.x);  fb[1]=(short)f2bf(ha.y);
    fb[2]=(short)f2bf(ha.z);  fb[3]=(short)f2bf(ha.w);
    fb[4]=(short)f2bf(hbv.x); fb[5]=(short)f2bf(hbv.y);
    fb[6]=(short)f2bf(hbv.z); fb[7]=(short)f2bf(hbv.w);
    f32x4 z = {};
    acc[j] = __builtin_amdgcn_mfma_f32_16x16x32_bf16(fa, fb, z, 0, 0, 0);
  }
  #pragma unroll
  for (int rr = 0; rr < 4; rr++) {
    float el = elA[wid*16 + fq*4 + rr];
    #pragma unroll
    for (int j = 0; j < 5; j++) acc[j][rr] *= el;
  }

  int wbase = wid << 9;
  for (int sc = 0; sc < 2; sc++) {
    int i0 = sc*32;
    #pragma unroll
    for (int jt = 0; jt < 2; jt++) {
      int col = i0 + jt*16 + fr;
      bf16x8 fbv = {};
      if (col < len)
        fbv = *(const bf16x8*)(xcb + (size_t)(m0+col)*CONVD + DI + fq*8);
      float sc_col = slA[col], dt_col = dtlA[col];
      f32x4 z = {};
      f32x4 g = __builtin_amdgcn_mfma_f32_16x16x32_bf16(fa, fbv, z, 0, 0, 0);
      #pragma unroll
      for (int rr = 0; rr < 4; rr++) {
        int lr = fq*4 + rr;
        int row = wid*16 + lr;
        float v = 0.f;
        if (col <= row)
          v = g[rr] * __expf(slA[row] - sc_col) * dt_col;
        int lc = jt*16 + fr;
        int slot = (lc >> 3) ^ (lr & 3);
        Wt[wbase + (lr<<5) + (slot<<3) + (lc&7)] = f2bf(v);
      }
    }
    bf16x8 wa = *(const bf16x8*)&Wt[wbase + (fr<<5) + ((fq ^ (fr&3))<<3)];
    #pragma unroll
    for (int j = 0; j < 5; j++) {
      int p = j*16 + fr;
      bf16x8 xb = *(const bf16x8*)&XT[swz64(p, i0 + fq*8)];
      acc[j] = __builtin_amdgcn_mfma_f32_16x16x32_bf16(wa, xb, acc[j], 0, 0, 0);
    }
  }

  float dpv = Dp[h];
  #pragma unroll
  for (int rr = 0; rr < 4; rr++) {
    int l = wid*16 + fq*4 + rr;
    if (l >= len) continue;
    size_t m = m0 + l;
    #pragma unroll
    for (int j = 0; j < 5; j++) {
      int p = j*16 + fr;
      int cc = h*HD + p;
      float xv = bf2f(XT[swz64(p, l)]);
      float y = acc[j][rr] + xv*dpv;
      float zv = bf2f(zxh[m*DIP + cc]);
      y *= zv / (1.f + __expf(-zv));
      ygb[m*DI + cc] = f2bf(y);
    }
  }
}

// ---------------- K6: RMS + scale, 8 rows/block, 32-lane groups ----------------
__global__ __launch_bounds__(256) void k_rms_scale(
    unsigned short* __restrict__ ygb, const float* __restrict__ rsw)
{
  int t = threadIdx.x;
  int grp = t >> 5;              // 8 row-groups per block
  int gl = t & 31;
  size_t m = (size_t)blockIdx.x*8 + grp;
  unsigned short* row = ygb + m*DI;
  float v[5][4];
  float ss = 0.f;
  #pragma unroll
  for (int k = 0; k < 5; k++) {
    uint2 u = *(const uint2*)(row + (gl + 32*k)*4);
    v[k][0] = bf2f((unsigned short)(u.x & 0xffff));
    v[k][1] = bf2f((unsigned short)(u.x >> 16));
    v[k][2] = bf2f((unsigned short)(u.y & 0xffff));
    v[k][3] = bf2f((unsigned short)(u.y >> 16));
    ss += v[k][0]*v[k][0] + v[k][1]*v[k][1] + v[k][2]*v[k][2] + v[k][3]*v[k][3];
  }
  #pragma unroll
  for (int o = 16; o; o >>= 1) ss += __shfl_xor(ss, o, 32);
  float rsv = rsqrtf(ss*(1.0f/DI) + 1e-5f);
  #pragma unroll
  for (int k = 0; k < 5; k++) {
    float4 wv = *(const float4*)(rsw + (gl + 32*k)*4);
    unsigned short o4[4];
    o4[0] = f2bf(v[k][0]*rsv*wv.x);
    o4[1] = f2bf(v[k][1]*rsv*wv.y);
    o4[2] = f2bf(v[k][2]*rsv*wv.z);
    o4[3] = f2bf(v[k][3]*rsv*wv.w);
    *(uint2*)(row + (gl + 32*k)*4) = *(const uint2*)o4;
  }
}

// ---------------- K7: out^T = w2 @ ygb^T via MFMA + global_load_lds ----------------
__global__ __launch_bounds__(256) void k_gemm2_mfma(
    const unsigned short* __restrict__ W2h, const unsigned short* __restrict__ Ygh,
    float* __restrict__ out)
{
  __shared__ unsigned short As[128*32];
  __shared__ unsigned short Bs[128*32];
  int id = blockIdx.x;
  int xcd = id & 7, pos = id >> 3;
  const int q = 48, r = 3;
  int swz = (xcd < r ? xcd*(q+1) : r*(q+1) + (xcd-r)*q) + pos;
  int c0 = (swz % 3) * 128;
  int t0 = (swz / 3) * 128;
  int tid = threadIdx.x;
  int lane = tid & 63, wid = tid >> 6;
  int wr = wid >> 1, wc = wid & 1;
  int fr = lane & 15, fq = lane >> 4;

  int srow = lane >> 2;
  int scol = (lane & 3) * 8;

  f32x4 acc[4][4] = {};
  for (int k0 = 0; k0 < DI; k0 += 32) {
    #pragma unroll
    for (int i = 0; i < 2; i++) {
      int seg = wid + i*4;
      int rowA = seg*16 + srow;
      int ga = c0 + rowA; if (ga > CDIM-1) ga = CDIM-1;
      gload16(W2h + (size_t)ga*DI + k0 + scol, &As[seg*512]);
      int gb = t0 + rowA; if (gb > MQ-1) gb = MQ-1;
      gload16(Ygh + (size_t)gb*DI + k0 + scol, &Bs[seg*512]);
    }
    __syncthreads();
    bf16x8 fa[4], fb[4];
    #pragma unroll
    for (int i = 0; i < 4; i++) {
      fa[i] = *(const bf16x8*)&As[(wr*64 + i*16 + fr)*32 + fq*8];
      fb[i] = *(const bf16x8*)&Bs[(wc*64 + i*16 + fr)*32 + fq*8];
    }
    #pragma unroll
    for (int i = 0; i < 4; i++)
      #pragma unroll
      for (int j = 0; j < 4; j++)
        acc[i][j] = __builtin_amdgcn_mfma_f32_16x16x32_bf16(fa[i], fb[j], acc[i][j], 0, 0, 0);
    __syncthreads();
  }
  #pragma unroll
  for (int i = 0; i < 4; i++) {
    #pragma unroll
    for (int j = 0; j < 4; j++) {
      #pragma unroll
      for (int rr = 0; rr < 4; rr++) {
        int ch  = c0 + wr*64 + i*16 + fq*4 + rr;
        int tok = t0 + wc*64 + j*16 + fr;
        if (ch < CDIM && tok < MQ) {
          int b = tok / LQ, l = tok % LQ;
          if (l < NTQ)
            out[((size_t)(b*CDIM + ch))*NTQ + l] = acc[i][j][rr];
        }
      }
    }
  }
}

extern "C" void kernel_launch(void* const* d_in, const int* in_sizes, int n_in,
                              void* d_out, int out_size, void* d_ws, size_t ws_size,
                              hipStream_t stream)
{
  const float* x       = (const float*)d_in[0];
  const float* pc      = (const float*)d_in[1];
  const float* lnw     = (const float*)d_in[2];
  const float* lnb     = (const float*)d_in[3];
  const float* w1      = (const float*)d_in[4];
  const float* cw      = (const float*)d_in[5];
  const float* cb      = (const float*)d_in[6];
  const float* dt_bias = (const float*)d_in[7];
  const float* A_log   = (const float*)d_in[8];
  const float* Dp      = (const float*)d_in[9];
  const float* rsw     = (const float*)d_in[10];
  const float* w2      = (const float*)d_in[11];
  const float* pg      = (const float*)d_in[12];
  const float* pew     = (const float*)d_in[13];
  const float* nap     = (const float*)d_in[14];
  const int*   plab    = (const int*)d_in[15];
  float* out = (float*)d_out;

  unsigned short* xnh  = (unsigned short*)d_ws;                     // MQ*CDIM bf16
  unsigned short* zxh  = xnh + (size_t)MQ*CDIM;                     // MQ*DIP bf16
  float* dtraw = (float*)(zxh + (size_t)MQ*DIP);                    // MQ*NH f32
  unsigned short* xcb  = (unsigned short*)(dtraw + (size_t)MQ*NH);  // MQ*CONVD bf16
  float* dtb = (float*)(xcb + (size_t)MQ*CONVD);                    // MQ*NH f32
  float* cs  = dtb + (size_t)MQ*NH;                                 // B*NH*NC*QC
  float* Dc  = cs  + (size_t)BQ*NH*NC*QC;                           // B*NH*NC
  float* Sb  = Dc  + (size_t)BQ*NH*NC;                              // B*NC*NH*HD*DS
  float* H0  = Sb;                                                  // in-place alias
  unsigned short* ygb = (unsigned short*)(Sb + (size_t)BQ*NC*NH*HD*DS); // MQ*DI bf16
  unsigned short* w1h = ygb + (size_t)MQ*DI;                        // DIP*CDIM bf16
  unsigned short* w2h = w1h + (size_t)DIP*CDIM;                     // CDIM*DI bf16
  float* muS = (float*)(w2h + (size_t)CDIM*DI);                     // B*NTQ f32
  float* s2S = muS + (size_t)BQ*NTQ;                                // B*NTQ f32

  k_f2bf2<<<(DIP*CDIM + CDIM*DI + 255)/256, 256, 0, stream>>>(
      w1, w1h, DIP*CDIM, w2, w2h, CDIM*DI);
  k_zero<<<(2*BQ*NTQ + 255)/256, 256, 0, stream>>>(muS, 2*BQ*NTQ);
  dim3 gs(NTQ/256, 8, BQ);
  k_stats<<<gs, 256, 0, stream>>>(x, muS, s2S);
  dim3 gn(NTQ/64, CDIM/64, BQ);
  k_norm_t<<<gn, 256, 0, stream>>>(x, muS, s2S, lnw, lnb, xnh);
  dim3 gp(8, BQ);
  k_pt_ln<<<gp, 320, 0, stream>>>(pc, lnw, lnb, pg, pew, nap, plab, xnh);
  k_gemm1_mfma<<<129*11, 256, 0, stream>>>(xnh, w1h, zxh, dtraw);
  k_conv<<<((MQ/8)*(CONVD/4) + 255)/256, 256, 0, stream>>>(zxh, cw, cb, xcb);
  dim3 gc(NC, NH, BQ);
  k_cumsum_state<<<gc, 256, 0, stream>>>(dtraw, dt_bias, A_log, xcb, dtb, cs, Dc, Sb);
  k_state_scan<<<(BQ*NH*HD*DS)/256, 256, 0, stream>>>(Sb, Dc, H0);
  k_chunk_y_mfma<<<gc, 256, 0, stream>>>(xcb, zxh, dtb, cs, H0, Dp, ygb);
  k_rms_scale<<<MQ/8, 256, 0, stream>>>(ygb, rsw);
  k_gemm2_mfma<<<129*3, 256, 0, stream>>>(w2h, ygb, out);
}

// Round 10
// 159.367 us; speedup vs baseline: 24.0774x; 1.0482x over previous
//
#include <hip/hip_runtime.h>
#include <math.h>

#define BQ 4
#define LQ 4104
#define NTQ 4096
#define CDIM 320
#define DIP 1352
#define DI 640
#define CONVD 704
#define NH 8
#define HD 80
#define DS 32
#define MQ (BQ*LQ)   // 16416
#define QC 64        // chunk length
#define NC 65        // ceil(LQ/QC)

typedef __attribute__((ext_vector_type(8))) short bf16x8;
typedef __attribute__((ext_vector_type(4))) float f32x4;

__device__ __forceinline__ unsigned short f2bf(float f){
  union { float f; unsigned u; } v; v.f = f;
  unsigned r = v.u + 0x7FFFu + ((v.u >> 16) & 1u);
  return (unsigned short)(r >> 16);
}
__device__ __forceinline__ float bf2f(unsigned short u){
  union { unsigned u; float f; } v; v.u = ((unsigned)u) << 16;
  return v.f;
}
__device__ __forceinline__ float warp_sum(float v){
  #pragma unroll
  for (int o = 32; o; o >>= 1) v += __shfl_xor(v, o);
  return v;
}
__device__ __forceinline__ void gload16(const unsigned short* g, unsigned short* l){
  __builtin_amdgcn_global_load_lds(
      (const __attribute__((address_space(1))) unsigned int*)g,
      (__attribute__((address_space(3))) unsigned int*)l, 16, 0, 0);
}
__device__ __forceinline__ int swz64(int p, int i){
  return p*QC + (i ^ ((p & 7) << 3));
}

// ---------------- K0: weights f32 -> bf16, float4-vectorized ----------------
__global__ __launch_bounds__(256) void k_f2bf4(
    const float* __restrict__ s1, unsigned short* __restrict__ d1, int n14,
    const float* __restrict__ s2, unsigned short* __restrict__ d2, int n24)
{
  int i4 = blockIdx.x*256 + threadIdx.x;
  if (i4 < n14) {
    float4 v = ((const float4*)s1)[i4];
    unsigned short o[4] = {f2bf(v.x), f2bf(v.y), f2bf(v.z), f2bf(v.w)};
    *(uint2*)&d1[i4*4] = *(const uint2*)o;
  } else if (i4 - n14 < n24) {
    int j = i4 - n14;
    float4 v = ((const float4*)s2)[j];
    unsigned short o[4] = {f2bf(v.x), f2bf(v.y), f2bf(v.z), f2bf(v.w)};
    *(uint2*)&d2[j*4] = *(const uint2*)o;
  }
}

// ---------------- K1a: LN stats, per-slice partials (no atomics) ----------------
__global__ __launch_bounds__(256) void k_stats(
    const float* __restrict__ x, float* __restrict__ muP, float* __restrict__ s2P)
{
  int b = blockIdx.z;
  int sl = blockIdx.y;
  int cs0 = sl * 40;
  int tok = blockIdx.x*256 + threadIdx.x;
  const float* xb = x + ((size_t)b*CDIM)*NTQ;
  float s = 0.f, s2 = 0.f;
  #pragma unroll 8
  for (int c = cs0; c < cs0 + 40; c++) {
    float v = xb[(size_t)c*NTQ + tok];
    s += v; s2 = fmaf(v, v, s2);
  }
  muP[((size_t)sl*BQ + b)*NTQ + tok] = s;
  s2P[((size_t)sl*BQ + b)*NTQ + tok] = s2;
}

// ---------------- K1b: normalize + transpose -> xnh bf16 ----------------
__global__ __launch_bounds__(256) void k_norm_t(
    const float* __restrict__ x, const float* __restrict__ muP,
    const float* __restrict__ s2P, const float* __restrict__ lnw,
    const float* __restrict__ lnb, unsigned short* __restrict__ xnh)
{
  int b = blockIdx.z;
  int c0 = blockIdx.y * 64;
  int t0 = blockIdx.x * 64;
  int t = threadIdx.x;
  int lt = t & 63, cg = t >> 6;
  const float* xb = x + ((size_t)b*CDIM)*NTQ;

  __shared__ unsigned short T[64][72];
  __shared__ float muL[64], rsL[64];
  if (t < 64) {
    float s = 0.f, s2 = 0.f;
    #pragma unroll
    for (int sl = 0; sl < 8; sl++) {
      s  += muP[((size_t)sl*BQ + b)*NTQ + t0 + t];
      s2 += s2P[((size_t)sl*BQ + b)*NTQ + t0 + t];
    }
    float mu = s*(1.0f/CDIM);
    muL[t] = mu;
    rsL[t] = rsqrtf(s2*(1.0f/CDIM) - mu*mu + 1e-5f);
  }
  __syncthreads();
  float mu = muL[lt], rs = rsL[lt];
  #pragma unroll
  for (int c = cg; c < 64; c += 4) {
    float v = xb[(size_t)(c0+c)*NTQ + t0 + lt];
    T[lt][c] = f2bf((v - mu)*rs*lnw[c0+c] + lnb[c0+c]);
  }
  __syncthreads();
  #pragma unroll
  for (int i = 0; i < 4; i++) {
    int idx = t + 256*i;
    int tok = idx >> 4, cq = idx & 15;
    *(uint2*)&xnh[((size_t)(b*LQ) + t0 + tok)*CDIM + c0 + cq*4] =
        *(const uint2*)&T[tok][cq*4];
  }
}

// ---------------- K1c: point tokens + LayerNorm ----------------
__global__ __launch_bounds__(320) void k_pt_ln(
    const float* __restrict__ pcoords, const float* __restrict__ lnw,
    const float* __restrict__ lnb, const float* __restrict__ pgauss,
    const float* __restrict__ pemb_w, const float* __restrict__ nap,
    const int* __restrict__ plabels, unsigned short* __restrict__ xnh)
{
  int j = blockIdx.x, b = blockIdx.y;
  int c = threadIdx.x;
  int f = (c < 160) ? c : c - 160;
  float p0 = pcoords[(b*8+j)*3+0]*(2.0f/16.0f) - 1.0f;
  float p1 = pcoords[(b*8+j)*3+1]*(2.0f/16.0f) - 1.0f;
  float p2 = pcoords[(b*8+j)*3+2]*(2.0f/16.0f) - 1.0f;
  float pe = 6.283185307179586f*(p0*pgauss[f] + p1*pgauss[160+f] + p2*pgauss[320+f]);
  float pv = (c < 160) ? sinf(pe) : cosf(pe);
  int lab = plabels[b*8+j];
  float val;
  if (lab == -1) val = nap[c];
  else {
    int safe = lab < 0 ? 0 : (lab > 1 ? 1 : lab);
    val = pv + pemb_w[safe*CDIM + c];
  }
  float s  = warp_sum(val);
  float s2 = warp_sum(val*val);
  __shared__ float r1[5], r2[5];
  int w = threadIdx.x >> 6, lane = threadIdx.x & 63;
  if (lane == 0) { r1[w] = s; r2[w] = s2; }
  __syncthreads();
  float ts = 0.f, ts2 = 0.f;
  #pragma unroll
  for (int i = 0; i < 5; i++) { ts += r1[i]; ts2 += r2[i]; }
  float mu  = ts * (1.0f/CDIM);
  float var = ts2 * (1.0f/CDIM) - mu*mu;
  float rsig = rsqrtf(var + 1e-5f);
  xnh[((size_t)b*LQ + NTQ + j)*CDIM + c] = f2bf((val - mu)*rsig*lnw[c] + lnb[c]);
}

// ---------------- K2: zxh = xn @ w1^T, double-buffered 2-phase pipeline ----------------
__global__ __launch_bounds__(256) void k_gemm1_mfma(
    const unsigned short* __restrict__ Abf, const unsigned short* __restrict__ Wbf,
    unsigned short* __restrict__ zxh, float* __restrict__ dtraw)
{
  __shared__ unsigned short As[2][128*32];
  __shared__ unsigned short Bs[2][128*32];
  int id = blockIdx.x;
  int xcd = id & 7, pos = id >> 3;
  const int q = 177, r = 3;
  int swz = (xcd < r ? xcd*(q+1) : r*(q+1) + (xcd-r)*q) + pos;
  int m0 = (swz / 11) * 128;
  int n0 = (swz % 11) * 128;
  int tid = threadIdx.x;
  int lane = tid & 63, wid = tid >> 6;
  int wr = wid >> 1, wc = wid & 1;
  int fr = lane & 15, fq = lane >> 4;
  int srow = lane >> 2;
  int scol = (lane & 3) * 8;

#define G1_STAGE(buf, kk)                                                   \
  {                                                                         \
    _Pragma("unroll")                                                       \
    for (int i = 0; i < 2; i++) {                                           \
      int seg = wid + i*4;                                                  \
      int rowA = seg*16 + srow;                                             \
      int ga = m0 + rowA; if (ga > MQ-1) ga = MQ-1;                         \
      gload16(Abf + (size_t)ga*CDIM + (kk) + scol, &As[buf][seg*512]);      \
      int gb = n0 + rowA; if (gb > DIP-1) gb = DIP-1;                       \
      gload16(Wbf + (size_t)gb*CDIM + (kk) + scol, &Bs[buf][seg*512]);      \
    }                                                                       \
  }

#define G1_COMPUTE(buf)                                                     \
  {                                                                         \
    bf16x8 fa[4], fb[4];                                                    \
    _Pragma("unroll")                                                       \
    for (int i = 0; i < 4; i++) {                                           \
      fa[i] = *(const bf16x8*)&As[buf][(wr*64 + i*16 + fr)*32 + fq*8];      \
      fb[i] = *(const bf16x8*)&Bs[buf][(wc*64 + i*16 + fr)*32 + fq*8];      \
    }                                                                       \
    _Pragma("unroll")                                                       \
    for (int i = 0; i < 4; i++)                                             \
      _Pragma("unroll")                                                     \
      for (int j = 0; j < 4; j++)                                           \
        acc[i][j] = __builtin_amdgcn_mfma_f32_16x16x32_bf16(fa[i], fb[j], acc[i][j], 0, 0, 0); \
  }

  f32x4 acc[4][4] = {};
  G1_STAGE(0, 0);
  __syncthreads();
  int cur = 0;
  for (int k0 = 32; k0 < CDIM; k0 += 32) {
    G1_STAGE(cur^1, k0);
    G1_COMPUTE(cur);
    __syncthreads();
    cur ^= 1;
  }
  G1_COMPUTE(cur);

  #pragma unroll
  for (int i = 0; i < 4; i++) {
    #pragma unroll
    for (int j = 0; j < 4; j++) {
      #pragma unroll
      for (int rr = 0; rr < 4; rr++) {
        int grow = m0 + wr*64 + i*16 + fq*4 + rr;
        int gcol = n0 + wc*64 + j*16 + fr;
        if (grow < MQ && gcol < DIP) {
          float v = acc[i][j][rr];
          zxh[(size_t)grow*DIP + gcol] = f2bf(v);
          if (gcol >= DI + CONVD)
            dtraw[(size_t)grow*NH + (gcol - (DI + CONVD))] = v;
        }
      }
    }
  }
}

// ---------------- K4: depthwise causal conv(4) + SiLU, register-tiled x8 tokens ----------------
__global__ __launch_bounds__(256) void k_conv(
    const unsigned short* __restrict__ zxh, const float* __restrict__ cw,
    const float* __restrict__ cb, unsigned short* __restrict__ xcb)
{
  const int nC4 = CONVD/4;
  int gid = blockIdx.x*256 + threadIdx.x;
  if (gid >= (MQ/8)*nC4) return;
  int c4 = gid % nC4;
  int mb = gid / nC4;
  int m0 = mb*8;
  int l0 = m0 % LQ;
  int c0 = c4*4;
  float4 cbv = *(const float4*)(cb + c0);
  float4 w0 = *(const float4*)(cw + (c0+0)*4);
  float4 w1 = *(const float4*)(cw + (c0+1)*4);
  float4 w2 = *(const float4*)(cw + (c0+2)*4);
  float4 w3 = *(const float4*)(cw + (c0+3)*4);
  const float* wp[4] = {(const float*)&w0, (const float*)&w1,
                        (const float*)&w2, (const float*)&w3};
  float vals[11][4];
  #pragma unroll
  for (int r = 0; r < 11; r++) {
    int ls = l0 - 3 + r;
    uint2 u = make_uint2(0,0);
    if (ls >= 0)
      u = *(const uint2*)(zxh + (size_t)(m0-3+r)*DIP + DI + c0);
    vals[r][0] = bf2f((unsigned short)(u.x & 0xffff));
    vals[r][1] = bf2f((unsigned short)(u.x >> 16));
    vals[r][2] = bf2f((unsigned short)(u.y & 0xffff));
    vals[r][3] = bf2f((unsigned short)(u.y >> 16));
  }
  const float* cbp = (const float*)&cbv;
  #pragma unroll
  for (int u = 0; u < 8; u++) {
    unsigned short o[4];
    #pragma unroll
    for (int ch = 0; ch < 4; ch++) {
      float a = cbp[ch];
      #pragma unroll
      for (int j = 0; j < 4; j++)
        a = fmaf(vals[u+j][ch], wp[ch][j], a);
      o[ch] = f2bf(a / (1.f + __expf(-a)));
    }
    *(uint2*)(xcb + (size_t)(m0+u)*CONVD + c0) = *(const uint2*)o;
  }
}

// ---------------- K5ab: fused softplus + in-wave cumsum + chunk end-state MFMA ----------------
__global__ __launch_bounds__(256) void k_cumsum_state(
    const float* __restrict__ dtraw, const float* __restrict__ dt_bias,
    const float* __restrict__ A_log, const unsigned short* __restrict__ xcb,
    float* __restrict__ dtb, float* __restrict__ cs, float* __restrict__ Dc,
    float* __restrict__ Sbuf)
{
  int c = blockIdx.x, h = blockIdx.y, b = blockIdx.z;
  int len = LQ - c*QC; if (len > QC) len = QC;
  int t = threadIdx.x;
  int lane = t & 63, wid = t >> 6;
  int fr = lane & 15, fq = lane >> 4;
  int m0 = b*LQ + c*QC;

  __shared__ unsigned short XT[HD*QC];
  __shared__ unsigned short BwT[DS*QC];
  __shared__ float ws[QC];

  // stage X^T early (loads in flight across the scan)
  for (int idx = t; idx < (HD/8)*QC; idx += 256) {
    int pg = idx % 10, i = idx / 10;
    uint4 v = make_uint4(0,0,0,0);
    if (i < len)
      v = *(const uint4*)(xcb + (size_t)(m0+i)*CONVD + h*HD + pg*8);
    union { uint4 u; unsigned short us[8]; } cv; cv.u = v;
    #pragma unroll
    for (int e = 0; e < 8; e++)
      XT[swz64(pg*8+e, i)] = cv.us[e];
  }

  // in-wave scan (threads 0..63 form wave 0)
  if (t < QC) {
    float A = -expf(A_log[h]);
    float sp = 0.f;
    if (t < len) {
      float v = dtraw[((size_t)(m0+t))*NH + h] + dt_bias[h];
      sp = (v > 20.f) ? v : log1pf(expf(v));
      dtb[((size_t)(m0+t))*NH + h] = sp;
    }
    float a = sp * A;
    #pragma unroll
    for (int off = 1; off < 64; off <<= 1) {
      float pv = __shfl_up(a, off, 64);
      if (t >= off) a += pv;
    }
    cs[((size_t)(b*NH+h)*NC + c)*QC + t] = a;
    if (t == len-1) Dc[(b*NH+h)*NC + c] = expf(a);
    float aEnd = __shfl(a, len-1, 64);
    ws[t] = (t < len) ? __expf(aEnd - a) * sp : 0.f;
  }
  __syncthreads();
  for (int idx = t; idx < DS*QC; idx += 256) {
    int n = idx & 31, i = idx >> 5;
    float v = (i < len) ? bf2f(xcb[(size_t)(m0+i)*CONVD + DI + n]) * ws[i] : 0.f;
    BwT[swz64(n, i)] = f2bf(v);
  }
  __syncthreads();

  size_t base = ((size_t)(b*NC + c)*NH + h)*(HD*DS);
  for (int tp = wid; tp < 10; tp += 4) {
    int pi = tp >> 1, ni = tp & 1;
    f32x4 acc = {};
    #pragma unroll
    for (int ks = 0; ks < 2; ks++) {
      bf16x8 fa = *(const bf16x8*)&XT[swz64(pi*16 + fr, ks*32 + fq*8)];
      bf16x8 fb = *(const bf16x8*)&BwT[swz64(ni*16 + fr, ks*32 + fq*8)];
      acc = __builtin_amdgcn_mfma_f32_16x16x32_bf16(fa, fb, acc, 0, 0, 0);
    }
    #pragma unroll
    for (int rr = 0; rr < 4; rr++)
      Sbuf[base + (size_t)(pi*16 + fq*4 + rr)*DS + ni*16 + fr] = acc[rr];
  }
}

// ---------------- K5c: sequential scan over chunk states (in-place H0) ----------------
__global__ __launch_bounds__(256) void k_state_scan(
    float* __restrict__ Sbuf, const float* __restrict__ Dc,
    float* __restrict__ H0)
{
  int tid = blockIdx.x*256 + threadIdx.x;
  int pn = tid % (HD*DS);
  int bh = tid / (HD*DS);
  int b = bh >> 3, h = bh & 7;
  float hst = 0.f;
  for (int c = 0; c < NC; c++) {
    size_t idx = ((size_t)(b*NC + c)*NH + h)*(HD*DS) + pn;
    float sv = Sbuf[idx];
    H0[idx] = hst;
    hst = hst * Dc[bh*NC + c] + sv;
  }
}

// ---------------- K5d: per-chunk outputs (QC=64): 4 waves x 16 rows ----------------
__global__ __launch_bounds__(256) void k_chunk_y_mfma(
    const unsigned short* __restrict__ xcb, const unsigned short* __restrict__ zxh,
    const float* __restrict__ dtb, const float* __restrict__ cs,
    const float* __restrict__ H0, const float* __restrict__ Dp,
    unsigned short* __restrict__ ygb)
{
  int c = blockIdx.x, h = blockIdx.y, b = blockIdx.z;
  int len = LQ - c*QC; if (len > QC) len = QC;
  int t = threadIdx.x;
  int lane = t & 63, wid = t >> 6;
  int fr = lane & 15, fq = lane >> 4;
  int m0 = b*LQ + c*QC;

  __shared__ unsigned short XT[HD*QC];
  __shared__ unsigned short Wt[4*16*32];
  __shared__ float slA[QC], dtlA[QC], elA[QC];

  const float* csb = cs + ((size_t)(b*NH+h)*NC + c)*QC;

  for (int idx = t; idx < (HD/8)*QC; idx += 256) {
    int pg = idx % 10, i = idx / 10;
    uint4 v = make_uint4(0,0,0,0);
    if (i < len)
      v = *(const uint4*)(xcb + (size_t)(m0+i)*CONVD + h*HD + pg*8);
    union { uint4 u; unsigned short us[8]; } cv; cv.u = v;
    #pragma unroll
    for (int e = 0; e < 8; e++)
      XT[swz64(pg*8+e, i)] = cv.us[e];
  }
  if (t < QC) {
    float s = csb[t];
    slA[t] = s;
    elA[t] = __expf(s);
    dtlA[t] = (t < len) ? dtb[((size_t)(m0+t))*NH + h] : 0.f;
  }
  __syncthreads();

  int row16 = wid*16 + fr;
  bf16x8 fa = {};
  if (row16 < len)
    fa = *(const bf16x8*)(xcb + (size_t)(m0+row16)*CONVD + DI + DS + fq*8);

  size_t hb = ((size_t)(b*NC + c)*NH + h)*(HD*DS);
  f32x4 acc[5];
  #pragma unroll
  for (int j = 0; j < 5; j++) {
    int p = j*16 + fr;
    const float* hp = H0 + hb + (size_t)p*DS + fq*8;
    float4 ha = *(const float4*)hp;
    float4 hbv = *(const float4*)(hp + 4);
    bf16x8 fb;
    fb[0]=(short)f2bf(ha.x);  fb[1]=(short)f2bf(ha.y);
    fb[2]=(short)f2bf(ha.z);  fb[3]=(short)f2bf(ha.w);
    fb[4]=(short)f2bf(hbv.x); fb[5]=(short)f2bf(hbv.y);
    fb[6]=(short)f2bf(hbv.z); fb[7]=(short)f2bf(hbv.w);
    f32x4 z = {};
    acc[j] = __builtin_amdgcn_mfma_f32_16x16x32_bf16(fa, fb, z, 0, 0, 0);
  }
  #pragma unroll
  for (int rr = 0; rr < 4; rr++) {
    float el = elA[wid*16 + fq*4 + rr];
    #pragma unroll
    for (int j = 0; j < 5; j++) acc[j][rr] *= el;
  }

  int wbase = wid << 9;
  for (int sc = 0; sc < 2; sc++) {
    int i0 = sc*32;
    #pragma unroll
    for (int jt = 0; jt < 2; jt++) {
      int col = i0 + jt*16 + fr;
      bf16x8 fbv = {};
      if (col < len)
        fbv = *(const bf16x8*)(xcb + (size_t)(m0+col)*CONVD + DI + fq*8);
      float sc_col = slA[col], dt_col = dtlA[col];
      f32x4 z = {};
      f32x4 g = __builtin_amdgcn_mfma_f32_16x16x32_bf16(fa, fbv, z, 0, 0, 0);
      #pragma unroll
      for (int rr = 0; rr < 4; rr++) {
        int lr = fq*4 + rr;
        int row = wid*16 + lr;
        float v = 0.f;
        if (col <= row)
          v = g[rr] * __expf(slA[row] - sc_col) * dt_col;
        int lc = jt*16 + fr;
        int slot = (lc >> 3) ^ (lr & 3);
        Wt[wbase + (lr<<5) + (slot<<3) + (lc&7)] = f2bf(v);
      }
    }
    bf16x8 wa = *(const bf16x8*)&Wt[wbase + (fr<<5) + ((fq ^ (fr&3))<<3)];
    #pragma unroll
    for (int j = 0; j < 5; j++) {
      int p = j*16 + fr;
      bf16x8 xb = *(const bf16x8*)&XT[swz64(p, i0 + fq*8)];
      acc[j] = __builtin_amdgcn_mfma_f32_16x16x32_bf16(wa, xb, acc[j], 0, 0, 0);
    }
  }

  float dpv = Dp[h];
  #pragma unroll
  for (int rr = 0; rr < 4; rr++) {
    int l = wid*16 + fq*4 + rr;
    if (l >= len) continue;
    size_t m = m0 + l;
    #pragma unroll
    for (int j = 0; j < 5; j++) {
      int p = j*16 + fr;
      int cc = h*HD + p;
      float xv = bf2f(XT[swz64(p, l)]);
      float y = acc[j][rr] + xv*dpv;
      float zv = bf2f(zxh[m*DIP + cc]);
      y *= zv / (1.f + __expf(-zv));
      ygb[m*DI + cc] = f2bf(y);
    }
  }
}

// ---------------- K6: RMS + scale, 8 rows/block, 32-lane groups ----------------
__global__ __launch_bounds__(256) void k_rms_scale(
    unsigned short* __restrict__ ygb, const float* __restrict__ rsw)
{
  int t = threadIdx.x;
  int grp = t >> 5;
  int gl = t & 31;
  size_t m = (size_t)blockIdx.x*8 + grp;
  unsigned short* row = ygb + m*DI;
  float v[5][4];
  float ss = 0.f;
  #pragma unroll
  for (int k = 0; k < 5; k++) {
    uint2 u = *(const uint2*)(row + (gl + 32*k)*4);
    v[k][0] = bf2f((unsigned short)(u.x & 0xffff));
    v[k][1] = bf2f((unsigned short)(u.x >> 16));
    v[k][2] = bf2f((unsigned short)(u.y & 0xffff));
    v[k][3] = bf2f((unsigned short)(u.y >> 16));
    ss += v[k][0]*v[k][0] + v[k][1]*v[k][1] + v[k][2]*v[k][2] + v[k][3]*v[k][3];
  }
  #pragma unroll
  for (int o = 16; o; o >>= 1) ss += __shfl_xor(ss, o, 32);
  float rsv = rsqrtf(ss*(1.0f/DI) + 1e-5f);
  #pragma unroll
  for (int k = 0; k < 5; k++) {
    float4 wv = *(const float4*)(rsw + (gl + 32*k)*4);
    unsigned short o4[4];
    o4[0] = f2bf(v[k][0]*rsv*wv.x);
    o4[1] = f2bf(v[k][1]*rsv*wv.y);
    o4[2] = f2bf(v[k][2]*rsv*wv.z);
    o4[3] = f2bf(v[k][3]*rsv*wv.w);
    *(uint2*)(row + (gl + 32*k)*4) = *(const uint2*)o4;
  }
}

// ---------------- K7: out^T = w2 @ ygb^T, double-buffered 2-phase pipeline ----------------
__global__ __launch_bounds__(256) void k_gemm2_mfma(
    const unsigned short* __restrict__ W2h, const unsigned short* __restrict__ Ygh,
    float* __restrict__ out)
{
  __shared__ unsigned short As[2][128*32];
  __shared__ unsigned short Bs[2][128*32];
  int id = blockIdx.x;
  int xcd = id & 7, pos = id >> 3;
  const int q = 48, r = 3;
  int swz = (xcd < r ? xcd*(q+1) : r*(q+1) + (xcd-r)*q) + pos;
  int c0 = (swz % 3) * 128;
  int t0 = (swz / 3) * 128;
  int tid = threadIdx.x;
  int lane = tid & 63, wid = tid >> 6;
  int wr = wid >> 1, wc = wid & 1;
  int fr = lane & 15, fq = lane >> 4;
  int srow = lane >> 2;
  int scol = (lane & 3) * 8;

#define G2_STAGE(buf, kk)                                                   \
  {                                                                         \
    _Pragma("unroll")                                                       \
    for (int i = 0; i < 2; i++) {                                           \
      int seg = wid + i*4;                                                  \
      int rowA = seg*16 + srow;                                             \
      int ga = c0 + rowA; if (ga > CDIM-1) ga = CDIM-1;                     \
      gload16(W2h + (size_t)ga*DI + (kk) + scol, &As[buf][seg*512]);        \
      int gb = t0 + rowA; if (gb > MQ-1) gb = MQ-1;                         \
      gload16(Ygh + (size_t)gb*DI + (kk) + scol, &Bs[buf][seg*512]);        \
    }                                                                       \
  }

#define G2_COMPUTE(buf)                                                     \
  {                                                                         \
    bf16x8 fa[4], fb[4];                                                    \
    _Pragma("unroll")                                                       \
    for (int i = 0; i < 4; i++) {                                           \
      fa[i] = *(const bf16x8*)&As[buf][(wr*64 + i*16 + fr)*32 + fq*8];      \
      fb[i] = *(const bf16x8*)&Bs[buf][(wc*64 + i*16 + fr)*32 + fq*8];      \
    }                                                                       \
    _Pragma("unroll")                                                       \
    for (int i = 0; i < 4; i++)                                             \
      _Pragma("unroll")                                                     \
      for (int j = 0; j < 4; j++)                                           \
        acc[i][j] = __builtin_amdgcn_mfma_f32_16x16x32_bf16(fa[i], fb[j], acc[i][j], 0, 0, 0); \
  }

  f32x4 acc[4][4] = {};
  G2_STAGE(0, 0);
  __syncthreads();
  int cur = 0;
  for (int k0 = 32; k0 < DI; k0 += 32) {
    G2_STAGE(cur^1, k0);
    G2_COMPUTE(cur);
    __syncthreads();
    cur ^= 1;
  }
  G2_COMPUTE(cur);

  #pragma unroll
  for (int i = 0; i < 4; i++) {
    #pragma unroll
    for (int j = 0; j < 4; j++) {
      #pragma unroll
      for (int rr = 0; rr < 4; rr++) {
        int ch  = c0 + wr*64 + i*16 + fq*4 + rr;
        int tok = t0 + wc*64 + j*16 + fr;
        if (ch < CDIM && tok < MQ) {
          int b = tok / LQ, l = tok % LQ;
          if (l < NTQ)
            out[((size_t)(b*CDIM + ch))*NTQ + l] = acc[i][j][rr];
        }
      }
    }
  }
}

extern "C" void kernel_launch(void* const* d_in, const int* in_sizes, int n_in,
                              void* d_out, int out_size, void* d_ws, size_t ws_size,
                              hipStream_t stream)
{
  const float* x       = (const float*)d_in[0];
  const float* pc      = (const float*)d_in[1];
  const float* lnw     = (const float*)d_in[2];
  const float* lnb     = (const float*)d_in[3];
  const float* w1      = (const float*)d_in[4];
  const float* cw      = (const float*)d_in[5];
  const float* cb      = (const float*)d_in[6];
  const float* dt_bias = (const float*)d_in[7];
  const float* A_log   = (const float*)d_in[8];
  const float* Dp      = (const float*)d_in[9];
  const float* rsw     = (const float*)d_in[10];
  const float* w2      = (const float*)d_in[11];
  const float* pg      = (const float*)d_in[12];
  const float* pew     = (const float*)d_in[13];
  const float* nap     = (const float*)d_in[14];
  const int*   plab    = (const int*)d_in[15];
  float* out = (float*)d_out;

  unsigned short* xnh  = (unsigned short*)d_ws;                     // MQ*CDIM bf16
  unsigned short* zxh  = xnh + (size_t)MQ*CDIM;                     // MQ*DIP bf16
  float* dtraw = (float*)(zxh + (size_t)MQ*DIP);                    // MQ*NH f32
  unsigned short* xcb  = (unsigned short*)(dtraw + (size_t)MQ*NH);  // MQ*CONVD bf16
  float* dtb = (float*)(xcb + (size_t)MQ*CONVD);                    // MQ*NH f32
  float* cs  = dtb + (size_t)MQ*NH;                                 // B*NH*NC*QC
  float* Dc  = cs  + (size_t)BQ*NH*NC*QC;                           // B*NH*NC
  float* Sb  = Dc  + (size_t)BQ*NH*NC;                              // B*NC*NH*HD*DS
  float* H0  = Sb;                                                  // in-place alias
  unsigned short* ygb = (unsigned short*)(Sb + (size_t)BQ*NC*NH*HD*DS); // MQ*DI bf16
  unsigned short* w1h = ygb + (size_t)MQ*DI;                        // DIP*CDIM bf16
  unsigned short* w2h = w1h + (size_t)DIP*CDIM;                     // CDIM*DI bf16
  float* muP = (float*)(w2h + (size_t)CDIM*DI);                     // 8*B*NTQ f32
  float* s2P = muP + (size_t)8*BQ*NTQ;                              // 8*B*NTQ f32

  k_f2bf4<<<((DIP*CDIM + CDIM*DI)/4 + 255)/256, 256, 0, stream>>>(
      w1, w1h, DIP*CDIM/4, w2, w2h, CDIM*DI/4);
  dim3 gs(NTQ/256, 8, BQ);
  k_stats<<<gs, 256, 0, stream>>>(x, muP, s2P);
  dim3 gn(NTQ/64, CDIM/64, BQ);
  k_norm_t<<<gn, 256, 0, stream>>>(x, muP, s2P, lnw, lnb, xnh);
  dim3 gp(8, BQ);
  k_pt_ln<<<gp, 320, 0, stream>>>(pc, lnw, lnb, pg, pew, nap, plab, xnh);
  k_gemm1_mfma<<<129*11, 256, 0, stream>>>(xnh, w1h, zxh, dtraw);
  k_conv<<<((MQ/8)*(CONVD/4) + 255)/256, 256, 0, stream>>>(zxh, cw, cb, xcb);
  dim3 gc(NC, NH, BQ);
  k_cumsum_state<<<gc, 256, 0, stream>>>(dtraw, dt_bias, A_log, xcb, dtb, cs, Dc, Sb);
  k_state_scan<<<(BQ*NH*HD*DS)/256, 256, 0, stream>>>(Sb, Dc, H0);
  k_chunk_y_mfma<<<gc, 256, 0, stream>>>(xcb, zxh, dtb, cs, H0, Dp, ygb);
  k_rms_scale<<<MQ/8, 256, 0, stream>>>(ygb, rsw);
  k_gemm2_mfma<<<129*3, 256, 0, stream>>>(w2h, ygb, out);
}

// Round 11
// 149.702 us; speedup vs baseline: 25.6318x; 1.0646x over previous
//
#include <hip/hip_runtime.h>
#include <math.h>

#define BQ 4
#define LQ 4104
#define NTQ 4096
#define CDIM 320
#define DIP 1352
#define DI 640
#define CONVD 704
#define NH 8
#define HD 80
#define DS 32
#define MQ (BQ*LQ)   // 16416
#define QC 64        // chunk length
#define NC 65        // ceil(LQ/QC)

typedef __attribute__((ext_vector_type(8))) short bf16x8;
typedef __attribute__((ext_vector_type(4))) float f32x4;

__device__ __forceinline__ unsigned short f2bf(float f){
  union { float f; unsigned u; } v; v.f = f;
  unsigned r = v.u + 0x7FFFu + ((v.u >> 16) & 1u);
  return (unsigned short)(r >> 16);
}
__device__ __forceinline__ float bf2f(unsigned short u){
  union { unsigned u; float f; } v; v.u = ((unsigned)u) << 16;
  return v.f;
}
__device__ __forceinline__ float warp_sum(float v){
  #pragma unroll
  for (int o = 32; o; o >>= 1) v += __shfl_xor(v, o);
  return v;
}
__device__ __forceinline__ void gload16(const unsigned short* g, unsigned short* l){
  __builtin_amdgcn_global_load_lds(
      (const __attribute__((address_space(1))) unsigned int*)g,
      (__attribute__((address_space(3))) unsigned int*)l, 16, 0, 0);
}
__device__ __forceinline__ int swz64(int p, int i){
  return p*QC + (i ^ ((p & 7) << 3));
}

// ---------------- K0: fused prologue: weight converts (rsw folded into w2) +
//                   LN stats partials + point-token LN ----------------
__global__ __launch_bounds__(256) void k_prep(
    const float* __restrict__ w1, unsigned short* __restrict__ w1h,
    const float* __restrict__ w2, const float* __restrict__ rsw,
    unsigned short* __restrict__ w2h,
    const float* __restrict__ x, float* __restrict__ muP, float* __restrict__ s2P,
    const float* __restrict__ pcoords, const float* __restrict__ lnw,
    const float* __restrict__ lnb, const float* __restrict__ pgauss,
    const float* __restrict__ pemb_w, const float* __restrict__ nap,
    const int* __restrict__ plabels, unsigned short* __restrict__ xnh)
{
  const int N1 = DIP*CDIM/4;          // 108160 float4s of w1
  const int N2 = CDIM*DI/4;           // 51200 float4s of w2
  const int NBW = (N1 + N2 + 255)/256;
  int bid = blockIdx.x;
  int t = threadIdx.x;

  if (bid < NBW) {   // role A: weight conversion
    int i4 = bid*256 + t;
    if (i4 < N1) {
      float4 v = ((const float4*)w1)[i4];
      unsigned short o[4] = {f2bf(v.x), f2bf(v.y), f2bf(v.z), f2bf(v.w)};
      *(uint2*)&w1h[i4*4] = *(const uint2*)o;
    } else if (i4 - N1 < N2) {
      int j = i4 - N1;
      float4 v = ((const float4*)w2)[j];
      float4 wv = *(const float4*)(rsw + (j*4) % DI);
      unsigned short o[4] = {f2bf(v.x*wv.x), f2bf(v.y*wv.y),
                             f2bf(v.z*wv.z), f2bf(v.w*wv.w)};
      *(uint2*)&w2h[j*4] = *(const uint2*)o;
    }
    return;
  }
  bid -= NBW;
  if (bid < 512) {   // role B: LN stats partials (8 channel-slices)
    int xblk = bid & 15, sl = (bid >> 4) & 7, b = bid >> 7;
    int cs0 = sl * 40;
    int tok = xblk*256 + t;
    const float* xb = x + ((size_t)b*CDIM)*NTQ;
    float s = 0.f, s2 = 0.f;
    #pragma unroll 8
    for (int c = cs0; c < cs0 + 40; c++) {
      float v = xb[(size_t)c*NTQ + tok];
      s += v; s2 = fmaf(v, v, s2);
    }
    muP[((size_t)sl*BQ + b)*NTQ + tok] = s;
    s2P[((size_t)sl*BQ + b)*NTQ + tok] = s2;
    return;
  }
  bid -= 512;        // role C: point tokens + LN (one block per (b,j))
  int j = bid & 7, b = bid >> 3;
  float p0 = pcoords[(b*8+j)*3+0]*(2.0f/16.0f) - 1.0f;
  float p1 = pcoords[(b*8+j)*3+1]*(2.0f/16.0f) - 1.0f;
  float p2 = pcoords[(b*8+j)*3+2]*(2.0f/16.0f) - 1.0f;
  int lab = plabels[b*8+j];
  int safe = lab < 0 ? 0 : (lab > 1 ? 1 : lab);
  float vA, vB = 0.f;
  {
    int cc = t;
    int f = (cc < 160) ? cc : cc - 160;
    float pe = 6.283185307179586f*(p0*pgauss[f] + p1*pgauss[160+f] + p2*pgauss[320+f]);
    float pv = (cc < 160) ? sinf(pe) : cosf(pe);
    vA = (lab == -1) ? nap[cc] : pv + pemb_w[safe*CDIM + cc];
  }
  if (t < 64) {
    int cc = t + 256;            // >=256 -> cos branch
    int f = cc - 160;
    float pe = 6.283185307179586f*(p0*pgauss[f] + p1*pgauss[160+f] + p2*pgauss[320+f]);
    float pv = cosf(pe);
    vB = (lab == -1) ? nap[cc] : pv + pemb_w[safe*CDIM + cc];
  }
  float s  = warp_sum(vA + vB);
  float s2 = warp_sum(vA*vA + vB*vB);
  __shared__ float r1[4], r2[4];
  int w = t >> 6, lane = t & 63;
  if (lane == 0) { r1[w] = s; r2[w] = s2; }
  __syncthreads();
  float ts  = r1[0]+r1[1]+r1[2]+r1[3];
  float ts2 = r2[0]+r2[1]+r2[2]+r2[3];
  float mu   = ts * (1.0f/CDIM);
  float rsig = rsqrtf(ts2*(1.0f/CDIM) - mu*mu + 1e-5f);
  size_t base = ((size_t)b*LQ + NTQ + j)*CDIM;
  xnh[base + t] = f2bf((vA - mu)*rsig*lnw[t] + lnb[t]);
  if (t < 64)
    xnh[base + t + 256] = f2bf((vB - mu)*rsig*lnw[t+256] + lnb[t+256]);
}

// ---------------- K1b: normalize + transpose -> xnh bf16 ----------------
__global__ __launch_bounds__(256) void k_norm_t(
    const float* __restrict__ x, const float* __restrict__ muP,
    const float* __restrict__ s2P, const float* __restrict__ lnw,
    const float* __restrict__ lnb, unsigned short* __restrict__ xnh)
{
  int b = blockIdx.z;
  int c0 = blockIdx.y * 64;
  int t0 = blockIdx.x * 64;
  int t = threadIdx.x;
  int lt = t & 63, cg = t >> 6;
  const float* xb = x + ((size_t)b*CDIM)*NTQ;

  __shared__ unsigned short T[64][72];
  __shared__ float muL[64], rsL[64];
  if (t < 64) {
    float s = 0.f, s2 = 0.f;
    #pragma unroll
    for (int sl = 0; sl < 8; sl++) {
      s  += muP[((size_t)sl*BQ + b)*NTQ + t0 + t];
      s2 += s2P[((size_t)sl*BQ + b)*NTQ + t0 + t];
    }
    float mu = s*(1.0f/CDIM);
    muL[t] = mu;
    rsL[t] = rsqrtf(s2*(1.0f/CDIM) - mu*mu + 1e-5f);
  }
  __syncthreads();
  float mu = muL[lt], rs = rsL[lt];
  #pragma unroll
  for (int c = cg; c < 64; c += 4) {
    float v = xb[(size_t)(c0+c)*NTQ + t0 + lt];
    T[lt][c] = f2bf((v - mu)*rs*lnw[c0+c] + lnb[c0+c]);
  }
  __syncthreads();
  #pragma unroll
  for (int i = 0; i < 4; i++) {
    int idx = t + 256*i;
    int tok = idx >> 4, cq = idx & 15;
    *(uint2*)&xnh[((size_t)(b*LQ) + t0 + tok)*CDIM + c0 + cq*4] =
        *(const uint2*)&T[tok][cq*4];
  }
}

// ---------------- K2: zxh = xn @ w1^T, double-buffered 2-phase pipeline ----------------
__global__ __launch_bounds__(256) void k_gemm1_mfma(
    const unsigned short* __restrict__ Abf, const unsigned short* __restrict__ Wbf,
    unsigned short* __restrict__ zxh, float* __restrict__ dtraw)
{
  __shared__ unsigned short As[2][128*32];
  __shared__ unsigned short Bs[2][128*32];
  int id = blockIdx.x;
  int xcd = id & 7, pos = id >> 3;
  const int q = 177, r = 3;
  int swz = (xcd < r ? xcd*(q+1) : r*(q+1) + (xcd-r)*q) + pos;
  int m0 = (swz / 11) * 128;
  int n0 = (swz % 11) * 128;
  int tid = threadIdx.x;
  int lane = tid & 63, wid = tid >> 6;
  int wr = wid >> 1, wc = wid & 1;
  int fr = lane & 15, fq = lane >> 4;
  int srow = lane >> 2;
  int scol = (lane & 3) * 8;

#define G1_STAGE(buf, kk)                                                   \
  {                                                                         \
    _Pragma("unroll")                                                       \
    for (int i = 0; i < 2; i++) {                                           \
      int seg = wid + i*4;                                                  \
      int rowA = seg*16 + srow;                                             \
      int ga = m0 + rowA; if (ga > MQ-1) ga = MQ-1;                         \
      gload16(Abf + (size_t)ga*CDIM + (kk) + scol, &As[buf][seg*512]);      \
      int gb = n0 + rowA; if (gb > DIP-1) gb = DIP-1;                       \
      gload16(Wbf + (size_t)gb*CDIM + (kk) + scol, &Bs[buf][seg*512]);      \
    }                                                                       \
  }

#define G1_COMPUTE(buf)                                                     \
  {                                                                         \
    bf16x8 fa[4], fb[4];                                                    \
    _Pragma("unroll")                                                       \
    for (int i = 0; i < 4; i++) {                                           \
      fa[i] = *(const bf16x8*)&As[buf][(wr*64 + i*16 + fr)*32 + fq*8];      \
      fb[i] = *(const bf16x8*)&Bs[buf][(wc*64 + i*16 + fr)*32 + fq*8];      \
    }                                                                       \
    _Pragma("unroll")                                                       \
    for (int i = 0; i < 4; i++)                                             \
      _Pragma("unroll")                                                     \
      for (int j = 0; j < 4; j++)                                           \
        acc[i][j] = __builtin_amdgcn_mfma_f32_16x16x32_bf16(fa[i], fb[j], acc[i][j], 0, 0, 0); \
  }

  f32x4 acc[4][4] = {};
  G1_STAGE(0, 0);
  __syncthreads();
  int cur = 0;
  for (int k0 = 32; k0 < CDIM; k0 += 32) {
    G1_STAGE(cur^1, k0);
    G1_COMPUTE(cur);
    __syncthreads();
    cur ^= 1;
  }
  G1_COMPUTE(cur);

  #pragma unroll
  for (int i = 0; i < 4; i++) {
    #pragma unroll
    for (int j = 0; j < 4; j++) {
      #pragma unroll
      for (int rr = 0; rr < 4; rr++) {
        int grow = m0 + wr*64 + i*16 + fq*4 + rr;
        int gcol = n0 + wc*64 + j*16 + fr;
        if (grow < MQ && gcol < DIP) {
          float v = acc[i][j][rr];
          zxh[(size_t)grow*DIP + gcol] = f2bf(v);
          if (gcol >= DI + CONVD)
            dtraw[(size_t)grow*NH + (gcol - (DI + CONVD))] = v;
        }
      }
    }
  }
}

// ---------------- K4: depthwise causal conv(4) + SiLU, register-tiled x8 tokens ----------------
__global__ __launch_bounds__(256) void k_conv(
    const unsigned short* __restrict__ zxh, const float* __restrict__ cw,
    const float* __restrict__ cb, unsigned short* __restrict__ xcb)
{
  const int nC4 = CONVD/4;
  int gid = blockIdx.x*256 + threadIdx.x;
  if (gid >= (MQ/8)*nC4) return;
  int c4 = gid % nC4;
  int mb = gid / nC4;
  int m0 = mb*8;
  int l0 = m0 % LQ;
  int c0 = c4*4;
  float4 cbv = *(const float4*)(cb + c0);
  float4 w0 = *(const float4*)(cw + (c0+0)*4);
  float4 w1 = *(const float4*)(cw + (c0+1)*4);
  float4 w2 = *(const float4*)(cw + (c0+2)*4);
  float4 w3 = *(const float4*)(cw + (c0+3)*4);
  const float* wp[4] = {(const float*)&w0, (const float*)&w1,
                        (const float*)&w2, (const float*)&w3};
  float vals[11][4];
  #pragma unroll
  for (int r = 0; r < 11; r++) {
    int ls = l0 - 3 + r;
    uint2 u = make_uint2(0,0);
    if (ls >= 0)
      u = *(const uint2*)(zxh + (size_t)(m0-3+r)*DIP + DI + c0);
    vals[r][0] = bf2f((unsigned short)(u.x & 0xffff));
    vals[r][1] = bf2f((unsigned short)(u.x >> 16));
    vals[r][2] = bf2f((unsigned short)(u.y & 0xffff));
    vals[r][3] = bf2f((unsigned short)(u.y >> 16));
  }
  const float* cbp = (const float*)&cbv;
  #pragma unroll
  for (int u = 0; u < 8; u++) {
    unsigned short o[4];
    #pragma unroll
    for (int ch = 0; ch < 4; ch++) {
      float a = cbp[ch];
      #pragma unroll
      for (int j = 0; j < 4; j++)
        a = fmaf(vals[u+j][ch], wp[ch][j], a);
      o[ch] = f2bf(a / (1.f + __expf(-a)));
    }
    *(uint2*)(xcb + (size_t)(m0+u)*CONVD + c0) = *(const uint2*)o;
  }
}

// ---------------- K5ab: fused softplus + in-wave cumsum + chunk end-state MFMA ----------------
__global__ __launch_bounds__(256) void k_cumsum_state(
    const float* __restrict__ dtraw, const float* __restrict__ dt_bias,
    const float* __restrict__ A_log, const unsigned short* __restrict__ xcb,
    float* __restrict__ dtb, float* __restrict__ cs, float* __restrict__ Dc,
    float* __restrict__ Sbuf)
{
  int c = blockIdx.x, h = blockIdx.y, b = blockIdx.z;
  int len = LQ - c*QC; if (len > QC) len = QC;
  int t = threadIdx.x;
  int lane = t & 63, wid = t >> 6;
  int fr = lane & 15, fq = lane >> 4;
  int m0 = b*LQ + c*QC;

  __shared__ unsigned short XT[HD*QC];
  __shared__ unsigned short BwT[DS*QC];
  __shared__ float ws[QC];

  for (int idx = t; idx < (HD/8)*QC; idx += 256) {
    int pg = idx % 10, i = idx / 10;
    uint4 v = make_uint4(0,0,0,0);
    if (i < len)
      v = *(const uint4*)(xcb + (size_t)(m0+i)*CONVD + h*HD + pg*8);
    union { uint4 u; unsigned short us[8]; } cv; cv.u = v;
    #pragma unroll
    for (int e = 0; e < 8; e++)
      XT[swz64(pg*8+e, i)] = cv.us[e];
  }

  if (t < QC) {
    float A = -expf(A_log[h]);
    float sp = 0.f;
    if (t < len) {
      float v = dtraw[((size_t)(m0+t))*NH + h] + dt_bias[h];
      sp = (v > 20.f) ? v : log1pf(expf(v));
      dtb[((size_t)(m0+t))*NH + h] = sp;
    }
    float a = sp * A;
    #pragma unroll
    for (int off = 1; off < 64; off <<= 1) {
      float pv = __shfl_up(a, off, 64);
      if (t >= off) a += pv;
    }
    cs[((size_t)(b*NH+h)*NC + c)*QC + t] = a;
    if (t == len-1) Dc[(b*NH+h)*NC + c] = expf(a);
    float aEnd = __shfl(a, len-1, 64);
    ws[t] = (t < len) ? __expf(aEnd - a) * sp : 0.f;
  }
  __syncthreads();
  for (int idx = t; idx < DS*QC; idx += 256) {
    int n = idx & 31, i = idx >> 5;
    float v = (i < len) ? bf2f(xcb[(size_t)(m0+i)*CONVD + DI + n]) * ws[i] : 0.f;
    BwT[swz64(n, i)] = f2bf(v);
  }
  __syncthreads();

  size_t base = ((size_t)(b*NC + c)*NH + h)*(HD*DS);
  for (int tp = wid; tp < 10; tp += 4) {
    int pi = tp >> 1, ni = tp & 1;
    f32x4 acc = {};
    #pragma unroll
    for (int ks = 0; ks < 2; ks++) {
      bf16x8 fa = *(const bf16x8*)&XT[swz64(pi*16 + fr, ks*32 + fq*8)];
      bf16x8 fb = *(const bf16x8*)&BwT[swz64(ni*16 + fr, ks*32 + fq*8)];
      acc = __builtin_amdgcn_mfma_f32_16x16x32_bf16(fa, fb, acc, 0, 0, 0);
    }
    #pragma unroll
    for (int rr = 0; rr < 4; rr++)
      Sbuf[base + (size_t)(pi*16 + fq*4 + rr)*DS + ni*16 + fr] = acc[rr];
  }
}

// ---------------- K5c: sequential scan over chunk states, bf16 H0 out ----------------
__global__ __launch_bounds__(256) void k_state_scan(
    const float* __restrict__ Sbuf, const float* __restrict__ Dc,
    unsigned short* __restrict__ H0h)
{
  int tid = blockIdx.x*256 + threadIdx.x;
  int pn = tid % (HD*DS);
  int bh = tid / (HD*DS);
  int b = bh >> 3, h = bh & 7;
  float hst = 0.f;
  for (int c = 0; c < NC; c++) {
    size_t idx = ((size_t)(b*NC + c)*NH + h)*(HD*DS) + pn;
    float sv = Sbuf[idx];
    H0h[idx] = f2bf(hst);
    hst = hst * Dc[bh*NC + c] + sv;
  }
}

// ---------------- K5d: per-chunk outputs (QC=64) + ssum8 partials ----------------
__global__ __launch_bounds__(256) void k_chunk_y_mfma(
    const unsigned short* __restrict__ xcb, const unsigned short* __restrict__ zxh,
    const float* __restrict__ dtb, const float* __restrict__ cs,
    const unsigned short* __restrict__ H0h, const float* __restrict__ Dp,
    unsigned short* __restrict__ ygb, float* __restrict__ ssum8)
{
  int c = blockIdx.x, h = blockIdx.y, b = blockIdx.z;
  int len = LQ - c*QC; if (len > QC) len = QC;
  int t = threadIdx.x;
  int lane = t & 63, wid = t >> 6;
  int fr = lane & 15, fq = lane >> 4;
  int m0 = b*LQ + c*QC;

  __shared__ unsigned short XT[HD*QC];
  __shared__ unsigned short Wt[4*16*32];
  __shared__ float slA[QC], dtlA[QC], elA[QC];

  const float* csb = cs + ((size_t)(b*NH+h)*NC + c)*QC;

  for (int idx = t; idx < (HD/8)*QC; idx += 256) {
    int pg = idx % 10, i = idx / 10;
    uint4 v = make_uint4(0,0,0,0);
    if (i < len)
      v = *(const uint4*)(xcb + (size_t)(m0+i)*CONVD + h*HD + pg*8);
    union { uint4 u; unsigned short us[8]; } cv; cv.u = v;
    #pragma unroll
    for (int e = 0; e < 8; e++)
      XT[swz64(pg*8+e, i)] = cv.us[e];
  }
  if (t < QC) {
    float s = csb[t];
    slA[t] = s;
    elA[t] = __expf(s);
    dtlA[t] = (t < len) ? dtb[((size_t)(m0+t))*NH + h] : 0.f;
  }
  __syncthreads();

  int row16 = wid*16 + fr;
  bf16x8 fa = {};
  if (row16 < len)
    fa = *(const bf16x8*)(xcb + (size_t)(m0+row16)*CONVD + DI + DS + fq*8);

  // inter-chunk: C @ H0^T (H0 already bf16)
  size_t hb = ((size_t)(b*NC + c)*NH + h)*(HD*DS);
  f32x4 acc[5];
  #pragma unroll
  for (int j = 0; j < 5; j++) {
    int p = j*16 + fr;
    bf16x8 fb = *(const bf16x8*)(H0h + hb + (size_t)p*DS + fq*8);
    f32x4 z = {};
    acc[j] = __builtin_amdgcn_mfma_f32_16x16x32_bf16(fa, fb, z, 0, 0, 0);
  }
  #pragma unroll
  for (int rr = 0; rr < 4; rr++) {
    float el = elA[wid*16 + fq*4 + rr];
    #pragma unroll
    for (int j = 0; j < 5; j++) acc[j][rr] *= el;
  }

  int wbase = wid << 9;
  for (int sc = 0; sc < 2; sc++) {
    int i0 = sc*32;
    #pragma unroll
    for (int jt = 0; jt < 2; jt++) {
      int col = i0 + jt*16 + fr;
      bf16x8 fbv = {};
      if (col < len)
        fbv = *(const bf16x8*)(xcb + (size_t)(m0+col)*CONVD + DI + fq*8);
      float sc_col = slA[col], dt_col = dtlA[col];
      f32x4 z = {};
      f32x4 g = __builtin_amdgcn_mfma_f32_16x16x32_bf16(fa, fbv, z, 0, 0, 0);
      #pragma unroll
      for (int rr = 0; rr < 4; rr++) {
        int lr = fq*4 + rr;
        int row = wid*16 + lr;
        float v = 0.f;
        if (col <= row)
          v = g[rr] * __expf(slA[row] - sc_col) * dt_col;
        int lc = jt*16 + fr;
        int slot = (lc >> 3) ^ (lr & 3);
        Wt[wbase + (lr<<5) + (slot<<3) + (lc&7)] = f2bf(v);
      }
    }
    bf16x8 wa = *(const bf16x8*)&Wt[wbase + (fr<<5) + ((fq ^ (fr&3))<<3)];
    #pragma unroll
    for (int j = 0; j < 5; j++) {
      int p = j*16 + fr;
      bf16x8 xb = *(const bf16x8*)&XT[swz64(p, i0 + fq*8)];
      acc[j] = __builtin_amdgcn_mfma_f32_16x16x32_bf16(wa, xb, acc[j], 0, 0, 0);
    }
  }

  // epilogue: Dp skip + z-gate, store RAW gated y (bf16) + ssum8 partial
  float dpv = Dp[h];
  #pragma unroll
  for (int rr = 0; rr < 4; rr++) {
    int l = wid*16 + fq*4 + rr;
    if (l >= len) continue;
    size_t m = m0 + l;
    float ssp = 0.f;
    #pragma unroll
    for (int j = 0; j < 5; j++) {
      int p = j*16 + fr;
      int cc = h*HD + p;
      float xv = bf2f(XT[swz64(p, l)]);
      float y = acc[j][rr] + xv*dpv;
      float zv = bf2f(zxh[m*DIP + cc]);
      y *= zv / (1.f + __expf(-zv));
      ygb[m*DI + cc] = f2bf(y);
      ssp = fmaf(y, y, ssp);
    }
    #pragma unroll
    for (int o = 1; o < 16; o <<= 1) ssp += __shfl_xor(ssp, o);
    if (fr == 0) ssum8[m*NH + h] = ssp;
  }
}

// ---------------- K7: out^T = (w2*rsw) @ ygb^T, rsv in epilogue ----------------
__global__ __launch_bounds__(256) void k_gemm2_mfma(
    const unsigned short* __restrict__ W2h, const unsigned short* __restrict__ Ygh,
    const float* __restrict__ ssum8, float* __restrict__ out)
{
  __shared__ unsigned short As[2][128*32];
  __shared__ unsigned short Bs[2][128*32];
  int id = blockIdx.x;
  int xcd = id & 7, pos = id >> 3;
  const int q = 48, r = 3;
  int swz = (xcd < r ? xcd*(q+1) : r*(q+1) + (xcd-r)*q) + pos;
  int c0 = (swz % 3) * 128;
  int t0 = (swz / 3) * 128;
  int tid = threadIdx.x;
  int lane = tid & 63, wid = tid >> 6;
  int wr = wid >> 1, wc = wid & 1;
  int fr = lane & 15, fq = lane >> 4;
  int srow = lane >> 2;
  int scol = (lane & 3) * 8;

#define G2_STAGE(buf, kk)                                                   \
  {                                                                         \
    _Pragma("unroll")                                                       \
    for (int i = 0; i < 2; i++) {                                           \
      int seg = wid + i*4;                                                  \
      int rowA = seg*16 + srow;                                             \
      int ga = c0 + rowA; if (ga > CDIM-1) ga = CDIM-1;                     \
      gload16(W2h + (size_t)ga*DI + (kk) + scol, &As[buf][seg*512]);        \
      int gb = t0 + rowA; if (gb > MQ-1) gb = MQ-1;                         \
      gload16(Ygh + (size_t)gb*DI + (kk) + scol, &Bs[buf][seg*512]);        \
    }                                                                       \
  }

#define G2_COMPUTE(buf)                                                     \
  {                                                                         \
    bf16x8 fa[4], fb[4];                                                    \
    _Pragma("unroll")                                                       \
    for (int i = 0; i < 4; i++) {                                           \
      fa[i] = *(const bf16x8*)&As[buf][(wr*64 + i*16 + fr)*32 + fq*8];      \
      fb[i] = *(const bf16x8*)&Bs[buf][(wc*64 + i*16 + fr)*32 + fq*8];      \
    }                                                                       \
    _Pragma("unroll")                                                       \
    for (int i = 0; i < 4; i++)                                             \
      _Pragma("unroll")                                                     \
      for (int j = 0; j < 4; j++)                                           \
        acc[i][j] = __builtin_amdgcn_mfma_f32_16x16x32_bf16(fa[i], fb[j], acc[i][j], 0, 0, 0); \
  }

  f32x4 acc[4][4] = {};
  G2_STAGE(0, 0);
  __syncthreads();
  int cur = 0;
  for (int k0 = 32; k0 < DI; k0 += 32) {
    G2_STAGE(cur^1, k0);
    G2_COMPUTE(cur);
    __syncthreads();
    cur ^= 1;
  }
  G2_COMPUTE(cur);

  // per-lane rsv for each token column j
  float rsvj[4];
  #pragma unroll
  for (int j = 0; j < 4; j++) {
    int tok = t0 + wc*64 + j*16 + fr;
    float ss = 0.f;
    if (tok < MQ) {
      float4 a = *(const float4*)(ssum8 + (size_t)tok*NH);
      float4 bb = *(const float4*)(ssum8 + (size_t)tok*NH + 4);
      ss = (a.x + a.y + a.z + a.w) + (bb.x + bb.y + bb.z + bb.w);
    }
    rsvj[j] = rsqrtf(ss*(1.0f/DI) + 1e-5f);
  }

  #pragma unroll
  for (int i = 0; i < 4; i++) {
    #pragma unroll
    for (int j = 0; j < 4; j++) {
      #pragma unroll
      for (int rr = 0; rr < 4; rr++) {
        int ch  = c0 + wr*64 + i*16 + fq*4 + rr;
        int tok = t0 + wc*64 + j*16 + fr;
        if (ch < CDIM && tok < MQ) {
          int b = tok / LQ, l = tok % LQ;
          if (l < NTQ)
            out[((size_t)(b*CDIM + ch))*NTQ + l] = acc[i][j][rr] * rsvj[j];
        }
      }
    }
  }
}

extern "C" void kernel_launch(void* const* d_in, const int* in_sizes, int n_in,
                              void* d_out, int out_size, void* d_ws, size_t ws_size,
                              hipStream_t stream)
{
  const float* x       = (const float*)d_in[0];
  const float* pc      = (const float*)d_in[1];
  const float* lnw     = (const float*)d_in[2];
  const float* lnb     = (const float*)d_in[3];
  const float* w1      = (const float*)d_in[4];
  const float* cw      = (const float*)d_in[5];
  const float* cb      = (const float*)d_in[6];
  const float* dt_bias = (const float*)d_in[7];
  const float* A_log   = (const float*)d_in[8];
  const float* Dp      = (const float*)d_in[9];
  const float* rsw     = (const float*)d_in[10];
  const float* w2      = (const float*)d_in[11];
  const float* pg      = (const float*)d_in[12];
  const float* pew     = (const float*)d_in[13];
  const float* nap     = (const float*)d_in[14];
  const int*   plab    = (const int*)d_in[15];
  float* out = (float*)d_out;

  unsigned short* xnh  = (unsigned short*)d_ws;                     // MQ*CDIM bf16
  unsigned short* zxh  = xnh + (size_t)MQ*CDIM;                     // MQ*DIP bf16
  float* dtraw = (float*)(zxh + (size_t)MQ*DIP);                    // MQ*NH f32
  unsigned short* xcb  = (unsigned short*)(dtraw + (size_t)MQ*NH);  // MQ*CONVD bf16
  float* dtb = (float*)(xcb + (size_t)MQ*CONVD);                    // MQ*NH f32
  float* cs  = dtb + (size_t)MQ*NH;                                 // B*NH*NC*QC
  float* Dc  = cs  + (size_t)BQ*NH*NC*QC;                           // B*NH*NC
  float* Sb  = Dc  + (size_t)BQ*NH*NC;                              // B*NC*NH*HD*DS f32
  unsigned short* H0h = (unsigned short*)(Sb + (size_t)BQ*NC*NH*HD*DS); // same count bf16
  unsigned short* ygb = H0h + (size_t)BQ*NC*NH*HD*DS;               // MQ*DI bf16
  unsigned short* w1h = ygb + (size_t)MQ*DI;                        // DIP*CDIM bf16
  unsigned short* w2h = w1h + (size_t)DIP*CDIM;                     // CDIM*DI bf16 (rsw folded)
  float* muP = (float*)(w2h + (size_t)CDIM*DI);                     // 8*B*NTQ f32
  float* s2P = muP + (size_t)8*BQ*NTQ;                              // 8*B*NTQ f32
  float* ssum8 = s2P + (size_t)8*BQ*NTQ;                            // MQ*NH f32

  const int NBW = (DIP*CDIM/4 + CDIM*DI/4 + 255)/256;
  k_prep<<<NBW + 512 + 32, 256, 0, stream>>>(
      w1, w1h, w2, rsw, w2h, x, muP, s2P,
      pc, lnw, lnb, pg, pew, nap, plab, xnh);
  dim3 gn(NTQ/64, CDIM/64, BQ);
  k_norm_t<<<gn, 256, 0, stream>>>(x, muP, s2P, lnw, lnb, xnh);
  k_gemm1_mfma<<<129*11, 256, 0, stream>>>(xnh, w1h, zxh, dtraw);
  k_conv<<<((MQ/8)*(CONVD/4) + 255)/256, 256, 0, stream>>>(zxh, cw, cb, xcb);
  dim3 gc(NC, NH, BQ);
  k_cumsum_state<<<gc, 256, 0, stream>>>(dtraw, dt_bias, A_log, xcb, dtb, cs, Dc, Sb);
  k_state_scan<<<(BQ*NH*HD*DS)/256, 256, 0, stream>>>(Sb, Dc, H0h);
  k_chunk_y_mfma<<<gc, 256, 0, stream>>>(xcb, zxh, dtb, cs, H0h, Dp, ygb, ssum8);
  k_gemm2_mfma<<<129*3, 256, 0, stream>>>(w2h, ygb, ssum8, out);
}